// Round 1
// baseline (1762.101 us; speedup 1.0000x reference)
//
#include <hip/hip_runtime.h>
#include <hip/hip_bf16.h>
#include <math.h>

#define T_STEPS 5
#define NNODES  10000
#define F_IN    16
#define NEDGES  160000
#define ETOT    (NEDGES + NNODES)   // + self loops
#define CH      32
#define H0      2
#define GRUH    64
#define OUTH    32

// ---------------- CSR build ----------------
__global__ __launch_bounds__(256) void k_count(const int* __restrict__ ei, int* __restrict__ counts) {
    int idx = blockIdx.x * 256 + threadIdx.x;
    if (idx >= ETOT) return;
    int dst = (idx < NEDGES) ? ei[NEDGES + idx] : (idx - NEDGES);
    atomicAdd(&counts[dst], 1);
}

__global__ __launch_bounds__(1024) void k_scan(const int* __restrict__ counts, int* __restrict__ offs) {
    __shared__ int ssum[1024];
    int t = threadIdx.x;
    const int chunk = (NNODES + 1023) / 1024;
    int start = t * chunk, end = min(start + chunk, NNODES);
    int s = 0;
    for (int i = start; i < end; i++) s += counts[i];
    ssum[t] = s;
    __syncthreads();
    for (int off = 1; off < 1024; off <<= 1) {
        int v = (t >= off) ? ssum[t - off] : 0;
        __syncthreads();
        ssum[t] += v;
        __syncthreads();
    }
    int excl = (t == 0) ? 0 : ssum[t - 1];
    for (int i = start; i < end; i++) { offs[i] = excl; excl += counts[i]; }
    if (t == 1023) offs[NNODES] = ssum[1023];
}

__global__ __launch_bounds__(256) void k_fill(const int* __restrict__ ei, const int* __restrict__ offs,
                                              int* __restrict__ cursor, int* __restrict__ csr) {
    int idx = blockIdx.x * 256 + threadIdx.x;
    if (idx >= ETOT) return;
    int src, dst;
    if (idx < NEDGES) { src = ei[idx]; dst = ei[NEDGES + idx]; }
    else              { src = dst = idx - NEDGES; }
    int p = atomicAdd(&cursor[dst], 1);
    csr[offs[dst] + p] = src;
}

// ---------------- GAT layer 0 projections (16 -> 64 twice) + attn logits ----------------
__global__ __launch_bounds__(256) void k_mm0(const float* __restrict__ x,      // [N,16]
                                             const float* __restrict__ W,     // [16,64]
                                             const float* __restrict__ Wres,  // [16,64]
                                             const float* __restrict__ asrc,  // [64] = [2,32]
                                             const float* __restrict__ adst,  // [64]
                                             float* __restrict__ xw, float* __restrict__ xres,
                                             float* __restrict__ als, float* __restrict__ ald) {
    int wave = threadIdx.x >> 6, lane = threadIdx.x & 63;
    int node = blockIdx.x * 4 + wave;
    if (node >= NNODES) return;
    const float* xr = x + (size_t)node * F_IN;
    float xreg[F_IN];
#pragma unroll
    for (int k = 0; k < F_IN; k++) xreg[k] = xr[k];
    float acc = 0.f, accr = 0.f;
#pragma unroll
    for (int k = 0; k < F_IN; k++) {
        acc  += xreg[k] * W[k * 64 + lane];
        accr += xreg[k] * Wres[k * 64 + lane];
    }
    xw[(size_t)node * 64 + lane]   = acc;
    xres[(size_t)node * 64 + lane] = accr;
    float ps = acc * asrc[lane], pd = acc * adst[lane];
    for (int off = 16; off; off >>= 1) {
        ps += __shfl_down(ps, off, 32);
        pd += __shfl_down(pd, off, 32);
    }
    if ((lane & 31) == 0) {
        int h = lane >> 5;
        als[node * 2 + h] = ps;
        ald[node * 2 + h] = pd;
    }
}

// ---------------- GAT layer 0 gather: softmax over in-edges + aggregate, ELU, residual ----------------
__global__ __launch_bounds__(256) void k_gather0(const float* __restrict__ xw,   // [N,64]
                                                 const float* __restrict__ xres, // [N,64]
                                                 const float* __restrict__ als,  // [N,2]
                                                 const float* __restrict__ ald,  // [N,2]
                                                 const int* __restrict__ offs, const int* __restrict__ csr,
                                                 const float* __restrict__ b,    // [64]
                                                 float* __restrict__ x1) {
    int wave = threadIdx.x >> 6, lane = threadIdx.x & 63;
    int node = blockIdx.x * 4 + wave;
    if (node >= NNODES) return;
    int beg = offs[node], end = offs[node + 1];
    float ad0 = ald[node * 2 + 0], ad1 = ald[node * 2 + 1];
    // pass 1: max per head
    float m0 = -INFINITY, m1 = -INFINITY;
    for (int i = beg + lane; i < end; i += 64) {
        int s = csr[i];
        float e0 = als[s * 2 + 0] + ad0; e0 = e0 > 0.f ? e0 : 0.2f * e0;
        float e1 = als[s * 2 + 1] + ad1; e1 = e1 > 0.f ? e1 : 0.2f * e1;
        m0 = fmaxf(m0, e0); m1 = fmaxf(m1, e1);
    }
    for (int off = 32; off; off >>= 1) {
        m0 = fmaxf(m0, __shfl_down(m0, off));
        m1 = fmaxf(m1, __shfl_down(m1, off));
    }
    m0 = __shfl(m0, 0); m1 = __shfl(m1, 0);
    // pass 2: denominator per head
    float d0 = 0.f, d1 = 0.f;
    for (int i = beg + lane; i < end; i += 64) {
        int s = csr[i];
        float e0 = als[s * 2 + 0] + ad0; e0 = e0 > 0.f ? e0 : 0.2f * e0;
        float e1 = als[s * 2 + 1] + ad1; e1 = e1 > 0.f ? e1 : 0.2f * e1;
        d0 += expf(e0 - m0); d1 += expf(e1 - m1);
    }
    for (int off = 32; off; off >>= 1) {
        d0 += __shfl_down(d0, off);
        d1 += __shfl_down(d1, off);
    }
    d0 = __shfl(d0, 0); d1 = __shfl(d1, 0);
    float inv0 = 1.f / (d0 + 1e-16f), inv1 = 1.f / (d1 + 1e-16f);
    // pass 3: aggregate (lane = output channel; head = lane/32)
    float acc = 0.f;
    for (int i = beg; i < end; i++) {
        int s = csr[i];
        float e, w;
        if (lane < 32) { e = als[s * 2 + 0] + ad0; e = e > 0.f ? e : 0.2f * e; w = expf(e - m0) * inv0; }
        else           { e = als[s * 2 + 1] + ad1; e = e > 0.f ? e : 0.2f * e; w = expf(e - m1) * inv1; }
        acc += w * xw[(size_t)s * 64 + lane];
    }
    float v = acc + b[lane];
    v = v > 0.f ? v : expm1f(v);                       // ELU
    x1[(size_t)node * 64 + lane] = v + xres[(size_t)node * 64 + lane];
}

// ---------------- GAT layer 1 projections (64 -> 32 twice) + attn logits ----------------
__global__ __launch_bounds__(256) void k_mm1(const float* __restrict__ x1,    // [N,64]
                                             const float* __restrict__ W,    // [64,32]
                                             const float* __restrict__ Wres, // [64,32]
                                             const float* __restrict__ asrc, // [32]
                                             const float* __restrict__ adst, // [32]
                                             float* __restrict__ xw, float* __restrict__ xres,
                                             float* __restrict__ als, float* __restrict__ ald) {
    int wave = threadIdx.x >> 6, lane = threadIdx.x & 63;
    int node = blockIdx.x * 4 + wave;
    if (node >= NNODES) return;
    const float* xr = x1 + (size_t)node * 64;
    int j = lane & 31;
    const float* Wp = (lane < 32) ? W : Wres;
    float acc = 0.f;
#pragma unroll
    for (int k = 0; k < 64; k++) acc += xr[k] * Wp[k * 32 + j];
    if (lane < 32) xw[(size_t)node * 32 + j] = acc;
    else           xres[(size_t)node * 32 + j] = acc;
    float ps = (lane < 32) ? acc * asrc[j] : 0.f;
    float pd = (lane < 32) ? acc * adst[j] : 0.f;
    for (int off = 16; off; off >>= 1) {
        ps += __shfl_down(ps, off, 32);
        pd += __shfl_down(pd, off, 32);
    }
    if (lane == 0) { als[node] = ps; ald[node] = pd; }
}

// ---------------- GAT layer 1 gather ----------------
__global__ __launch_bounds__(256) void k_gather1(const float* __restrict__ xw,   // [N,32]
                                                 const float* __restrict__ xres, // [N,32]
                                                 const float* __restrict__ als,  // [N]
                                                 const float* __restrict__ ald,  // [N]
                                                 const int* __restrict__ offs, const int* __restrict__ csr,
                                                 const float* __restrict__ b,    // [32]
                                                 float* __restrict__ x2) {
    int wave = threadIdx.x >> 6, lane = threadIdx.x & 63;
    int node = blockIdx.x * 4 + wave;
    if (node >= NNODES) return;
    int beg = offs[node], end = offs[node + 1];
    float ad = ald[node];
    float m = -INFINITY;
    for (int i = beg + lane; i < end; i += 64) {
        float e = als[csr[i]] + ad; e = e > 0.f ? e : 0.2f * e;
        m = fmaxf(m, e);
    }
    for (int off = 32; off; off >>= 1) m = fmaxf(m, __shfl_down(m, off));
    m = __shfl(m, 0);
    float d = 0.f;
    for (int i = beg + lane; i < end; i += 64) {
        float e = als[csr[i]] + ad; e = e > 0.f ? e : 0.2f * e;
        d += expf(e - m);
    }
    for (int off = 32; off; off >>= 1) d += __shfl_down(d, off);
    d = __shfl(d, 0);
    float inv = 1.f / (d + 1e-16f);
    float acc = 0.f;
    for (int i = beg; i < end; i++) {
        int s = csr[i];
        float e = als[s] + ad; e = e > 0.f ? e : 0.2f * e;
        float w = expf(e - m) * inv;
        if (lane < 32) acc += w * xw[(size_t)s * 32 + lane];
    }
    if (lane < 32) {
        float v = acc + b[lane];
        v = v > 0.f ? v : expm1f(v);
        x2[(size_t)node * 32 + lane] = v + xres[(size_t)node * 32 + lane];
    }
}

// ---------------- GRU cell (torch GRUCell semantics) ----------------
template <int K>
__global__ __launch_bounds__(256) void k_gru(const float* __restrict__ x,   // [N,K]
                                             const float* __restrict__ hin, // [N,64]
                                             const float* __restrict__ Wi,  // [192,K]
                                             const float* __restrict__ Wh,  // [192,64]
                                             const float* __restrict__ bi, const float* __restrict__ bh,
                                             float* __restrict__ hout) {
    int wave = threadIdx.x >> 6, lane = threadIdx.x & 63;
    int node = blockIdx.x * 4 + wave;
    if (node >= NNODES) return;
    const float* xr = x + (size_t)node * K;
    const float* hr = hin + (size_t)node * 64;
    float gi_r = bi[lane], gi_z = bi[64 + lane], gi_n = bi[128 + lane];
#pragma unroll
    for (int k = 0; k < K; k++) {
        float xv = xr[k];
        gi_r += xv * Wi[lane * K + k];
        gi_z += xv * Wi[(64 + lane) * K + k];
        gi_n += xv * Wi[(128 + lane) * K + k];
    }
    float gh_r = bh[lane], gh_z = bh[64 + lane], gh_n = bh[128 + lane];
#pragma unroll
    for (int k = 0; k < 64; k++) {
        float hv = hr[k];
        gh_r += hv * Wh[lane * 64 + k];
        gh_z += hv * Wh[(64 + lane) * 64 + k];
        gh_n += hv * Wh[(128 + lane) * 64 + k];
    }
    float r = 1.f / (1.f + expf(-(gi_r + gh_r)));
    float z = 1.f / (1.f + expf(-(gi_z + gh_z)));
    float nn = tanhf(gi_n + r * gh_n);
    hout[(size_t)node * 64 + lane] = (1.f - z) * nn + z * hr[lane];
}

// ---------------- MLP head: relu(h1@fc1+b) @ fc2 + b ----------------
__global__ __launch_bounds__(256) void k_head(const float* __restrict__ h1,
                                              const float* __restrict__ fc1W, // [64,32]
                                              const float* __restrict__ fc1b, // [32]
                                              const float* __restrict__ fc2W, // [32]
                                              const float* __restrict__ fc2b, // [1]
                                              float* __restrict__ out) {
    int wave = threadIdx.x >> 6, lane = threadIdx.x & 63;
    int node = blockIdx.x * 4 + wave;
    if (node >= NNODES) return;
    const float* hr = h1 + (size_t)node * 64;
    float v = 0.f;
    if (lane < 32) {
        float a = fc1b[lane];
#pragma unroll
        for (int k = 0; k < 64; k++) a += hr[k] * fc1W[k * 32 + lane];
        a = fmaxf(a, 0.f);
        v = a * fc2W[lane];
    }
    for (int off = 32; off; off >>= 1) v += __shfl_down(v, off);
    if (lane == 0) out[node] = v + fc2b[0];
}

extern "C" void kernel_launch(void* const* d_in, const int* in_sizes, int n_in,
                              void* d_out, int out_size, void* d_ws, size_t ws_size,
                              hipStream_t stream) {
    const float* x_seq   = (const float*)d_in[0];
    const int*   ei      = (const int*)d_in[1];
    const float* gat0_W  = (const float*)d_in[2];
    const float* gat0_as = (const float*)d_in[3];
    const float* gat0_ad = (const float*)d_in[4];
    const float* gat0_b  = (const float*)d_in[5];
    const float* res0_W  = (const float*)d_in[6];
    const float* gat1_W  = (const float*)d_in[7];
    const float* gat1_as = (const float*)d_in[8];
    const float* gat1_ad = (const float*)d_in[9];
    const float* gat1_b  = (const float*)d_in[10];
    const float* res1_W  = (const float*)d_in[11];
    const float* gru0_Wi = (const float*)d_in[12];
    const float* gru0_Wh = (const float*)d_in[13];
    const float* gru0_bi = (const float*)d_in[14];
    const float* gru0_bh = (const float*)d_in[15];
    const float* gru1_Wi = (const float*)d_in[16];
    const float* gru1_Wh = (const float*)d_in[17];
    const float* gru1_bi = (const float*)d_in[18];
    const float* gru1_bh = (const float*)d_in[19];
    const float* fc1_W   = (const float*)d_in[20];
    const float* fc1_b   = (const float*)d_in[21];
    const float* fc2_W   = (const float*)d_in[22];
    const float* fc2_b   = (const float*)d_in[23];
    float* out = (float*)d_out;

    char* w = (char*)d_ws;
    size_t off = 0;
    auto take = [&](size_t bytes) { size_t r = off; off += (bytes + 255) & ~(size_t)255; return r; };
    const size_t N = NNODES;
    int*   counts = (int*)(w + take(N * 4));
    int*   cursor = (int*)(w + take(N * 4));
    int*   offs   = (int*)(w + take((N + 1) * 4));
    int*   csr    = (int*)(w + take((size_t)ETOT * 4));
    float* xw0    = (float*)(w + take(N * 64 * 4));
    float* xres0  = (float*)(w + take(N * 64 * 4));
    float* als0   = (float*)(w + take(N * 2 * 4));
    float* ald0   = (float*)(w + take(N * 2 * 4));
    float* x1     = (float*)(w + take(N * 64 * 4));
    float* xw1    = (float*)(w + take(N * 32 * 4));
    float* xres1  = (float*)(w + take(N * 32 * 4));
    float* als1   = (float*)(w + take(N * 4));
    float* ald1   = (float*)(w + take(N * 4));
    float* x2     = (float*)(w + take(N * 32 * 4));
    float* h0a    = (float*)(w + take(N * 64 * 4));
    float* h0b    = (float*)(w + take(N * 64 * 4));
    float* h1a    = (float*)(w + take(N * 64 * 4));
    float* h1b    = (float*)(w + take(N * 64 * 4));

    // CSR build (once per launch; ws is re-poisoned before every call)
    hipMemsetAsync(counts, 0, N * 4, stream);
    hipMemsetAsync(cursor, 0, N * 4, stream);
    const int egrid = (ETOT + 255) / 256;
    k_count<<<egrid, 256, 0, stream>>>(ei, counts);
    k_scan<<<1, 1024, 0, stream>>>(counts, offs);
    k_fill<<<egrid, 256, 0, stream>>>(ei, offs, cursor, csr);

    hipMemsetAsync(h0a, 0, N * 64 * 4, stream);
    hipMemsetAsync(h1a, 0, N * 64 * 4, stream);

    const int ngrid = (NNODES + 3) / 4;
    float *h0_in = h0a, *h0_out = h0b, *h1_in = h1a, *h1_out = h1b;
    for (int t = 0; t < T_STEPS; t++) {
        const float* xt = x_seq + (size_t)t * N * F_IN;
        k_mm0<<<ngrid, 256, 0, stream>>>(xt, gat0_W, res0_W, gat0_as, gat0_ad, xw0, xres0, als0, ald0);
        k_gather0<<<ngrid, 256, 0, stream>>>(xw0, xres0, als0, ald0, offs, csr, gat0_b, x1);
        k_mm1<<<ngrid, 256, 0, stream>>>(x1, gat1_W, res1_W, gat1_as, gat1_ad, xw1, xres1, als1, ald1);
        k_gather1<<<ngrid, 256, 0, stream>>>(xw1, xres1, als1, ald1, offs, csr, gat1_b, x2);
        k_gru<32><<<ngrid, 256, 0, stream>>>(x2, h0_in, gru0_Wi, gru0_Wh, gru0_bi, gru0_bh, h0_out);
        k_gru<64><<<ngrid, 256, 0, stream>>>(h0_out, h1_in, gru1_Wi, gru1_Wh, gru1_bi, gru1_bh, h1_out);
        float* tmp;
        tmp = h0_in; h0_in = h0_out; h0_out = tmp;
        tmp = h1_in; h1_in = h1_out; h1_out = tmp;
    }
    k_head<<<ngrid, 256, 0, stream>>>(h1_in, fc1_W, fc1_b, fc2_W, fc2_b, out);
}

// Round 2
// 883.135 us; speedup vs baseline: 1.9953x; 1.9953x over previous
//
#include <hip/hip_runtime.h>
#include <hip/hip_bf16.h>
#include <math.h>

#define T_STEPS 5
#define NNODES  10000
#define F_IN    16
#define NEDGES  160000
#define ETOT    (NEDGES + NNODES)   // + self loops
#define CH      32
#define H0      2
#define GRUH    64
#define OUTH    32

// ---------------- CSR build ----------------
__global__ __launch_bounds__(256) void k_count(const int* __restrict__ ei, int* __restrict__ counts) {
    int idx = blockIdx.x * 256 + threadIdx.x;
    if (idx >= ETOT) return;
    int dst = (idx < NEDGES) ? ei[NEDGES + idx] : (idx - NEDGES);
    atomicAdd(&counts[dst], 1);
}

__global__ __launch_bounds__(1024) void k_scan(const int* __restrict__ counts, int* __restrict__ offs) {
    __shared__ int ssum[1024];
    int t = threadIdx.x;
    const int chunk = (NNODES + 1023) / 1024;
    int start = t * chunk, end = min(start + chunk, NNODES);
    int s = 0;
    for (int i = start; i < end; i++) s += counts[i];
    ssum[t] = s;
    __syncthreads();
    for (int off = 1; off < 1024; off <<= 1) {
        int v = (t >= off) ? ssum[t - off] : 0;
        __syncthreads();
        ssum[t] += v;
        __syncthreads();
    }
    int excl = (t == 0) ? 0 : ssum[t - 1];
    for (int i = start; i < end; i++) { offs[i] = excl; excl += counts[i]; }
    if (t == 1023) offs[NNODES] = ssum[1023];
}

__global__ __launch_bounds__(256) void k_fill(const int* __restrict__ ei, const int* __restrict__ offs,
                                              int* __restrict__ cursor, int* __restrict__ csr) {
    int idx = blockIdx.x * 256 + threadIdx.x;
    if (idx >= ETOT) return;
    int src, dst;
    if (idx < NEDGES) { src = ei[idx]; dst = ei[NEDGES + idx]; }
    else              { src = dst = idx - NEDGES; }
    int p = atomicAdd(&cursor[dst], 1);
    csr[offs[dst] + p] = src;
}

// ---------------- one-time weight transpose for GRU cells ----------------
// WiT[k*192 + r] = Wi[r*K + k]; WhT[k*192 + r] = Wh[r*64 + k]
__global__ __launch_bounds__(256) void k_transpose(const float* __restrict__ Wi0, const float* __restrict__ Wh0,
                                                   const float* __restrict__ Wi1, const float* __restrict__ Wh1,
                                                   float* __restrict__ WiT0, float* __restrict__ WhT0,
                                                   float* __restrict__ WiT1, float* __restrict__ WhT1) {
    int idx = blockIdx.x * 256 + threadIdx.x;
    if (idx < 32 * 192) {
        int k = idx / 192, r = idx % 192;
        WiT0[idx] = Wi0[r * 32 + k];
        return;
    }
    idx -= 32 * 192;
    if (idx < 64 * 192) {
        int k = idx / 192, r = idx % 192;
        WhT0[idx] = Wh0[r * 64 + k];
        return;
    }
    idx -= 64 * 192;
    if (idx < 64 * 192) {
        int k = idx / 192, r = idx % 192;
        WiT1[idx] = Wi1[r * 64 + k];
        return;
    }
    idx -= 64 * 192;
    if (idx < 64 * 192) {
        int k = idx / 192, r = idx % 192;
        WhT1[idx] = Wh1[r * 64 + k];
    }
}

// ---------------- GAT layer 0 projections (16 -> 64 twice) + attn logits ----------------
__global__ __launch_bounds__(256) void k_mm0(const float* __restrict__ x,      // [N,16]
                                             const float* __restrict__ W,     // [16,64]
                                             const float* __restrict__ Wres,  // [16,64]
                                             const float* __restrict__ asrc,  // [64] = [2,32]
                                             const float* __restrict__ adst,  // [64]
                                             float* __restrict__ xw, float* __restrict__ xres,
                                             float* __restrict__ als, float* __restrict__ ald) {
    int wave = threadIdx.x >> 6, lane = threadIdx.x & 63;
    int node = blockIdx.x * 4 + wave;
    if (node >= NNODES) return;
    const float* xr = x + (size_t)node * F_IN;
    float xreg[F_IN];
#pragma unroll
    for (int k = 0; k < F_IN; k++) xreg[k] = xr[k];
    float acc = 0.f, accr = 0.f;
#pragma unroll
    for (int k = 0; k < F_IN; k++) {
        acc  += xreg[k] * W[k * 64 + lane];
        accr += xreg[k] * Wres[k * 64 + lane];
    }
    xw[(size_t)node * 64 + lane]   = acc;
    xres[(size_t)node * 64 + lane] = accr;
    float ps = acc * asrc[lane], pd = acc * adst[lane];
    for (int off = 16; off; off >>= 1) {
        ps += __shfl_down(ps, off, 32);
        pd += __shfl_down(pd, off, 32);
    }
    if ((lane & 31) == 0) {
        int h = lane >> 5;
        als[node * 2 + h] = ps;
        ald[node * 2 + h] = pd;
    }
}

// ---------------- GAT layer 0 gather: softmax over in-edges + aggregate, ELU, residual ----------------
__global__ __launch_bounds__(256) void k_gather0(const float* __restrict__ xw,   // [N,64]
                                                 const float* __restrict__ xres, // [N,64]
                                                 const float* __restrict__ als,  // [N,2]
                                                 const float* __restrict__ ald,  // [N,2]
                                                 const int* __restrict__ offs, const int* __restrict__ csr,
                                                 const float* __restrict__ b,    // [64]
                                                 float* __restrict__ x1) {
    int wave = threadIdx.x >> 6, lane = threadIdx.x & 63;
    int node = blockIdx.x * 4 + wave;
    if (node >= NNODES) return;
    int beg = offs[node], end = offs[node + 1];
    float ad0 = ald[node * 2 + 0], ad1 = ald[node * 2 + 1];
    // pass 1: max per head
    float m0 = -INFINITY, m1 = -INFINITY;
    for (int i = beg + lane; i < end; i += 64) {
        int s = csr[i];
        float e0 = als[s * 2 + 0] + ad0; e0 = e0 > 0.f ? e0 : 0.2f * e0;
        float e1 = als[s * 2 + 1] + ad1; e1 = e1 > 0.f ? e1 : 0.2f * e1;
        m0 = fmaxf(m0, e0); m1 = fmaxf(m1, e1);
    }
    for (int off = 32; off; off >>= 1) {
        m0 = fmaxf(m0, __shfl_down(m0, off));
        m1 = fmaxf(m1, __shfl_down(m1, off));
    }
    m0 = __shfl(m0, 0); m1 = __shfl(m1, 0);
    // pass 2: denominator per head
    float d0 = 0.f, d1 = 0.f;
    for (int i = beg + lane; i < end; i += 64) {
        int s = csr[i];
        float e0 = als[s * 2 + 0] + ad0; e0 = e0 > 0.f ? e0 : 0.2f * e0;
        float e1 = als[s * 2 + 1] + ad1; e1 = e1 > 0.f ? e1 : 0.2f * e1;
        d0 += expf(e0 - m0); d1 += expf(e1 - m1);
    }
    for (int off = 32; off; off >>= 1) {
        d0 += __shfl_down(d0, off);
        d1 += __shfl_down(d1, off);
    }
    d0 = __shfl(d0, 0); d1 = __shfl(d1, 0);
    float inv0 = 1.f / (d0 + 1e-16f), inv1 = 1.f / (d1 + 1e-16f);
    // pass 3: aggregate (lane = output channel; head = lane/32)
    float acc = 0.f;
    for (int i = beg; i < end; i++) {
        int s = csr[i];
        float e, w;
        if (lane < 32) { e = als[s * 2 + 0] + ad0; e = e > 0.f ? e : 0.2f * e; w = expf(e - m0) * inv0; }
        else           { e = als[s * 2 + 1] + ad1; e = e > 0.f ? e : 0.2f * e; w = expf(e - m1) * inv1; }
        acc += w * xw[(size_t)s * 64 + lane];
    }
    float v = acc + b[lane];
    v = v > 0.f ? v : expm1f(v);                       // ELU
    x1[(size_t)node * 64 + lane] = v + xres[(size_t)node * 64 + lane];
}

// ---------------- GAT layer 1 projections (64 -> 32 twice) + attn logits ----------------
__global__ __launch_bounds__(256) void k_mm1(const float* __restrict__ x1,    // [N,64]
                                             const float* __restrict__ W,    // [64,32]
                                             const float* __restrict__ Wres, // [64,32]
                                             const float* __restrict__ asrc, // [32]
                                             const float* __restrict__ adst, // [32]
                                             float* __restrict__ xw, float* __restrict__ xres,
                                             float* __restrict__ als, float* __restrict__ ald) {
    int wave = threadIdx.x >> 6, lane = threadIdx.x & 63;
    int node = blockIdx.x * 4 + wave;
    if (node >= NNODES) return;
    const float* xr = x1 + (size_t)node * 64;
    int j = lane & 31;
    const float* Wp = (lane < 32) ? W : Wres;
    float acc = 0.f;
#pragma unroll
    for (int k = 0; k < 64; k++) acc += xr[k] * Wp[k * 32 + j];
    if (lane < 32) xw[(size_t)node * 32 + j] = acc;
    else           xres[(size_t)node * 32 + j] = acc;
    float ps = (lane < 32) ? acc * asrc[j] : 0.f;
    float pd = (lane < 32) ? acc * adst[j] : 0.f;
    for (int off = 16; off; off >>= 1) {
        ps += __shfl_down(ps, off, 32);
        pd += __shfl_down(pd, off, 32);
    }
    if (lane == 0) { als[node] = ps; ald[node] = pd; }
}

// ---------------- GAT layer 1 gather ----------------
__global__ __launch_bounds__(256) void k_gather1(const float* __restrict__ xw,   // [N,32]
                                                 const float* __restrict__ xres, // [N,32]
                                                 const float* __restrict__ als,  // [N]
                                                 const float* __restrict__ ald,  // [N]
                                                 const int* __restrict__ offs, const int* __restrict__ csr,
                                                 const float* __restrict__ b,    // [32]
                                                 float* __restrict__ x2) {
    int wave = threadIdx.x >> 6, lane = threadIdx.x & 63;
    int node = blockIdx.x * 4 + wave;
    if (node >= NNODES) return;
    int beg = offs[node], end = offs[node + 1];
    float ad = ald[node];
    float m = -INFINITY;
    for (int i = beg + lane; i < end; i += 64) {
        float e = als[csr[i]] + ad; e = e > 0.f ? e : 0.2f * e;
        m = fmaxf(m, e);
    }
    for (int off = 32; off; off >>= 1) m = fmaxf(m, __shfl_down(m, off));
    m = __shfl(m, 0);
    float d = 0.f;
    for (int i = beg + lane; i < end; i += 64) {
        float e = als[csr[i]] + ad; e = e > 0.f ? e : 0.2f * e;
        d += expf(e - m);
    }
    for (int off = 32; off; off >>= 1) d += __shfl_down(d, off);
    d = __shfl(d, 0);
    float inv = 1.f / (d + 1e-16f);
    float acc = 0.f;
    for (int i = beg; i < end; i++) {
        int s = csr[i];
        float e = als[s] + ad; e = e > 0.f ? e : 0.2f * e;
        float w = expf(e - m) * inv;
        if (lane < 32) acc += w * xw[(size_t)s * 32 + lane];
    }
    if (lane < 32) {
        float v = acc + b[lane];
        v = v > 0.f ? v : expm1f(v);
        x2[(size_t)node * 32 + lane] = v + xres[(size_t)node * 32 + lane];
    }
}

// ---------------- GRU cell, transposed weights, 8 nodes per wave ----------------
// WiT: [K][192] (k-major), WhT: [64][192]. lane = hidden j.
#define NPW 8
template <int K>
__global__ __launch_bounds__(256) void k_gru(const float* __restrict__ x,   // [N,K]
                                             const float* __restrict__ hin, // [N,64]
                                             const float* __restrict__ WiT, // [K,192]
                                             const float* __restrict__ WhT, // [64,192]
                                             const float* __restrict__ bi, const float* __restrict__ bh,
                                             float* __restrict__ hout) {
    int wave = threadIdx.x >> 6, lane = threadIdx.x & 63;
    int node0 = (blockIdx.x * 4 + wave) * NPW;
    if (node0 >= NNODES) return;
    float gi_r[NPW], gi_z[NPW], gi_n[NPW], gh_r[NPW], gh_z[NPW], gh_n[NPW];
    float bir = bi[lane], biz = bi[64 + lane], bin_ = bi[128 + lane];
    float bhr = bh[lane], bhz = bh[64 + lane], bhn = bh[128 + lane];
#pragma unroll
    for (int n = 0; n < NPW; n++) {
        gi_r[n] = bir; gi_z[n] = biz; gi_n[n] = bin_;
        gh_r[n] = bhr; gh_z[n] = bhz; gh_n[n] = bhn;
    }
    int nclamp[NPW];
#pragma unroll
    for (int n = 0; n < NPW; n++) nclamp[n] = min(node0 + n, NNODES - 1);
#pragma unroll 4
    for (int k = 0; k < K; k++) {
        float wr = WiT[k * 192 + lane];
        float wz = WiT[k * 192 + 64 + lane];
        float wn = WiT[k * 192 + 128 + lane];
#pragma unroll
        for (int n = 0; n < NPW; n++) {
            float xv = x[(size_t)nclamp[n] * K + k];
            gi_r[n] += xv * wr; gi_z[n] += xv * wz; gi_n[n] += xv * wn;
        }
    }
#pragma unroll 4
    for (int k = 0; k < 64; k++) {
        float wr = WhT[k * 192 + lane];
        float wz = WhT[k * 192 + 64 + lane];
        float wn = WhT[k * 192 + 128 + lane];
#pragma unroll
        for (int n = 0; n < NPW; n++) {
            float hv = hin[(size_t)nclamp[n] * 64 + k];
            gh_r[n] += hv * wr; gh_z[n] += hv * wz; gh_n[n] += hv * wn;
        }
    }
#pragma unroll
    for (int n = 0; n < NPW; n++) {
        int node = node0 + n;
        if (node >= NNODES) break;
        float hprev = hin[(size_t)node * 64 + lane];
        float r = 1.f / (1.f + expf(-(gi_r[n] + gh_r[n])));
        float z = 1.f / (1.f + expf(-(gi_z[n] + gh_z[n])));
        float nn = tanhf(gi_n[n] + r * gh_n[n]);
        hout[(size_t)node * 64 + lane] = (1.f - z) * nn + z * hprev;
    }
}

// ---------------- MLP head: relu(h1@fc1+b) @ fc2 + b ----------------
__global__ __launch_bounds__(256) void k_head(const float* __restrict__ h1,
                                              const float* __restrict__ fc1W, // [64,32]
                                              const float* __restrict__ fc1b, // [32]
                                              const float* __restrict__ fc2W, // [32]
                                              const float* __restrict__ fc2b, // [1]
                                              float* __restrict__ out) {
    int wave = threadIdx.x >> 6, lane = threadIdx.x & 63;
    int node = blockIdx.x * 4 + wave;
    if (node >= NNODES) return;
    const float* hr = h1 + (size_t)node * 64;
    float v = 0.f;
    if (lane < 32) {
        float a = fc1b[lane];
#pragma unroll
        for (int k = 0; k < 64; k++) a += hr[k] * fc1W[k * 32 + lane];
        a = fmaxf(a, 0.f);
        v = a * fc2W[lane];
    }
    for (int off = 32; off; off >>= 1) v += __shfl_down(v, off);
    if (lane == 0) out[node] = v + fc2b[0];
}

extern "C" void kernel_launch(void* const* d_in, const int* in_sizes, int n_in,
                              void* d_out, int out_size, void* d_ws, size_t ws_size,
                              hipStream_t stream) {
    const float* x_seq   = (const float*)d_in[0];
    const int*   ei      = (const int*)d_in[1];
    const float* gat0_W  = (const float*)d_in[2];
    const float* gat0_as = (const float*)d_in[3];
    const float* gat0_ad = (const float*)d_in[4];
    const float* gat0_b  = (const float*)d_in[5];
    const float* res0_W  = (const float*)d_in[6];
    const float* gat1_W  = (const float*)d_in[7];
    const float* gat1_as = (const float*)d_in[8];
    const float* gat1_ad = (const float*)d_in[9];
    const float* gat1_b  = (const float*)d_in[10];
    const float* res1_W  = (const float*)d_in[11];
    const float* gru0_Wi = (const float*)d_in[12];
    const float* gru0_Wh = (const float*)d_in[13];
    const float* gru0_bi = (const float*)d_in[14];
    const float* gru0_bh = (const float*)d_in[15];
    const float* gru1_Wi = (const float*)d_in[16];
    const float* gru1_Wh = (const float*)d_in[17];
    const float* gru1_bi = (const float*)d_in[18];
    const float* gru1_bh = (const float*)d_in[19];
    const float* fc1_W   = (const float*)d_in[20];
    const float* fc1_b   = (const float*)d_in[21];
    const float* fc2_W   = (const float*)d_in[22];
    const float* fc2_b   = (const float*)d_in[23];
    float* out = (float*)d_out;

    char* w = (char*)d_ws;
    size_t off = 0;
    auto take = [&](size_t bytes) { size_t r = off; off += (bytes + 255) & ~(size_t)255; return r; };
    const size_t N = NNODES;
    int*   counts = (int*)(w + take(N * 4));
    int*   cursor = (int*)(w + take(N * 4));
    int*   offs   = (int*)(w + take((N + 1) * 4));
    int*   csr    = (int*)(w + take((size_t)ETOT * 4));
    float* xw0    = (float*)(w + take(N * 64 * 4));
    float* xres0  = (float*)(w + take(N * 64 * 4));
    float* als0   = (float*)(w + take(N * 2 * 4));
    float* ald0   = (float*)(w + take(N * 2 * 4));
    float* x1     = (float*)(w + take(N * 64 * 4));
    float* xw1    = (float*)(w + take(N * 32 * 4));
    float* xres1  = (float*)(w + take(N * 32 * 4));
    float* als1   = (float*)(w + take(N * 4));
    float* ald1   = (float*)(w + take(N * 4));
    float* x2     = (float*)(w + take(N * 32 * 4));
    float* h0a    = (float*)(w + take(N * 64 * 4));
    float* h0b    = (float*)(w + take(N * 64 * 4));
    float* h1a    = (float*)(w + take(N * 64 * 4));
    float* h1b    = (float*)(w + take(N * 64 * 4));
    float* wiT0   = (float*)(w + take(32 * 192 * 4));
    float* whT0   = (float*)(w + take(64 * 192 * 4));
    float* wiT1   = (float*)(w + take(64 * 192 * 4));
    float* whT1   = (float*)(w + take(64 * 192 * 4));

    // CSR build + weight transpose (once per launch; ws re-poisoned each call)
    hipMemsetAsync(counts, 0, N * 4, stream);
    hipMemsetAsync(cursor, 0, N * 4, stream);
    const int egrid = (ETOT + 255) / 256;
    k_count<<<egrid, 256, 0, stream>>>(ei, counts);
    k_scan<<<1, 1024, 0, stream>>>(counts, offs);
    k_fill<<<egrid, 256, 0, stream>>>(ei, offs, cursor, csr);
    const int ttot = 32 * 192 + 3 * 64 * 192;
    k_transpose<<<(ttot + 255) / 256, 256, 0, stream>>>(gru0_Wi, gru0_Wh, gru1_Wi, gru1_Wh,
                                                        wiT0, whT0, wiT1, whT1);

    hipMemsetAsync(h0a, 0, N * 64 * 4, stream);
    hipMemsetAsync(h1a, 0, N * 64 * 4, stream);

    const int ngrid = (NNODES + 3) / 4;
    const int ggrid = (NNODES + 4 * NPW - 1) / (4 * NPW);
    float *h0_in = h0a, *h0_out = h0b, *h1_in = h1a, *h1_out = h1b;
    for (int t = 0; t < T_STEPS; t++) {
        const float* xt = x_seq + (size_t)t * N * F_IN;
        k_mm0<<<ngrid, 256, 0, stream>>>(xt, gat0_W, res0_W, gat0_as, gat0_ad, xw0, xres0, als0, ald0);
        k_gather0<<<ngrid, 256, 0, stream>>>(xw0, xres0, als0, ald0, offs, csr, gat0_b, x1);
        k_mm1<<<ngrid, 256, 0, stream>>>(x1, gat1_W, res1_W, gat1_as, gat1_ad, xw1, xres1, als1, ald1);
        k_gather1<<<ngrid, 256, 0, stream>>>(xw1, xres1, als1, ald1, offs, csr, gat1_b, x2);
        k_gru<32><<<ggrid, 256, 0, stream>>>(x2, h0_in, wiT0, whT0, gru0_bi, gru0_bh, h0_out);
        k_gru<64><<<ggrid, 256, 0, stream>>>(h0_out, h1_in, wiT1, whT1, gru1_bi, gru1_bh, h1_out);
        float* tmp;
        tmp = h0_in; h0_in = h0_out; h0_out = tmp;
        tmp = h1_in; h1_in = h1_out; h1_out = tmp;
    }
    k_head<<<ngrid, 256, 0, stream>>>(h1_in, fc1_W, fc1_b, fc2_W, fc2_b, out);
}

// Round 3
// 604.067 us; speedup vs baseline: 2.9171x; 1.4620x over previous
//
#include <hip/hip_runtime.h>
#include <hip/hip_bf16.h>
#include <math.h>

#define T_STEPS 5
#define NNODES  10000
#define F_IN    16
#define NEDGES  160000
#define ETOT    (NEDGES + NNODES)   // + self loops
#define NPW     8                   // nodes per wave in GRU kernel

// ---------------- CSR build ----------------
__global__ __launch_bounds__(256) void k_count(const int* __restrict__ ei, int* __restrict__ counts) {
    int idx = blockIdx.x * 256 + threadIdx.x;
    if (idx >= ETOT) return;
    int dst = (idx < NEDGES) ? ei[NEDGES + idx] : (idx - NEDGES);
    atomicAdd(&counts[dst], 1);
}

__global__ __launch_bounds__(1024) void k_scan(const int* __restrict__ counts, int* __restrict__ offs) {
    __shared__ int ssum[1024];
    int t = threadIdx.x;
    const int chunk = (NNODES + 1023) / 1024;
    int start = t * chunk, end = min(start + chunk, NNODES);
    int s = 0;
    for (int i = start; i < end; i++) s += counts[i];
    ssum[t] = s;
    __syncthreads();
    for (int off = 1; off < 1024; off <<= 1) {
        int v = (t >= off) ? ssum[t - off] : 0;
        __syncthreads();
        ssum[t] += v;
        __syncthreads();
    }
    int excl = (t == 0) ? 0 : ssum[t - 1];
    for (int i = start; i < end; i++) { offs[i] = excl; excl += counts[i]; }
    if (t == 1023) offs[NNODES] = ssum[1023];
}

__global__ __launch_bounds__(256) void k_fill(const int* __restrict__ ei, const int* __restrict__ offs,
                                              int* __restrict__ cursor, int* __restrict__ csr) {
    int idx = blockIdx.x * 256 + threadIdx.x;
    if (idx >= ETOT) return;
    int src, dst;
    if (idx < NEDGES) { src = ei[idx]; dst = ei[NEDGES + idx]; }
    else              { src = dst = idx - NEDGES; }
    int p = atomicAdd(&cursor[dst], 1);
    csr[offs[dst] + p] = src;
}

// ---------------- one-time weight transpose for GRU cells ----------------
// WiT[k*192 + r] = Wi[r*K + k]; WhT[k*192 + r] = Wh[r*64 + k]
__global__ __launch_bounds__(256) void k_transpose(const float* __restrict__ Wi0, const float* __restrict__ Wh0,
                                                   const float* __restrict__ Wi1, const float* __restrict__ Wh1,
                                                   float* __restrict__ WiT0, float* __restrict__ WhT0,
                                                   float* __restrict__ WiT1, float* __restrict__ WhT1) {
    int idx = blockIdx.x * 256 + threadIdx.x;
    if (idx < 32 * 192) {
        int k = idx / 192, r = idx % 192;
        WiT0[idx] = Wi0[r * 32 + k];
        return;
    }
    idx -= 32 * 192;
    if (idx < 64 * 192) {
        int k = idx / 192, r = idx % 192;
        WhT0[idx] = Wh0[r * 64 + k];
        return;
    }
    idx -= 64 * 192;
    if (idx < 64 * 192) {
        int k = idx / 192, r = idx % 192;
        WiT1[idx] = Wi1[r * 64 + k];
        return;
    }
    idx -= 64 * 192;
    if (idx < 64 * 192) {
        int k = idx / 192, r = idx % 192;
        WhT1[idx] = Wh1[r * 64 + k];
    }
}

// ---------------- GAT layer 0 projections (16 -> 64 twice) + attn logits ----------------
__global__ __launch_bounds__(256) void k_mm0(const float* __restrict__ x,      // [N,16]
                                             const float* __restrict__ W,     // [16,64]
                                             const float* __restrict__ Wres,  // [16,64]
                                             const float* __restrict__ asrc,  // [64]
                                             const float* __restrict__ adst,  // [64]
                                             float* __restrict__ xw, float* __restrict__ xres,
                                             float* __restrict__ als, float* __restrict__ ald) {
    int wave = threadIdx.x >> 6, lane = threadIdx.x & 63;
    int node = blockIdx.x * 4 + wave;
    if (node >= NNODES) return;
    const float* xr = x + (size_t)node * F_IN;
    float xreg[F_IN];
#pragma unroll
    for (int k = 0; k < F_IN; k++) xreg[k] = xr[k];
    float acc = 0.f, accr = 0.f;
#pragma unroll
    for (int k = 0; k < F_IN; k++) {
        acc  += xreg[k] * W[k * 64 + lane];
        accr += xreg[k] * Wres[k * 64 + lane];
    }
    xw[(size_t)node * 64 + lane]   = acc;
    xres[(size_t)node * 64 + lane] = accr;
    float ps = acc * asrc[lane], pd = acc * adst[lane];
    for (int off = 16; off; off >>= 1) {
        ps += __shfl_down(ps, off, 32);
        pd += __shfl_down(pd, off, 32);
    }
    if ((lane & 31) == 0) {
        int h = lane >> 5;
        als[node * 2 + h] = ps;
        ald[node * 2 + h] = pd;
    }
}

// ---------------- fused: GAT0 gather+softmax+ELU+residual, then GAT1 projection ----------------
__global__ __launch_bounds__(256) void k_gat0(const float* __restrict__ xw,   // [N,64]
                                              const float* __restrict__ xres, // [N,64]
                                              const float* __restrict__ als,  // [N,2]
                                              const float* __restrict__ ald,  // [N,2]
                                              const int* __restrict__ offs, const int* __restrict__ csr,
                                              const float* __restrict__ b,    // [64]
                                              const float* __restrict__ W1,   // [64,32]
                                              const float* __restrict__ Wres1,// [64,32]
                                              const float* __restrict__ as1,  // [32]
                                              const float* __restrict__ ad1v, // [32]
                                              float* __restrict__ xw1, float* __restrict__ xres1,
                                              float* __restrict__ als1, float* __restrict__ ald1) {
    int wave = threadIdx.x >> 6, lane = threadIdx.x & 63;
    int node = blockIdx.x * 4 + wave;
    if (node >= NNODES) return;
    int beg = offs[node], end = offs[node + 1];
    int deg = end - beg;
    float ad0 = ald[node * 2 + 0], ad1 = ald[node * 2 + 1];
    float acc;
    if (deg <= 64) {
        // one edge per lane, logits in registers
        int s = 0; float e0 = -INFINITY, e1 = -INFINITY;
        if (lane < deg) {
            s = csr[beg + lane];
            e0 = als[s * 2 + 0] + ad0; e0 = e0 > 0.f ? e0 : 0.2f * e0;
            e1 = als[s * 2 + 1] + ad1; e1 = e1 > 0.f ? e1 : 0.2f * e1;
        }
        float m0 = e0, m1 = e1;
        for (int o = 32; o; o >>= 1) {
            m0 = fmaxf(m0, __shfl_xor(m0, o));
            m1 = fmaxf(m1, __shfl_xor(m1, o));
        }
        float ex0 = (lane < deg) ? expf(e0 - m0) : 0.f;
        float ex1 = (lane < deg) ? expf(e1 - m1) : 0.f;
        float d0 = ex0, d1 = ex1;
        for (int o = 32; o; o >>= 1) {
            d0 += __shfl_xor(d0, o);
            d1 += __shfl_xor(d1, o);
        }
        ex0 *= 1.f / (d0 + 1e-16f);
        ex1 *= 1.f / (d1 + 1e-16f);
        // aggregation: lane = channel (head = lane>>5), unrolled over edges
        float a0 = 0.f, a1 = 0.f, a2 = 0.f, a3 = 0.f;
        int i = 0;
        for (; i + 4 <= deg; i += 4) {
            int   s0 = __shfl(s, i),     s1 = __shfl(s, i + 1), s2 = __shfl(s, i + 2), s3 = __shfl(s, i + 3);
            float u0 = __shfl(ex0, i),   v0 = __shfl(ex1, i);
            float u1 = __shfl(ex0, i+1), v1 = __shfl(ex1, i+1);
            float u2 = __shfl(ex0, i+2), v2 = __shfl(ex1, i+2);
            float u3 = __shfl(ex0, i+3), v3 = __shfl(ex1, i+3);
            a0 += (lane < 32 ? u0 : v0) * xw[(size_t)s0 * 64 + lane];
            a1 += (lane < 32 ? u1 : v1) * xw[(size_t)s1 * 64 + lane];
            a2 += (lane < 32 ? u2 : v2) * xw[(size_t)s2 * 64 + lane];
            a3 += (lane < 32 ? u3 : v3) * xw[(size_t)s3 * 64 + lane];
        }
        for (; i < deg; i++) {
            int s0 = __shfl(s, i);
            float u = __shfl(ex0, i), v = __shfl(ex1, i);
            a0 += (lane < 32 ? u : v) * xw[(size_t)s0 * 64 + lane];
        }
        acc = (a0 + a1) + (a2 + a3);
    } else {
        // general fallback: 3-pass
        float m0 = -INFINITY, m1 = -INFINITY;
        for (int i = beg + lane; i < end; i += 64) {
            int s = csr[i];
            float e0 = als[s * 2 + 0] + ad0; e0 = e0 > 0.f ? e0 : 0.2f * e0;
            float e1 = als[s * 2 + 1] + ad1; e1 = e1 > 0.f ? e1 : 0.2f * e1;
            m0 = fmaxf(m0, e0); m1 = fmaxf(m1, e1);
        }
        for (int o = 32; o; o >>= 1) {
            m0 = fmaxf(m0, __shfl_xor(m0, o));
            m1 = fmaxf(m1, __shfl_xor(m1, o));
        }
        float d0 = 0.f, d1 = 0.f;
        for (int i = beg + lane; i < end; i += 64) {
            int s = csr[i];
            float e0 = als[s * 2 + 0] + ad0; e0 = e0 > 0.f ? e0 : 0.2f * e0;
            float e1 = als[s * 2 + 1] + ad1; e1 = e1 > 0.f ? e1 : 0.2f * e1;
            d0 += expf(e0 - m0); d1 += expf(e1 - m1);
        }
        for (int o = 32; o; o >>= 1) { d0 += __shfl_xor(d0, o); d1 += __shfl_xor(d1, o); }
        float inv0 = 1.f / (d0 + 1e-16f), inv1 = 1.f / (d1 + 1e-16f);
        acc = 0.f;
        for (int i = beg; i < end; i++) {
            int s = csr[i];
            float e, wgt;
            if (lane < 32) { e = als[s * 2 + 0] + ad0; e = e > 0.f ? e : 0.2f * e; wgt = expf(e - m0) * inv0; }
            else           { e = als[s * 2 + 1] + ad1; e = e > 0.f ? e : 0.2f * e; wgt = expf(e - m1) * inv1; }
            acc += wgt * xw[(size_t)s * 64 + lane];
        }
    }
    // epilogue of GAT0: bias + ELU + residual (x1 stays in registers)
    float x1v = acc + b[lane];
    x1v = x1v > 0.f ? x1v : expm1f(x1v);
    x1v += xres[(size_t)node * 64 + lane];
    // GAT1 projection via shuffles: lane<32 -> W1 col j, lane>=32 -> Wres1 col j
    int j = lane & 31;
    const float* Wp = (lane < 32) ? W1 : Wres1;
    float pacc = 0.f;
#pragma unroll
    for (int k = 0; k < 64; k++) {
        float xv = __shfl(x1v, k);
        pacc += xv * Wp[k * 32 + j];
    }
    if (lane < 32) xw1[(size_t)node * 32 + j]   = pacc;
    else           xres1[(size_t)node * 32 + j] = pacc;
    float ps = (lane < 32) ? pacc * as1[j]  : 0.f;
    float pd = (lane < 32) ? pacc * ad1v[j] : 0.f;
    for (int o = 16; o; o >>= 1) {
        ps += __shfl_down(ps, o, 32);
        pd += __shfl_down(pd, o, 32);
    }
    if (lane == 0) { als1[node] = ps; ald1[node] = pd; }
}

// ---------------- GAT layer 1 gather -> x2 ----------------
__global__ __launch_bounds__(256) void k_gat1(const float* __restrict__ xw1,   // [N,32]
                                              const float* __restrict__ xres1, // [N,32]
                                              const float* __restrict__ als1,  // [N]
                                              const float* __restrict__ ald1,  // [N]
                                              const int* __restrict__ offs, const int* __restrict__ csr,
                                              const float* __restrict__ b,     // [32]
                                              float* __restrict__ x2) {
    int wave = threadIdx.x >> 6, lane = threadIdx.x & 63;
    int node = blockIdx.x * 4 + wave;
    if (node >= NNODES) return;
    int beg = offs[node], end = offs[node + 1];
    int deg = end - beg;
    float adv = ald1[node];
    int ch = lane & 31, half = lane >> 5;
    float aggr;
    if (deg <= 64) {
        int s = 0; float e = -INFINITY;
        if (lane < deg) {
            s = csr[beg + lane];
            e = als1[s] + adv; e = e > 0.f ? e : 0.2f * e;
        }
        float m = e;
        for (int o = 32; o; o >>= 1) m = fmaxf(m, __shfl_xor(m, o));
        float ex = (lane < deg) ? expf(e - m) : 0.f;
        float d = ex;
        for (int o = 32; o; o >>= 1) d += __shfl_xor(d, o);
        ex *= 1.f / (d + 1e-16f);
        // two edges per iteration: half 0 takes even i, half 1 takes odd i
        float acc = 0.f;
        for (int i = 0; i < deg; i += 2) {
            int i2 = (i + 1 < deg) ? i + 1 : i;
            int   sa = __shfl(s, i),  sb = __shfl(s, i2);
            float wa = __shfl(ex, i), wb = __shfl(ex, i2);
            if (i + 1 >= deg) wb = 0.f;
            int   sm = half ? sb : sa;
            float wm = half ? wb : wa;
            acc += wm * xw1[(size_t)sm * 32 + ch];
        }
        acc += __shfl_xor(acc, 32);
        aggr = acc;
    } else {
        float m = -INFINITY;
        for (int i = beg + lane; i < end; i += 64) {
            float e = als1[csr[i]] + adv; e = e > 0.f ? e : 0.2f * e;
            m = fmaxf(m, e);
        }
        for (int o = 32; o; o >>= 1) m = fmaxf(m, __shfl_xor(m, o));
        float d = 0.f;
        for (int i = beg + lane; i < end; i += 64) {
            float e = als1[csr[i]] + adv; e = e > 0.f ? e : 0.2f * e;
            d += expf(e - m);
        }
        for (int o = 32; o; o >>= 1) d += __shfl_xor(d, o);
        float inv = 1.f / (d + 1e-16f);
        float acc = 0.f;
        for (int i = beg; i < end; i++) {
            int s = csr[i];
            float e = als1[s] + adv; e = e > 0.f ? e : 0.2f * e;
            float wgt = expf(e - m) * inv;
            acc += wgt * xw1[(size_t)s * 32 + ch];   // both halves compute same; only lane<32 stores
        }
        aggr = acc;
    }
    if (lane < 32) {
        float v = aggr + b[ch];
        v = v > 0.f ? v : expm1f(v);
        x2[(size_t)node * 32 + ch] = v + xres1[(size_t)node * 32 + ch];
    }
}

// ---------------- fused GRU0 + GRU1, NPW nodes per wave, transposed weights ----------------
// ZH: h0_in and h1_in are implicit zeros (t==0)
template <bool ZH>
__global__ __launch_bounds__(256) void k_gru01(const float* __restrict__ x2,   // [N,32]
                                               const float* __restrict__ h0in, // [N,64]
                                               const float* __restrict__ h1in, // [N,64]
                                               const float* __restrict__ WiT0, // [32,192]
                                               const float* __restrict__ WhT0, // [64,192]
                                               const float* __restrict__ WiT1, // [64,192]
                                               const float* __restrict__ WhT1, // [64,192]
                                               const float* __restrict__ bi0, const float* __restrict__ bh0,
                                               const float* __restrict__ bi1, const float* __restrict__ bh1,
                                               float* __restrict__ h0out, float* __restrict__ h1out) {
    int wave = threadIdx.x >> 6, lane = threadIdx.x & 63;
    int node0 = (blockIdx.x * 4 + wave) * NPW;
    if (node0 >= NNODES) return;
    int ncl[NPW];
#pragma unroll
    for (int n = 0; n < NPW; n++) ncl[n] = min(node0 + n, NNODES - 1);

    float gr[NPW], gz[NPW], gn[NPW], hrr[NPW], hz[NPW], hn[NPW];
    {
        float bir = bi0[lane], biz = bi0[64 + lane], bin_ = bi0[128 + lane];
        float bhr = bh0[lane], bhz = bh0[64 + lane], bhn = bh0[128 + lane];
#pragma unroll
        for (int n = 0; n < NPW; n++) {
            gr[n] = bir; gz[n] = biz; gn[n] = bin_;
            hrr[n] = bhr; hz[n] = bhz; hn[n] = bhn;
        }
    }
#pragma unroll 4
    for (int k = 0; k < 32; k++) {
        float wr = WiT0[k * 192 + lane];
        float wz = WiT0[k * 192 + 64 + lane];
        float wn = WiT0[k * 192 + 128 + lane];
#pragma unroll
        for (int n = 0; n < NPW; n++) {
            float xv = x2[(size_t)ncl[n] * 32 + k];
            gr[n] += xv * wr; gz[n] += xv * wz; gn[n] += xv * wn;
        }
    }
    if (!ZH) {
#pragma unroll 4
        for (int k = 0; k < 64; k++) {
            float wr = WhT0[k * 192 + lane];
            float wz = WhT0[k * 192 + 64 + lane];
            float wn = WhT0[k * 192 + 128 + lane];
#pragma unroll
            for (int n = 0; n < NPW; n++) {
                float hv = h0in[(size_t)ncl[n] * 64 + k];
                hrr[n] += hv * wr; hz[n] += hv * wz; hn[n] += hv * wn;
            }
        }
    }
    float h0new[NPW];
#pragma unroll
    for (int n = 0; n < NPW; n++) {
        float hprev = ZH ? 0.f : h0in[(size_t)ncl[n] * 64 + lane];
        float r = 1.f / (1.f + expf(-(gr[n] + hrr[n])));
        float z = 1.f / (1.f + expf(-(gz[n] + hz[n])));
        float nn = tanhf(gn[n] + r * hn[n]);
        h0new[n] = (1.f - z) * nn + z * hprev;
        if (node0 + n < NNODES) h0out[(size_t)(node0 + n) * 64 + lane] = h0new[n];
    }
    // ---- GRU1: x = h0new (in registers, broadcast by shuffle), h = h1in ----
    {
        float bir = bi1[lane], biz = bi1[64 + lane], bin_ = bi1[128 + lane];
        float bhr = bh1[lane], bhz = bh1[64 + lane], bhn = bh1[128 + lane];
#pragma unroll
        for (int n = 0; n < NPW; n++) {
            gr[n] = bir; gz[n] = biz; gn[n] = bin_;
            hrr[n] = bhr; hz[n] = bhz; hn[n] = bhn;
        }
    }
#pragma unroll 2
    for (int k = 0; k < 64; k++) {
        float wir = WiT1[k * 192 + lane];
        float wiz = WiT1[k * 192 + 64 + lane];
        float win = WiT1[k * 192 + 128 + lane];
#pragma unroll
        for (int n = 0; n < NPW; n++) {
            float xv = __shfl(h0new[n], k);
            gr[n] += xv * wir; gz[n] += xv * wiz; gn[n] += xv * win;
        }
        if (!ZH) {
            float whr = WhT1[k * 192 + lane];
            float whz = WhT1[k * 192 + 64 + lane];
            float whn = WhT1[k * 192 + 128 + lane];
#pragma unroll
            for (int n = 0; n < NPW; n++) {
                float hv = h1in[(size_t)ncl[n] * 64 + k];
                hrr[n] += hv * whr; hz[n] += hv * whz; hn[n] += hv * whn;
            }
        }
    }
#pragma unroll
    for (int n = 0; n < NPW; n++) {
        float hprev = ZH ? 0.f : h1in[(size_t)ncl[n] * 64 + lane];
        float r = 1.f / (1.f + expf(-(gr[n] + hrr[n])));
        float z = 1.f / (1.f + expf(-(gz[n] + hz[n])));
        float nn = tanhf(gn[n] + r * hn[n]);
        float hv = (1.f - z) * nn + z * hprev;
        if (node0 + n < NNODES) h1out[(size_t)(node0 + n) * 64 + lane] = hv;
    }
}

// ---------------- MLP head: relu(h1@fc1+b) @ fc2 + b ----------------
__global__ __launch_bounds__(256) void k_head(const float* __restrict__ h1,
                                              const float* __restrict__ fc1W, // [64,32]
                                              const float* __restrict__ fc1b, // [32]
                                              const float* __restrict__ fc2W, // [32]
                                              const float* __restrict__ fc2b, // [1]
                                              float* __restrict__ out) {
    int wave = threadIdx.x >> 6, lane = threadIdx.x & 63;
    int node = blockIdx.x * 4 + wave;
    if (node >= NNODES) return;
    const float* hr = h1 + (size_t)node * 64;
    float v = 0.f;
    if (lane < 32) {
        float a = fc1b[lane];
#pragma unroll
        for (int k = 0; k < 64; k++) a += hr[k] * fc1W[k * 32 + lane];
        a = fmaxf(a, 0.f);
        v = a * fc2W[lane];
    }
    for (int off = 32; off; off >>= 1) v += __shfl_down(v, off);
    if (lane == 0) out[node] = v + fc2b[0];
}

extern "C" void kernel_launch(void* const* d_in, const int* in_sizes, int n_in,
                              void* d_out, int out_size, void* d_ws, size_t ws_size,
                              hipStream_t stream) {
    const float* x_seq   = (const float*)d_in[0];
    const int*   ei      = (const int*)d_in[1];
    const float* gat0_W  = (const float*)d_in[2];
    const float* gat0_as = (const float*)d_in[3];
    const float* gat0_ad = (const float*)d_in[4];
    const float* gat0_b  = (const float*)d_in[5];
    const float* res0_W  = (const float*)d_in[6];
    const float* gat1_W  = (const float*)d_in[7];
    const float* gat1_as = (const float*)d_in[8];
    const float* gat1_ad = (const float*)d_in[9];
    const float* gat1_b  = (const float*)d_in[10];
    const float* res1_W  = (const float*)d_in[11];
    const float* gru0_Wi = (const float*)d_in[12];
    const float* gru0_Wh = (const float*)d_in[13];
    const float* gru0_bi = (const float*)d_in[14];
    const float* gru0_bh = (const float*)d_in[15];
    const float* gru1_Wi = (const float*)d_in[16];
    const float* gru1_Wh = (const float*)d_in[17];
    const float* gru1_bi = (const float*)d_in[18];
    const float* gru1_bh = (const float*)d_in[19];
    const float* fc1_W   = (const float*)d_in[20];
    const float* fc1_b   = (const float*)d_in[21];
    const float* fc2_W   = (const float*)d_in[22];
    const float* fc2_b   = (const float*)d_in[23];
    float* out = (float*)d_out;

    char* w = (char*)d_ws;
    size_t off = 0;
    auto take = [&](size_t bytes) { size_t r = off; off += (bytes + 255) & ~(size_t)255; return r; };
    const size_t N = NNODES;
    int*   counts = (int*)(w + take(N * 4));
    int*   cursor = (int*)(w + take(N * 4));
    int*   offs   = (int*)(w + take((N + 1) * 4));
    int*   csr    = (int*)(w + take((size_t)ETOT * 4));
    float* xw0    = (float*)(w + take(N * 64 * 4));
    float* xres0  = (float*)(w + take(N * 64 * 4));
    float* als0   = (float*)(w + take(N * 2 * 4));
    float* ald0   = (float*)(w + take(N * 2 * 4));
    float* xw1    = (float*)(w + take(N * 32 * 4));
    float* xres1  = (float*)(w + take(N * 32 * 4));
    float* als1   = (float*)(w + take(N * 4));
    float* ald1   = (float*)(w + take(N * 4));
    float* x2     = (float*)(w + take(N * 32 * 4));
    float* h0a    = (float*)(w + take(N * 64 * 4));
    float* h0b    = (float*)(w + take(N * 64 * 4));
    float* h1a    = (float*)(w + take(N * 64 * 4));
    float* h1b    = (float*)(w + take(N * 64 * 4));
    float* wiT0   = (float*)(w + take(32 * 192 * 4));
    float* whT0   = (float*)(w + take(64 * 192 * 4));
    float* wiT1   = (float*)(w + take(64 * 192 * 4));
    float* whT1   = (float*)(w + take(64 * 192 * 4));

    // CSR build + weight transpose (once per launch; ws re-poisoned each call)
    hipMemsetAsync(counts, 0, N * 4, stream);
    hipMemsetAsync(cursor, 0, N * 4, stream);
    const int egrid = (ETOT + 255) / 256;
    k_count<<<egrid, 256, 0, stream>>>(ei, counts);
    k_scan<<<1, 1024, 0, stream>>>(counts, offs);
    k_fill<<<egrid, 256, 0, stream>>>(ei, offs, cursor, csr);
    const int ttot = 32 * 192 + 3 * 64 * 192;
    k_transpose<<<(ttot + 255) / 256, 256, 0, stream>>>(gru0_Wi, gru0_Wh, gru1_Wi, gru1_Wh,
                                                        wiT0, whT0, wiT1, whT1);

    const int ngrid = (NNODES + 3) / 4;
    const int ggrid = (NNODES + 4 * NPW - 1) / (4 * NPW);
    float *h0_in = h0a, *h0_out = h0b, *h1_in = h1a, *h1_out = h1b;
    for (int t = 0; t < T_STEPS; t++) {
        const float* xt = x_seq + (size_t)t * N * F_IN;
        k_mm0<<<ngrid, 256, 0, stream>>>(xt, gat0_W, res0_W, gat0_as, gat0_ad, xw0, xres0, als0, ald0);
        k_gat0<<<ngrid, 256, 0, stream>>>(xw0, xres0, als0, ald0, offs, csr, gat0_b,
                                          gat1_W, res1_W, gat1_as, gat1_ad,
                                          xw1, xres1, als1, ald1);
        k_gat1<<<ngrid, 256, 0, stream>>>(xw1, xres1, als1, ald1, offs, csr, gat1_b, x2);
        if (t == 0)
            k_gru01<true><<<ggrid, 256, 0, stream>>>(x2, h0_in, h1_in, wiT0, whT0, wiT1, whT1,
                                                     gru0_bi, gru0_bh, gru1_bi, gru1_bh, h0_out, h1_out);
        else
            k_gru01<false><<<ggrid, 256, 0, stream>>>(x2, h0_in, h1_in, wiT0, whT0, wiT1, whT1,
                                                      gru0_bi, gru0_bh, gru1_bi, gru1_bh, h0_out, h1_out);
        float* tmp;
        tmp = h0_in; h0_in = h0_out; h0_out = tmp;
        tmp = h1_in; h1_in = h1_out; h1_out = tmp;
    }
    k_head<<<ngrid, 256, 0, stream>>>(h1_in, fc1_W, fc1_b, fc2_W, fc2_b, out);
}

// Round 4
// 504.556 us; speedup vs baseline: 3.4924x; 1.1972x over previous
//
#include <hip/hip_runtime.h>
#include <hip/hip_bf16.h>
#include <math.h>

#define T_STEPS 5
#define NNODES  10000
#define F_IN    16
#define NEDGES  160000
#define ETOT    (NEDGES + NNODES)   // + self loops
#define NPW     2                   // nodes per wave in GRU kernel (10000 % (4*NPW) == 0)

// ---------------- CSR build ----------------
__global__ __launch_bounds__(256) void k_count(const int* __restrict__ ei, int* __restrict__ counts) {
    int idx = blockIdx.x * 256 + threadIdx.x;
    if (idx >= ETOT) return;
    int dst = (idx < NEDGES) ? ei[NEDGES + idx] : (idx - NEDGES);
    atomicAdd(&counts[dst], 1);
}

__global__ __launch_bounds__(1024) void k_scan(const int* __restrict__ counts, int* __restrict__ offs) {
    __shared__ int ssum[1024];
    int t = threadIdx.x;
    const int chunk = (NNODES + 1023) / 1024;
    int start = t * chunk, end = min(start + chunk, NNODES);
    int s = 0;
    for (int i = start; i < end; i++) s += counts[i];
    ssum[t] = s;
    __syncthreads();
    for (int off = 1; off < 1024; off <<= 1) {
        int v = (t >= off) ? ssum[t - off] : 0;
        __syncthreads();
        ssum[t] += v;
        __syncthreads();
    }
    int excl = (t == 0) ? 0 : ssum[t - 1];
    for (int i = start; i < end; i++) { offs[i] = excl; excl += counts[i]; }
    if (t == 1023) offs[NNODES] = ssum[1023];
}

__global__ __launch_bounds__(256) void k_fill(const int* __restrict__ ei, const int* __restrict__ offs,
                                              int* __restrict__ cursor, int* __restrict__ csr) {
    int idx = blockIdx.x * 256 + threadIdx.x;
    if (idx >= ETOT) return;
    int src, dst;
    if (idx < NEDGES) { src = ei[idx]; dst = ei[NEDGES + idx]; }
    else              { src = dst = idx - NEDGES; }
    int p = atomicAdd(&cursor[dst], 1);
    csr[offs[dst] + p] = src;
}

// ---------------- one-time weight transpose for GRU cells ----------------
// WiT[k*192 + r] = Wi[r*K + k]; WhT[k*192 + r] = Wh[r*64 + k]
__global__ __launch_bounds__(256) void k_transpose(const float* __restrict__ Wi0, const float* __restrict__ Wh0,
                                                   const float* __restrict__ Wi1, const float* __restrict__ Wh1,
                                                   float* __restrict__ WiT0, float* __restrict__ WhT0,
                                                   float* __restrict__ WiT1, float* __restrict__ WhT1) {
    int idx = blockIdx.x * 256 + threadIdx.x;
    if (idx < 32 * 192) {
        int k = idx / 192, r = idx % 192;
        WiT0[idx] = Wi0[r * 32 + k];
        return;
    }
    idx -= 32 * 192;
    if (idx < 64 * 192) {
        int k = idx / 192, r = idx % 192;
        WhT0[idx] = Wh0[r * 64 + k];
        return;
    }
    idx -= 64 * 192;
    if (idx < 64 * 192) {
        int k = idx / 192, r = idx % 192;
        WiT1[idx] = Wi1[r * 64 + k];
        return;
    }
    idx -= 64 * 192;
    if (idx < 64 * 192) {
        int k = idx / 192, r = idx % 192;
        WhT1[idx] = Wh1[r * 64 + k];
    }
}

// ---------------- GAT layer 0 projections (16 -> 64 twice) + attn logits ----------------
__global__ __launch_bounds__(256) void k_mm0(const float* __restrict__ x,      // [N,16]
                                             const float* __restrict__ W,     // [16,64]
                                             const float* __restrict__ Wres,  // [16,64]
                                             const float* __restrict__ asrc,  // [64]
                                             const float* __restrict__ adst,  // [64]
                                             float* __restrict__ xw, float* __restrict__ xres,
                                             float* __restrict__ als, float* __restrict__ ald) {
    int wave = threadIdx.x >> 6, lane = threadIdx.x & 63;
    int node = blockIdx.x * 4 + wave;
    if (node >= NNODES) return;
    const float* xr = x + (size_t)node * F_IN;
    float xreg[F_IN];
#pragma unroll
    for (int k = 0; k < F_IN; k++) xreg[k] = xr[k];
    float acc = 0.f, accr = 0.f;
#pragma unroll
    for (int k = 0; k < F_IN; k++) {
        acc  += xreg[k] * W[k * 64 + lane];
        accr += xreg[k] * Wres[k * 64 + lane];
    }
    xw[(size_t)node * 64 + lane]   = acc;
    xres[(size_t)node * 64 + lane] = accr;
    float ps = acc * asrc[lane], pd = acc * adst[lane];
    for (int off = 16; off; off >>= 1) {
        ps += __shfl_down(ps, off, 32);
        pd += __shfl_down(pd, off, 32);
    }
    if ((lane & 31) == 0) {
        int h = lane >> 5;
        als[node * 2 + h] = ps;
        ald[node * 2 + h] = pd;
    }
}

// ---------------- fused: GAT0 gather+softmax+ELU+residual, then GAT1 projection ----------------
__global__ __launch_bounds__(256) void k_gat0(const float* __restrict__ xw,   // [N,64]
                                              const float* __restrict__ xres, // [N,64]
                                              const float* __restrict__ als,  // [N,2]
                                              const float* __restrict__ ald,  // [N,2]
                                              const int* __restrict__ offs, const int* __restrict__ csr,
                                              const float* __restrict__ b,    // [64]
                                              const float* __restrict__ W1,   // [64,32]
                                              const float* __restrict__ Wres1,// [64,32]
                                              const float* __restrict__ as1,  // [32]
                                              const float* __restrict__ ad1v, // [32]
                                              float* __restrict__ xw1, float* __restrict__ xres1,
                                              float* __restrict__ als1, float* __restrict__ ald1) {
    int wave = threadIdx.x >> 6, lane = threadIdx.x & 63;
    int node = blockIdx.x * 4 + wave;
    if (node >= NNODES) return;
    int beg = offs[node], end = offs[node + 1];
    int deg = end - beg;
    float ad0 = ald[node * 2 + 0], ad1 = ald[node * 2 + 1];
    float acc;
    if (deg <= 64) {
        // one edge per lane, logits in registers
        int s = 0; float e0 = -INFINITY, e1 = -INFINITY;
        if (lane < deg) {
            s = csr[beg + lane];
            e0 = als[s * 2 + 0] + ad0; e0 = e0 > 0.f ? e0 : 0.2f * e0;
            e1 = als[s * 2 + 1] + ad1; e1 = e1 > 0.f ? e1 : 0.2f * e1;
        }
        float m0 = e0, m1 = e1;
        for (int o = 32; o; o >>= 1) {
            m0 = fmaxf(m0, __shfl_xor(m0, o));
            m1 = fmaxf(m1, __shfl_xor(m1, o));
        }
        float ex0 = (lane < deg) ? expf(e0 - m0) : 0.f;
        float ex1 = (lane < deg) ? expf(e1 - m1) : 0.f;
        float d0 = ex0, d1 = ex1;
        for (int o = 32; o; o >>= 1) {
            d0 += __shfl_xor(d0, o);
            d1 += __shfl_xor(d1, o);
        }
        ex0 *= 1.f / (d0 + 1e-16f);
        ex1 *= 1.f / (d1 + 1e-16f);
        // aggregation: lane = channel (head = lane>>5), unrolled over edges
        float a0 = 0.f, a1 = 0.f, a2 = 0.f, a3 = 0.f;
        int i = 0;
        for (; i + 4 <= deg; i += 4) {
            int   s0 = __shfl(s, i),     s1 = __shfl(s, i + 1), s2 = __shfl(s, i + 2), s3 = __shfl(s, i + 3);
            float u0 = __shfl(ex0, i),   v0 = __shfl(ex1, i);
            float u1 = __shfl(ex0, i+1), v1 = __shfl(ex1, i+1);
            float u2 = __shfl(ex0, i+2), v2 = __shfl(ex1, i+2);
            float u3 = __shfl(ex0, i+3), v3 = __shfl(ex1, i+3);
            a0 += (lane < 32 ? u0 : v0) * xw[(size_t)s0 * 64 + lane];
            a1 += (lane < 32 ? u1 : v1) * xw[(size_t)s1 * 64 + lane];
            a2 += (lane < 32 ? u2 : v2) * xw[(size_t)s2 * 64 + lane];
            a3 += (lane < 32 ? u3 : v3) * xw[(size_t)s3 * 64 + lane];
        }
        for (; i < deg; i++) {
            int s0 = __shfl(s, i);
            float u = __shfl(ex0, i), v = __shfl(ex1, i);
            a0 += (lane < 32 ? u : v) * xw[(size_t)s0 * 64 + lane];
        }
        acc = (a0 + a1) + (a2 + a3);
    } else {
        // general fallback: 3-pass
        float m0 = -INFINITY, m1 = -INFINITY;
        for (int i = beg + lane; i < end; i += 64) {
            int s = csr[i];
            float e0 = als[s * 2 + 0] + ad0; e0 = e0 > 0.f ? e0 : 0.2f * e0;
            float e1 = als[s * 2 + 1] + ad1; e1 = e1 > 0.f ? e1 : 0.2f * e1;
            m0 = fmaxf(m0, e0); m1 = fmaxf(m1, e1);
        }
        for (int o = 32; o; o >>= 1) {
            m0 = fmaxf(m0, __shfl_xor(m0, o));
            m1 = fmaxf(m1, __shfl_xor(m1, o));
        }
        float d0 = 0.f, d1 = 0.f;
        for (int i = beg + lane; i < end; i += 64) {
            int s = csr[i];
            float e0 = als[s * 2 + 0] + ad0; e0 = e0 > 0.f ? e0 : 0.2f * e0;
            float e1 = als[s * 2 + 1] + ad1; e1 = e1 > 0.f ? e1 : 0.2f * e1;
            d0 += expf(e0 - m0); d1 += expf(e1 - m1);
        }
        for (int o = 32; o; o >>= 1) { d0 += __shfl_xor(d0, o); d1 += __shfl_xor(d1, o); }
        float inv0 = 1.f / (d0 + 1e-16f), inv1 = 1.f / (d1 + 1e-16f);
        acc = 0.f;
        for (int i = beg; i < end; i++) {
            int s = csr[i];
            float e, wgt;
            if (lane < 32) { e = als[s * 2 + 0] + ad0; e = e > 0.f ? e : 0.2f * e; wgt = expf(e - m0) * inv0; }
            else           { e = als[s * 2 + 1] + ad1; e = e > 0.f ? e : 0.2f * e; wgt = expf(e - m1) * inv1; }
            acc += wgt * xw[(size_t)s * 64 + lane];
        }
    }
    // epilogue of GAT0: bias + ELU + residual (x1 stays in registers)
    float x1v = acc + b[lane];
    x1v = x1v > 0.f ? x1v : expm1f(x1v);
    x1v += xres[(size_t)node * 64 + lane];
    // GAT1 projection via shuffles: lane<32 -> W1 col j, lane>=32 -> Wres1 col j
    int j = lane & 31;
    const float* Wp = (lane < 32) ? W1 : Wres1;
    float pacc = 0.f;
#pragma unroll
    for (int k = 0; k < 64; k++) {
        float xv = __shfl(x1v, k);
        pacc += xv * Wp[k * 32 + j];
    }
    if (lane < 32) xw1[(size_t)node * 32 + j]   = pacc;
    else           xres1[(size_t)node * 32 + j] = pacc;
    float ps = (lane < 32) ? pacc * as1[j]  : 0.f;
    float pd = (lane < 32) ? pacc * ad1v[j] : 0.f;
    for (int o = 16; o; o >>= 1) {
        ps += __shfl_down(ps, o, 32);
        pd += __shfl_down(pd, o, 32);
    }
    if (lane == 0) { als1[node] = ps; ald1[node] = pd; }
}

// ---------------- GAT layer 1 gather -> x2 ----------------
__global__ __launch_bounds__(256) void k_gat1(const float* __restrict__ xw1,   // [N,32]
                                              const float* __restrict__ xres1, // [N,32]
                                              const float* __restrict__ als1,  // [N]
                                              const float* __restrict__ ald1,  // [N]
                                              const int* __restrict__ offs, const int* __restrict__ csr,
                                              const float* __restrict__ b,     // [32]
                                              float* __restrict__ x2) {
    int wave = threadIdx.x >> 6, lane = threadIdx.x & 63;
    int node = blockIdx.x * 4 + wave;
    if (node >= NNODES) return;
    int beg = offs[node], end = offs[node + 1];
    int deg = end - beg;
    float adv = ald1[node];
    int ch = lane & 31, half = lane >> 5;
    float aggr;
    if (deg <= 64) {
        int s = 0; float e = -INFINITY;
        if (lane < deg) {
            s = csr[beg + lane];
            e = als1[s] + adv; e = e > 0.f ? e : 0.2f * e;
        }
        float m = e;
        for (int o = 32; o; o >>= 1) m = fmaxf(m, __shfl_xor(m, o));
        float ex = (lane < deg) ? expf(e - m) : 0.f;
        float d = ex;
        for (int o = 32; o; o >>= 1) d += __shfl_xor(d, o);
        ex *= 1.f / (d + 1e-16f);
        // two edges per iteration: half 0 takes even i, half 1 takes odd i
        float acc = 0.f;
        for (int i = 0; i < deg; i += 2) {
            int i2 = (i + 1 < deg) ? i + 1 : i;
            int   sa = __shfl(s, i),  sb = __shfl(s, i2);
            float wa = __shfl(ex, i), wb = __shfl(ex, i2);
            if (i + 1 >= deg) wb = 0.f;
            int   sm = half ? sb : sa;
            float wm = half ? wb : wa;
            acc += wm * xw1[(size_t)sm * 32 + ch];
        }
        acc += __shfl_xor(acc, 32);
        aggr = acc;
    } else {
        float m = -INFINITY;
        for (int i = beg + lane; i < end; i += 64) {
            float e = als1[csr[i]] + adv; e = e > 0.f ? e : 0.2f * e;
            m = fmaxf(m, e);
        }
        for (int o = 32; o; o >>= 1) m = fmaxf(m, __shfl_xor(m, o));
        float d = 0.f;
        for (int i = beg + lane; i < end; i += 64) {
            float e = als1[csr[i]] + adv; e = e > 0.f ? e : 0.2f * e;
            d += expf(e - m);
        }
        for (int o = 32; o; o >>= 1) d += __shfl_xor(d, o);
        float inv = 1.f / (d + 1e-16f);
        float acc = 0.f;
        for (int i = beg; i < end; i++) {
            int s = csr[i];
            float e = als1[s] + adv; e = e > 0.f ? e : 0.2f * e;
            float wgt = expf(e - m) * inv;
            acc += wgt * xw1[(size_t)s * 32 + ch];   // both halves compute same; only lane<32 stores
        }
        aggr = acc;
    }
    if (lane < 32) {
        float v = aggr + b[ch];
        v = v > 0.f ? v : expm1f(v);
        x2[(size_t)node * 32 + ch] = v + xres1[(size_t)node * 32 + ch];
    }
}

// ---------------- fused GRU0 + GRU1, NPW=2 nodes per wave, transposed weights ----------------
// x/h rows staged in registers once (coalesced), broadcast per-k via __shfl.
// ZH: h0_in and h1_in are implicit zeros (t==0)
template <bool ZH>
__global__ __launch_bounds__(256) void k_gru01(const float* __restrict__ x2,   // [N,32]
                                               const float* __restrict__ h0in, // [N,64]
                                               const float* __restrict__ h1in, // [N,64]
                                               const float* __restrict__ WiT0, // [32,192]
                                               const float* __restrict__ WhT0, // [64,192]
                                               const float* __restrict__ WiT1, // [64,192]
                                               const float* __restrict__ WhT1, // [64,192]
                                               const float* __restrict__ bi0, const float* __restrict__ bh0,
                                               const float* __restrict__ bi1, const float* __restrict__ bh1,
                                               float* __restrict__ h0out, float* __restrict__ h1out) {
    int wave = threadIdx.x >> 6, lane = threadIdx.x & 63;
    int node0 = (blockIdx.x * 4 + wave) * NPW;   // NNODES % (4*NPW) == 0: no bounds checks

    // stage inputs: x2 rows of node0,node0+1 = 64 contiguous floats; h rows = 2x64
    float x2v = x2[(size_t)node0 * 32 + lane];
    float h0v0 = 0.f, h0v1 = 0.f, h1v0 = 0.f, h1v1 = 0.f;
    if (!ZH) {
        h0v0 = h0in[(size_t)node0 * 64 + lane];
        h0v1 = h0in[(size_t)node0 * 64 + 64 + lane];
        h1v0 = h1in[(size_t)node0 * 64 + lane];
        h1v1 = h1in[(size_t)node0 * 64 + 64 + lane];
    }

    float gr0, gz0, gn0, gr1, gz1, gn1;   // gi accumulators (node0, node1)
    float hr0, hz0, hn0, hr1, hz1, hn1;   // gh accumulators
    gr0 = gr1 = bi0[lane]; gz0 = gz1 = bi0[64 + lane]; gn0 = gn1 = bi0[128 + lane];
    hr0 = hr1 = bh0[lane]; hz0 = hz1 = bh0[64 + lane]; hn0 = hn1 = bh0[128 + lane];

#pragma unroll 8
    for (int k = 0; k < 32; k++) {
        float wr = WiT0[k * 192 + lane];
        float wz = WiT0[k * 192 + 64 + lane];
        float wn = WiT0[k * 192 + 128 + lane];
        float xa = __shfl(x2v, k);
        float xb = __shfl(x2v, 32 + k);
        gr0 += xa * wr; gz0 += xa * wz; gn0 += xa * wn;
        gr1 += xb * wr; gz1 += xb * wz; gn1 += xb * wn;
    }
    if (!ZH) {
#pragma unroll 8
        for (int k = 0; k < 64; k++) {
            float wr = WhT0[k * 192 + lane];
            float wz = WhT0[k * 192 + 64 + lane];
            float wn = WhT0[k * 192 + 128 + lane];
            float ha = __shfl(h0v0, k);
            float hb = __shfl(h0v1, k);
            hr0 += ha * wr; hz0 += ha * wz; hn0 += ha * wn;
            hr1 += hb * wr; hz1 += hb * wz; hn1 += hb * wn;
        }
    }
    float h0new0, h0new1;
    {
        float r0 = 1.f / (1.f + expf(-(gr0 + hr0)));
        float z0 = 1.f / (1.f + expf(-(gz0 + hz0)));
        float n0 = tanhf(gn0 + r0 * hn0);
        h0new0 = (1.f - z0) * n0 + z0 * h0v0;
        float r1 = 1.f / (1.f + expf(-(gr1 + hr1)));
        float z1 = 1.f / (1.f + expf(-(gz1 + hz1)));
        float n1 = tanhf(gn1 + r1 * hn1);
        h0new1 = (1.f - z1) * n1 + z1 * h0v1;
        h0out[(size_t)node0 * 64 + lane]      = h0new0;
        h0out[(size_t)node0 * 64 + 64 + lane] = h0new1;
    }

    // ---- GRU1: x = h0new (registers), h = h1 rows ----
    gr0 = gr1 = bi1[lane]; gz0 = gz1 = bi1[64 + lane]; gn0 = gn1 = bi1[128 + lane];
    hr0 = hr1 = bh1[lane]; hz0 = hz1 = bh1[64 + lane]; hn0 = hn1 = bh1[128 + lane];
#pragma unroll 4
    for (int k = 0; k < 64; k++) {
        float wir = WiT1[k * 192 + lane];
        float wiz = WiT1[k * 192 + 64 + lane];
        float win = WiT1[k * 192 + 128 + lane];
        float xa = __shfl(h0new0, k);
        float xb = __shfl(h0new1, k);
        gr0 += xa * wir; gz0 += xa * wiz; gn0 += xa * win;
        gr1 += xb * wir; gz1 += xb * wiz; gn1 += xb * win;
        if (!ZH) {
            float whr = WhT1[k * 192 + lane];
            float whz = WhT1[k * 192 + 64 + lane];
            float whn = WhT1[k * 192 + 128 + lane];
            float ha = __shfl(h1v0, k);
            float hb = __shfl(h1v1, k);
            hr0 += ha * whr; hz0 += ha * whz; hn0 += ha * whn;
            hr1 += hb * whr; hz1 += hb * whz; hn1 += hb * whn;
        }
    }
    {
        float r0 = 1.f / (1.f + expf(-(gr0 + hr0)));
        float z0 = 1.f / (1.f + expf(-(gz0 + hz0)));
        float n0 = tanhf(gn0 + r0 * hn0);
        h1out[(size_t)node0 * 64 + lane] = (1.f - z0) * n0 + z0 * h1v0;
        float r1 = 1.f / (1.f + expf(-(gr1 + hr1)));
        float z1 = 1.f / (1.f + expf(-(gz1 + hz1)));
        float n1 = tanhf(gn1 + r1 * hn1);
        h1out[(size_t)node0 * 64 + 64 + lane] = (1.f - z1) * n1 + z1 * h1v1;
    }
}

// ---------------- MLP head: relu(h1@fc1+b) @ fc2 + b ----------------
__global__ __launch_bounds__(256) void k_head(const float* __restrict__ h1,
                                              const float* __restrict__ fc1W, // [64,32]
                                              const float* __restrict__ fc1b, // [32]
                                              const float* __restrict__ fc2W, // [32]
                                              const float* __restrict__ fc2b, // [1]
                                              float* __restrict__ out) {
    int wave = threadIdx.x >> 6, lane = threadIdx.x & 63;
    int node = blockIdx.x * 4 + wave;
    if (node >= NNODES) return;
    const float* hr = h1 + (size_t)node * 64;
    float v = 0.f;
    if (lane < 32) {
        float a = fc1b[lane];
#pragma unroll
        for (int k = 0; k < 64; k++) a += hr[k] * fc1W[k * 32 + lane];
        a = fmaxf(a, 0.f);
        v = a * fc2W[lane];
    }
    for (int off = 32; off; off >>= 1) v += __shfl_down(v, off);
    if (lane == 0) out[node] = v + fc2b[0];
}

extern "C" void kernel_launch(void* const* d_in, const int* in_sizes, int n_in,
                              void* d_out, int out_size, void* d_ws, size_t ws_size,
                              hipStream_t stream) {
    const float* x_seq   = (const float*)d_in[0];
    const int*   ei      = (const int*)d_in[1];
    const float* gat0_W  = (const float*)d_in[2];
    const float* gat0_as = (const float*)d_in[3];
    const float* gat0_ad = (const float*)d_in[4];
    const float* gat0_b  = (const float*)d_in[5];
    const float* res0_W  = (const float*)d_in[6];
    const float* gat1_W  = (const float*)d_in[7];
    const float* gat1_as = (const float*)d_in[8];
    const float* gat1_ad = (const float*)d_in[9];
    const float* gat1_b  = (const float*)d_in[10];
    const float* res1_W  = (const float*)d_in[11];
    const float* gru0_Wi = (const float*)d_in[12];
    const float* gru0_Wh = (const float*)d_in[13];
    const float* gru0_bi = (const float*)d_in[14];
    const float* gru0_bh = (const float*)d_in[15];
    const float* gru1_Wi = (const float*)d_in[16];
    const float* gru1_Wh = (const float*)d_in[17];
    const float* gru1_bi = (const float*)d_in[18];
    const float* gru1_bh = (const float*)d_in[19];
    const float* fc1_W   = (const float*)d_in[20];
    const float* fc1_b   = (const float*)d_in[21];
    const float* fc2_W   = (const float*)d_in[22];
    const float* fc2_b   = (const float*)d_in[23];
    float* out = (float*)d_out;

    char* w = (char*)d_ws;
    size_t off = 0;
    auto take = [&](size_t bytes) { size_t r = off; off += (bytes + 255) & ~(size_t)255; return r; };
    const size_t N = NNODES;
    int*   counts = (int*)(w + take(N * 4));
    int*   cursor = (int*)(w + take(N * 4));
    int*   offs   = (int*)(w + take((N + 1) * 4));
    int*   csr    = (int*)(w + take((size_t)ETOT * 4));
    float* xw0    = (float*)(w + take(N * 64 * 4));
    float* xres0  = (float*)(w + take(N * 64 * 4));
    float* als0   = (float*)(w + take(N * 2 * 4));
    float* ald0   = (float*)(w + take(N * 2 * 4));
    float* xw1    = (float*)(w + take(N * 32 * 4));
    float* xres1  = (float*)(w + take(N * 32 * 4));
    float* als1   = (float*)(w + take(N * 4));
    float* ald1   = (float*)(w + take(N * 4));
    float* x2     = (float*)(w + take(N * 32 * 4));
    float* h0a    = (float*)(w + take(N * 64 * 4));
    float* h0b    = (float*)(w + take(N * 64 * 4));
    float* h1a    = (float*)(w + take(N * 64 * 4));
    float* h1b    = (float*)(w + take(N * 64 * 4));
    float* wiT0   = (float*)(w + take(32 * 192 * 4));
    float* whT0   = (float*)(w + take(64 * 192 * 4));
    float* wiT1   = (float*)(w + take(64 * 192 * 4));
    float* whT1   = (float*)(w + take(64 * 192 * 4));

    // CSR build + weight transpose (once per launch; ws re-poisoned each call)
    hipMemsetAsync(counts, 0, N * 4, stream);
    hipMemsetAsync(cursor, 0, N * 4, stream);
    const int egrid = (ETOT + 255) / 256;
    k_count<<<egrid, 256, 0, stream>>>(ei, counts);
    k_scan<<<1, 1024, 0, stream>>>(counts, offs);
    k_fill<<<egrid, 256, 0, stream>>>(ei, offs, cursor, csr);
    const int ttot = 32 * 192 + 3 * 64 * 192;
    k_transpose<<<(ttot + 255) / 256, 256, 0, stream>>>(gru0_Wi, gru0_Wh, gru1_Wi, gru1_Wh,
                                                        wiT0, whT0, wiT1, whT1);

    const int ngrid = (NNODES + 3) / 4;
    const int ggrid = NNODES / (4 * NPW);   // exact: 10000 / 8 = 1250
    float *h0_in = h0a, *h0_out = h0b, *h1_in = h1a, *h1_out = h1b;
    for (int t = 0; t < T_STEPS; t++) {
        const float* xt = x_seq + (size_t)t * N * F_IN;
        k_mm0<<<ngrid, 256, 0, stream>>>(xt, gat0_W, res0_W, gat0_as, gat0_ad, xw0, xres0, als0, ald0);
        k_gat0<<<ngrid, 256, 0, stream>>>(xw0, xres0, als0, ald0, offs, csr, gat0_b,
                                          gat1_W, res1_W, gat1_as, gat1_ad,
                                          xw1, xres1, als1, ald1);
        k_gat1<<<ngrid, 256, 0, stream>>>(xw1, xres1, als1, ald1, offs, csr, gat1_b, x2);
        if (t == 0)
            k_gru01<true><<<ggrid, 256, 0, stream>>>(x2, h0_in, h1_in, wiT0, whT0, wiT1, whT1,
                                                     gru0_bi, gru0_bh, gru1_bi, gru1_bh, h0_out, h1_out);
        else
            k_gru01<false><<<ggrid, 256, 0, stream>>>(x2, h0_in, h1_in, wiT0, whT0, wiT1, whT1,
                                                      gru0_bi, gru0_bh, gru1_bi, gru1_bh, h0_out, h1_out);
        float* tmp;
        tmp = h0_in; h0_in = h0_out; h0_out = tmp;
        tmp = h1_in; h1_in = h1_out; h1_out = tmp;
    }
    k_head<<<ngrid, 256, 0, stream>>>(h1_in, fc1_W, fc1_b, fc2_W, fc2_b, out);
}

// Round 5
// 444.906 us; speedup vs baseline: 3.9606x; 1.1341x over previous
//
#include <hip/hip_runtime.h>
#include <hip/hip_bf16.h>
#include <math.h>

#define T_STEPS 5
#define NNODES  10000
#define NM      (T_STEPS * NNODES)   // 50000 node-instances (t,n)
#define F_IN    16
#define NEDGES  160000
#define ETOT    (NEDGES + NNODES)    // + self loops

// ---------------- CSR build ----------------
__global__ __launch_bounds__(256) void k_count(const int* __restrict__ ei, int* __restrict__ counts) {
    int idx = blockIdx.x * 256 + threadIdx.x;
    if (idx >= ETOT) return;
    int dst = (idx < NEDGES) ? ei[NEDGES + idx] : (idx - NEDGES);
    atomicAdd(&counts[dst], 1);
}

__global__ __launch_bounds__(1024) void k_scan(const int* __restrict__ counts, int* __restrict__ offs) {
    __shared__ int ssum[1024];
    int t = threadIdx.x;
    const int chunk = (NNODES + 1023) / 1024;
    int start = t * chunk, end = min(start + chunk, NNODES);
    int s = 0;
    for (int i = start; i < end; i++) s += counts[i];
    ssum[t] = s;
    __syncthreads();
    for (int off = 1; off < 1024; off <<= 1) {
        int v = (t >= off) ? ssum[t - off] : 0;
        __syncthreads();
        ssum[t] += v;
        __syncthreads();
    }
    int excl = (t == 0) ? 0 : ssum[t - 1];
    for (int i = start; i < end; i++) { offs[i] = excl; excl += counts[i]; }
    if (t == 1023) offs[NNODES] = ssum[1023];
}

__global__ __launch_bounds__(256) void k_fill(const int* __restrict__ ei, const int* __restrict__ offs,
                                              int* __restrict__ cursor, int* __restrict__ csr) {
    int idx = blockIdx.x * 256 + threadIdx.x;
    if (idx >= ETOT) return;
    int src, dst;
    if (idx < NEDGES) { src = ei[idx]; dst = ei[NEDGES + idx]; }
    else              { src = dst = idx - NEDGES; }
    int p = atomicAdd(&cursor[dst], 1);
    csr[offs[dst] + p] = src;
}

// ---------------- one-time weight transpose for GRU cells ----------------
// WiT[k*192 + r] = Wi[r*K + k]; WhT[k*192 + r] = Wh[r*64 + k]
__global__ __launch_bounds__(256) void k_transpose(const float* __restrict__ Wi0, const float* __restrict__ Wh0,
                                                   const float* __restrict__ Wi1, const float* __restrict__ Wh1,
                                                   float* __restrict__ WiT0, float* __restrict__ WhT0,
                                                   float* __restrict__ WiT1, float* __restrict__ WhT1) {
    int idx = blockIdx.x * 256 + threadIdx.x;
    if (idx < 32 * 192) {
        int k = idx / 192, r = idx % 192;
        WiT0[idx] = Wi0[r * 32 + k];
        return;
    }
    idx -= 32 * 192;
    if (idx < 64 * 192) {
        int k = idx / 192, r = idx % 192;
        WhT0[idx] = Wh0[r * 64 + k];
        return;
    }
    idx -= 64 * 192;
    if (idx < 64 * 192) {
        int k = idx / 192, r = idx % 192;
        WiT1[idx] = Wi1[r * 64 + k];
        return;
    }
    idx -= 64 * 192;
    if (idx < 64 * 192) {
        int k = idx / 192, r = idx % 192;
        WhT1[idx] = Wh1[r * 64 + k];
    }
}

// ---------------- GAT0 projections for ALL timesteps: [5N,16] -> xw/xres [5N,64], logits ----------------
__global__ __launch_bounds__(256) void k_mm0_all(const float* __restrict__ x,      // [5N,16]
                                                 const float* __restrict__ W,     // [16,64]
                                                 const float* __restrict__ Wres,  // [16,64]
                                                 const float* __restrict__ asrc,  // [64]
                                                 const float* __restrict__ adst,  // [64]
                                                 float* __restrict__ xw, float* __restrict__ xres,
                                                 float* __restrict__ als, float* __restrict__ ald) {
    int wave = threadIdx.x >> 6, lane = threadIdx.x & 63;
    int m = blockIdx.x * 4 + wave;
    if (m >= NM) return;
    const float* xr = x + (size_t)m * F_IN;
    float xreg[F_IN];
#pragma unroll
    for (int k = 0; k < F_IN; k++) xreg[k] = xr[k];
    float acc = 0.f, accr = 0.f;
#pragma unroll
    for (int k = 0; k < F_IN; k++) {
        acc  += xreg[k] * W[k * 64 + lane];
        accr += xreg[k] * Wres[k * 64 + lane];
    }
    xw[(size_t)m * 64 + lane]   = acc;
    xres[(size_t)m * 64 + lane] = accr;
    float ps = acc * asrc[lane], pd = acc * adst[lane];
    for (int off = 16; off; off >>= 1) {
        ps += __shfl_down(ps, off, 32);
        pd += __shfl_down(pd, off, 32);
    }
    if ((lane & 31) == 0) {
        int h = lane >> 5;
        als[m * 2 + h] = ps;
        ald[m * 2 + h] = pd;
    }
}

// ---------------- fused GAT0 gather + ELU + residual + GAT1 projection, ALL timesteps ----------------
__global__ __launch_bounds__(256) void k_gat0_all(const float* __restrict__ xw,   // [5N,64]
                                                  const float* __restrict__ xres, // [5N,64]
                                                  const float* __restrict__ als,  // [5N,2]
                                                  const float* __restrict__ ald,  // [5N,2]
                                                  const int* __restrict__ offs, const int* __restrict__ csr,
                                                  const float* __restrict__ b,    // [64]
                                                  const float* __restrict__ W1,   // [64,32]
                                                  const float* __restrict__ Wres1,// [64,32]
                                                  const float* __restrict__ as1,  // [32]
                                                  const float* __restrict__ ad1v, // [32]
                                                  float* __restrict__ xw1, float* __restrict__ xres1,
                                                  float* __restrict__ als1, float* __restrict__ ald1) {
    int wave = threadIdx.x >> 6, lane = threadIdx.x & 63;
    int m = blockIdx.x * 4 + wave;
    if (m >= NM) return;
    int t = m / NNODES;            // magic-mul div by constant
    int node = m - t * NNODES;
    int base = t * NNODES;         // instance offset for source rows
    int beg = offs[node], end = offs[node + 1];
    int deg = end - beg;
    float ad0 = ald[m * 2 + 0], ad1 = ald[m * 2 + 1];
    float acc;
    if (deg <= 64) {
        int s = 0; float e0 = -INFINITY, e1 = -INFINITY;
        if (lane < deg) {
            s = base + csr[beg + lane];
            e0 = als[s * 2 + 0] + ad0; e0 = e0 > 0.f ? e0 : 0.2f * e0;
            e1 = als[s * 2 + 1] + ad1; e1 = e1 > 0.f ? e1 : 0.2f * e1;
        }
        float m0 = e0, m1 = e1;
        for (int o = 32; o; o >>= 1) {
            m0 = fmaxf(m0, __shfl_xor(m0, o));
            m1 = fmaxf(m1, __shfl_xor(m1, o));
        }
        float ex0 = (lane < deg) ? expf(e0 - m0) : 0.f;
        float ex1 = (lane < deg) ? expf(e1 - m1) : 0.f;
        float d0 = ex0, d1 = ex1;
        for (int o = 32; o; o >>= 1) {
            d0 += __shfl_xor(d0, o);
            d1 += __shfl_xor(d1, o);
        }
        ex0 *= 1.f / (d0 + 1e-16f);
        ex1 *= 1.f / (d1 + 1e-16f);
        float a0 = 0.f, a1 = 0.f, a2 = 0.f, a3 = 0.f;
        int i = 0;
        for (; i + 4 <= deg; i += 4) {
            int   s0 = __shfl(s, i),     s1 = __shfl(s, i + 1), s2 = __shfl(s, i + 2), s3 = __shfl(s, i + 3);
            float u0 = __shfl(ex0, i),   v0 = __shfl(ex1, i);
            float u1 = __shfl(ex0, i+1), v1 = __shfl(ex1, i+1);
            float u2 = __shfl(ex0, i+2), v2 = __shfl(ex1, i+2);
            float u3 = __shfl(ex0, i+3), v3 = __shfl(ex1, i+3);
            a0 += (lane < 32 ? u0 : v0) * xw[(size_t)s0 * 64 + lane];
            a1 += (lane < 32 ? u1 : v1) * xw[(size_t)s1 * 64 + lane];
            a2 += (lane < 32 ? u2 : v2) * xw[(size_t)s2 * 64 + lane];
            a3 += (lane < 32 ? u3 : v3) * xw[(size_t)s3 * 64 + lane];
        }
        for (; i < deg; i++) {
            int s0 = __shfl(s, i);
            float u = __shfl(ex0, i), v = __shfl(ex1, i);
            a0 += (lane < 32 ? u : v) * xw[(size_t)s0 * 64 + lane];
        }
        acc = (a0 + a1) + (a2 + a3);
    } else {
        float m0 = -INFINITY, m1 = -INFINITY;
        for (int i = beg + lane; i < end; i += 64) {
            int s = base + csr[i];
            float e0 = als[s * 2 + 0] + ad0; e0 = e0 > 0.f ? e0 : 0.2f * e0;
            float e1 = als[s * 2 + 1] + ad1; e1 = e1 > 0.f ? e1 : 0.2f * e1;
            m0 = fmaxf(m0, e0); m1 = fmaxf(m1, e1);
        }
        for (int o = 32; o; o >>= 1) {
            m0 = fmaxf(m0, __shfl_xor(m0, o));
            m1 = fmaxf(m1, __shfl_xor(m1, o));
        }
        float d0 = 0.f, d1 = 0.f;
        for (int i = beg + lane; i < end; i += 64) {
            int s = base + csr[i];
            float e0 = als[s * 2 + 0] + ad0; e0 = e0 > 0.f ? e0 : 0.2f * e0;
            float e1 = als[s * 2 + 1] + ad1; e1 = e1 > 0.f ? e1 : 0.2f * e1;
            d0 += expf(e0 - m0); d1 += expf(e1 - m1);
        }
        for (int o = 32; o; o >>= 1) { d0 += __shfl_xor(d0, o); d1 += __shfl_xor(d1, o); }
        float inv0 = 1.f / (d0 + 1e-16f), inv1 = 1.f / (d1 + 1e-16f);
        acc = 0.f;
        for (int i = beg; i < end; i++) {
            int s = base + csr[i];
            float e, wgt;
            if (lane < 32) { e = als[s * 2 + 0] + ad0; e = e > 0.f ? e : 0.2f * e; wgt = expf(e - m0) * inv0; }
            else           { e = als[s * 2 + 1] + ad1; e = e > 0.f ? e : 0.2f * e; wgt = expf(e - m1) * inv1; }
            acc += wgt * xw[(size_t)s * 64 + lane];
        }
    }
    float x1v = acc + b[lane];
    x1v = x1v > 0.f ? x1v : expm1f(x1v);
    x1v += xres[(size_t)m * 64 + lane];
    // GAT1 projection: lane<32 -> W1 col j, lane>=32 -> Wres1 col j
    int j = lane & 31;
    const float* Wp = (lane < 32) ? W1 : Wres1;
    float pacc = 0.f;
#pragma unroll
    for (int k = 0; k < 64; k++) {
        float xv = __shfl(x1v, k);
        pacc += xv * Wp[k * 32 + j];
    }
    if (lane < 32) xw1[(size_t)m * 32 + j]   = pacc;
    else           xres1[(size_t)m * 32 + j] = pacc;
    float ps = (lane < 32) ? pacc * as1[j]  : 0.f;
    float pd = (lane < 32) ? pacc * ad1v[j] : 0.f;
    for (int o = 16; o; o >>= 1) {
        ps += __shfl_down(ps, o, 32);
        pd += __shfl_down(pd, o, 32);
    }
    if (lane == 0) { als1[m] = ps; ald1[m] = pd; }
}

// ---------------- GAT1 gather -> x2, ALL timesteps ----------------
__global__ __launch_bounds__(256) void k_gat1_all(const float* __restrict__ xw1,   // [5N,32]
                                                  const float* __restrict__ xres1, // [5N,32]
                                                  const float* __restrict__ als1,  // [5N]
                                                  const float* __restrict__ ald1,  // [5N]
                                                  const int* __restrict__ offs, const int* __restrict__ csr,
                                                  const float* __restrict__ b,     // [32]
                                                  float* __restrict__ x2) {
    int wave = threadIdx.x >> 6, lane = threadIdx.x & 63;
    int m = blockIdx.x * 4 + wave;
    if (m >= NM) return;
    int t = m / NNODES;
    int node = m - t * NNODES;
    int base = t * NNODES;
    int beg = offs[node], end = offs[node + 1];
    int deg = end - beg;
    float adv = ald1[m];
    int ch = lane & 31, half = lane >> 5;
    float aggr;
    if (deg <= 64) {
        int s = 0; float e = -INFINITY;
        if (lane < deg) {
            s = base + csr[beg + lane];
            e = als1[s] + adv; e = e > 0.f ? e : 0.2f * e;
        }
        float mx = e;
        for (int o = 32; o; o >>= 1) mx = fmaxf(mx, __shfl_xor(mx, o));
        float ex = (lane < deg) ? expf(e - mx) : 0.f;
        float d = ex;
        for (int o = 32; o; o >>= 1) d += __shfl_xor(d, o);
        ex *= 1.f / (d + 1e-16f);
        float acc = 0.f;
        for (int i = 0; i < deg; i += 2) {
            int i2 = (i + 1 < deg) ? i + 1 : i;
            int   sa = __shfl(s, i),  sb = __shfl(s, i2);
            float wa = __shfl(ex, i), wb = __shfl(ex, i2);
            if (i + 1 >= deg) wb = 0.f;
            int   sm = half ? sb : sa;
            float wm = half ? wb : wa;
            acc += wm * xw1[(size_t)sm * 32 + ch];
        }
        acc += __shfl_xor(acc, 32);
        aggr = acc;
    } else {
        float mx = -INFINITY;
        for (int i = beg + lane; i < end; i += 64) {
            float e = als1[base + csr[i]] + adv; e = e > 0.f ? e : 0.2f * e;
            mx = fmaxf(mx, e);
        }
        for (int o = 32; o; o >>= 1) mx = fmaxf(mx, __shfl_xor(mx, o));
        float d = 0.f;
        for (int i = beg + lane; i < end; i += 64) {
            float e = als1[base + csr[i]] + adv; e = e > 0.f ? e : 0.2f * e;
            d += expf(e - mx);
        }
        for (int o = 32; o; o >>= 1) d += __shfl_xor(d, o);
        float inv = 1.f / (d + 1e-16f);
        float acc = 0.f;
        for (int i = beg; i < end; i++) {
            int s = base + csr[i];
            float e = als1[s] + adv; e = e > 0.f ? e : 0.2f * e;
            float wgt = expf(e - mx) * inv;
            acc += wgt * xw1[(size_t)s * 32 + ch];
        }
        aggr = acc;
    }
    if (lane < 32) {
        float v = aggr + b[ch];
        v = v > 0.f ? v : expm1f(v);
        x2[(size_t)m * 32 + ch] = v + xres1[(size_t)m * 32 + ch];
    }
}

// ---------------- fused: 5-step GRU0+GRU1 chain + MLP head, 2 nodes per wave ----------------
// h-state lives in registers across all timesteps; only x2_all is read per step.
__global__ __launch_bounds__(256) void k_gruhead(const float* __restrict__ x2,   // [5N,32]
                                                 const float* __restrict__ WiT0, // [32,192]
                                                 const float* __restrict__ WhT0, // [64,192]
                                                 const float* __restrict__ WiT1, // [64,192]
                                                 const float* __restrict__ WhT1, // [64,192]
                                                 const float* __restrict__ bi0, const float* __restrict__ bh0,
                                                 const float* __restrict__ bi1, const float* __restrict__ bh1,
                                                 const float* __restrict__ fc1W, // [64,32]
                                                 const float* __restrict__ fc1b, // [32]
                                                 const float* __restrict__ fc2W, // [32]
                                                 const float* __restrict__ fc2b, // [1]
                                                 float* __restrict__ out) {
    int wave = threadIdx.x >> 6, lane = threadIdx.x & 63;
    int node0 = (blockIdx.x * 4 + wave) * 2;   // 10000 % 8 == 0: no bounds checks

    float bir0 = bi0[lane], biz0 = bi0[64 + lane], bin0 = bi0[128 + lane];
    float bhr0 = bh0[lane], bhz0 = bh0[64 + lane], bhn0 = bh0[128 + lane];
    float bir1 = bi1[lane], biz1 = bi1[64 + lane], bin1 = bi1[128 + lane];
    float bhr1 = bh1[lane], bhz1 = bh1[64 + lane], bhn1 = bh1[128 + lane];

    float h0v0 = 0.f, h0v1 = 0.f, h1v0 = 0.f, h1v1 = 0.f;   // lane = hidden ch

    for (int t = 0; t < T_STEPS; t++) {
        // x2 rows of node0,node0+1: 64 contiguous floats
        float x2v = x2[((size_t)t * NNODES + node0) * 32 + lane];

        float gr0 = bir0, gz0 = biz0, gn0 = bin0, gr1 = bir0, gz1 = biz0, gn1 = bin0;
        float hr0 = bhr0, hz0 = bhz0, hn0 = bhn0, hr1 = bhr0, hz1 = bhz0, hn1 = bhn0;
#pragma unroll 8
        for (int k = 0; k < 32; k++) {
            float wr = WiT0[k * 192 + lane];
            float wz = WiT0[k * 192 + 64 + lane];
            float wn = WiT0[k * 192 + 128 + lane];
            float xa = __shfl(x2v, k);
            float xb = __shfl(x2v, 32 + k);
            gr0 += xa * wr; gz0 += xa * wz; gn0 += xa * wn;
            gr1 += xb * wr; gz1 += xb * wz; gn1 += xb * wn;
        }
#pragma unroll 8
        for (int k = 0; k < 64; k++) {
            float wr = WhT0[k * 192 + lane];
            float wz = WhT0[k * 192 + 64 + lane];
            float wn = WhT0[k * 192 + 128 + lane];
            float ha = __shfl(h0v0, k);
            float hb = __shfl(h0v1, k);
            hr0 += ha * wr; hz0 += ha * wz; hn0 += ha * wn;
            hr1 += hb * wr; hz1 += hb * wz; hn1 += hb * wn;
        }
        {
            float r0 = 1.f / (1.f + expf(-(gr0 + hr0)));
            float z0 = 1.f / (1.f + expf(-(gz0 + hz0)));
            float n0 = tanhf(gn0 + r0 * hn0);
            h0v0 = (1.f - z0) * n0 + z0 * h0v0;
            float r1 = 1.f / (1.f + expf(-(gr1 + hr1)));
            float z1 = 1.f / (1.f + expf(-(gz1 + hz1)));
            float n1 = tanhf(gn1 + r1 * hn1);
            h0v1 = (1.f - z1) * n1 + z1 * h0v1;
        }
        // GRU1: x = h0 (registers), h = h1
        gr0 = bir1; gz0 = biz1; gn0 = bin1; gr1 = bir1; gz1 = biz1; gn1 = bin1;
        hr0 = bhr1; hz0 = bhz1; hn0 = bhn1; hr1 = bhr1; hz1 = bhz1; hn1 = bhn1;
#pragma unroll 4
        for (int k = 0; k < 64; k++) {
            float wir = WiT1[k * 192 + lane];
            float wiz = WiT1[k * 192 + 64 + lane];
            float win = WiT1[k * 192 + 128 + lane];
            float xa = __shfl(h0v0, k);
            float xb = __shfl(h0v1, k);
            gr0 += xa * wir; gz0 += xa * wiz; gn0 += xa * win;
            gr1 += xb * wir; gz1 += xb * wiz; gn1 += xb * win;
            float whr = WhT1[k * 192 + lane];
            float whz = WhT1[k * 192 + 64 + lane];
            float whn = WhT1[k * 192 + 128 + lane];
            float ha = __shfl(h1v0, k);
            float hb = __shfl(h1v1, k);
            hr0 += ha * whr; hz0 += ha * whz; hn0 += ha * whn;
            hr1 += hb * whr; hz1 += hb * whz; hn1 += hb * whn;
        }
        {
            float r0 = 1.f / (1.f + expf(-(gr0 + hr0)));
            float z0 = 1.f / (1.f + expf(-(gz0 + hz0)));
            float n0 = tanhf(gn0 + r0 * hn0);
            h1v0 = (1.f - z0) * n0 + z0 * h1v0;
            float r1 = 1.f / (1.f + expf(-(gr1 + hr1)));
            float z1 = 1.f / (1.f + expf(-(gz1 + hz1)));
            float n1 = tanhf(gn1 + r1 * hn1);
            h1v1 = (1.f - z1) * n1 + z1 * h1v1;
        }
    }

    // MLP head: lanes 0..31 -> node0, lanes 32..63 -> node0+1
    int j = lane & 31, half = lane >> 5;
    float a = fc1b[j];
#pragma unroll
    for (int k = 0; k < 64; k++) {
        float h_a = __shfl(h1v0, k);
        float h_b = __shfl(h1v1, k);
        a += (half ? h_b : h_a) * fc1W[k * 32 + j];
    }
    a = fmaxf(a, 0.f);
    float v = a * fc2W[j];
    for (int o = 16; o; o >>= 1) v += __shfl_down(v, o, 32);
    if ((lane & 31) == 0) out[node0 + half] = v + fc2b[0];
}

extern "C" void kernel_launch(void* const* d_in, const int* in_sizes, int n_in,
                              void* d_out, int out_size, void* d_ws, size_t ws_size,
                              hipStream_t stream) {
    const float* x_seq   = (const float*)d_in[0];
    const int*   ei      = (const int*)d_in[1];
    const float* gat0_W  = (const float*)d_in[2];
    const float* gat0_as = (const float*)d_in[3];
    const float* gat0_ad = (const float*)d_in[4];
    const float* gat0_b  = (const float*)d_in[5];
    const float* res0_W  = (const float*)d_in[6];
    const float* gat1_W  = (const float*)d_in[7];
    const float* gat1_as = (const float*)d_in[8];
    const float* gat1_ad = (const float*)d_in[9];
    const float* gat1_b  = (const float*)d_in[10];
    const float* res1_W  = (const float*)d_in[11];
    const float* gru0_Wi = (const float*)d_in[12];
    const float* gru0_Wh = (const float*)d_in[13];
    const float* gru0_bi = (const float*)d_in[14];
    const float* gru0_bh = (const float*)d_in[15];
    const float* gru1_Wi = (const float*)d_in[16];
    const float* gru1_Wh = (const float*)d_in[17];
    const float* gru1_bi = (const float*)d_in[18];
    const float* gru1_bh = (const float*)d_in[19];
    const float* fc1_W   = (const float*)d_in[20];
    const float* fc1_b   = (const float*)d_in[21];
    const float* fc2_W   = (const float*)d_in[22];
    const float* fc2_b   = (const float*)d_in[23];
    float* out = (float*)d_out;

    char* w = (char*)d_ws;
    size_t off = 0;
    auto take = [&](size_t bytes) { size_t r = off; off += (bytes + 255) & ~(size_t)255; return r; };
    const size_t N = NNODES, M = NM;
    int*   counts = (int*)(w + take(N * 4));
    int*   cursor = (int*)(w + take(N * 4));
    int*   offs   = (int*)(w + take((N + 1) * 4));
    int*   csr    = (int*)(w + take((size_t)ETOT * 4));
    float* xw0    = (float*)(w + take(M * 64 * 4));
    float* xres0  = (float*)(w + take(M * 64 * 4));
    float* als0   = (float*)(w + take(M * 2 * 4));
    float* ald0   = (float*)(w + take(M * 2 * 4));
    float* xw1    = (float*)(w + take(M * 32 * 4));
    float* xres1  = (float*)(w + take(M * 32 * 4));
    float* als1   = (float*)(w + take(M * 4));
    float* ald1   = (float*)(w + take(M * 4));
    float* x2     = (float*)(w + take(M * 32 * 4));
    float* wiT0   = (float*)(w + take(32 * 192 * 4));
    float* whT0   = (float*)(w + take(64 * 192 * 4));
    float* wiT1   = (float*)(w + take(64 * 192 * 4));
    float* whT1   = (float*)(w + take(64 * 192 * 4));

    // CSR build + weight transpose (once per launch; ws re-poisoned each call)
    hipMemsetAsync(counts, 0, N * 4, stream);
    hipMemsetAsync(cursor, 0, N * 4, stream);
    const int egrid = (ETOT + 255) / 256;
    k_count<<<egrid, 256, 0, stream>>>(ei, counts);
    k_scan<<<1, 1024, 0, stream>>>(counts, offs);
    k_fill<<<egrid, 256, 0, stream>>>(ei, offs, cursor, csr);
    const int ttot = 32 * 192 + 3 * 64 * 192;
    k_transpose<<<(ttot + 255) / 256, 256, 0, stream>>>(gru0_Wi, gru0_Wh, gru1_Wi, gru1_Wh,
                                                        wiT0, whT0, wiT1, whT1);

    // Batched GAT phases over all 5 timesteps (independent of recurrence)
    const int mgrid = (NM + 3) / 4;   // 12500 blocks
    k_mm0_all<<<mgrid, 256, 0, stream>>>(x_seq, gat0_W, res0_W, gat0_as, gat0_ad, xw0, xres0, als0, ald0);
    k_gat0_all<<<mgrid, 256, 0, stream>>>(xw0, xres0, als0, ald0, offs, csr, gat0_b,
                                          gat1_W, res1_W, gat1_as, gat1_ad,
                                          xw1, xres1, als1, ald1);
    k_gat1_all<<<mgrid, 256, 0, stream>>>(xw1, xres1, als1, ald1, offs, csr, gat1_b, x2);

    // Recurrent chain + head, single kernel (per-node recurrence, h-state in registers)
    const int ggrid = NNODES / 8;     // 1250 blocks, 2 nodes/wave
    k_gruhead<<<ggrid, 256, 0, stream>>>(x2, wiT0, whT0, wiT1, whT1,
                                         gru0_bi, gru0_bh, gru1_bi, gru1_bh,
                                         fc1_W, fc1_b, fc2_W, fc2_b, out);
}

// Round 6
// 417.546 us; speedup vs baseline: 4.2201x; 1.0655x over previous
//
#include <hip/hip_runtime.h>
#include <hip/hip_bf16.h>
#include <math.h>

#define T_STEPS 5
#define NNODES  10000
#define NM      (T_STEPS * NNODES)   // 50000 node-instances (t,n)
#define F_IN    16
#define NEDGES  160000
#define ETOT    (NEDGES + NNODES)    // + self loops
#define GNPW    4                    // nodes per wave in GRU kernel (10000 % 16 == 0)

// SGPR broadcast: readlane (uniform index) instead of ds_bpermute shuffles
#define RL(v, k) __int_as_float(__builtin_amdgcn_readlane(__float_as_int(v), (k)))

// ---------------- CSR build ----------------
__global__ __launch_bounds__(256) void k_count(const int* __restrict__ ei, int* __restrict__ counts) {
    int idx = blockIdx.x * 256 + threadIdx.x;
    if (idx >= ETOT) return;
    int dst = (idx < NEDGES) ? ei[NEDGES + idx] : (idx - NEDGES);
    atomicAdd(&counts[dst], 1);
}

__global__ __launch_bounds__(1024) void k_scan(const int* __restrict__ counts, int* __restrict__ offs) {
    __shared__ int ssum[1024];
    int t = threadIdx.x;
    const int chunk = (NNODES + 1023) / 1024;
    int start = t * chunk, end = min(start + chunk, NNODES);
    int s = 0;
    for (int i = start; i < end; i++) s += counts[i];
    ssum[t] = s;
    __syncthreads();
    for (int off = 1; off < 1024; off <<= 1) {
        int v = (t >= off) ? ssum[t - off] : 0;
        __syncthreads();
        ssum[t] += v;
        __syncthreads();
    }
    int excl = (t == 0) ? 0 : ssum[t - 1];
    for (int i = start; i < end; i++) { offs[i] = excl; excl += counts[i]; }
    if (t == 1023) offs[NNODES] = ssum[1023];
}

__global__ __launch_bounds__(256) void k_fill(const int* __restrict__ ei, const int* __restrict__ offs,
                                              int* __restrict__ cursor, int* __restrict__ csr) {
    int idx = blockIdx.x * 256 + threadIdx.x;
    if (idx >= ETOT) return;
    int src, dst;
    if (idx < NEDGES) { src = ei[idx]; dst = ei[NEDGES + idx]; }
    else              { src = dst = idx - NEDGES; }
    int p = atomicAdd(&cursor[dst], 1);
    csr[offs[dst] + p] = src;
}

// ---------------- one-time weight transpose for GRU cells ----------------
// WiT[k*192 + r] = Wi[r*K + k]; WhT[k*192 + r] = Wh[r*64 + k]
__global__ __launch_bounds__(256) void k_transpose(const float* __restrict__ Wi0, const float* __restrict__ Wh0,
                                                   const float* __restrict__ Wi1, const float* __restrict__ Wh1,
                                                   float* __restrict__ WiT0, float* __restrict__ WhT0,
                                                   float* __restrict__ WiT1, float* __restrict__ WhT1) {
    int idx = blockIdx.x * 256 + threadIdx.x;
    if (idx < 32 * 192) {
        int k = idx / 192, r = idx % 192;
        WiT0[idx] = Wi0[r * 32 + k];
        return;
    }
    idx -= 32 * 192;
    if (idx < 64 * 192) {
        int k = idx / 192, r = idx % 192;
        WhT0[idx] = Wh0[r * 64 + k];
        return;
    }
    idx -= 64 * 192;
    if (idx < 64 * 192) {
        int k = idx / 192, r = idx % 192;
        WiT1[idx] = Wi1[r * 64 + k];
        return;
    }
    idx -= 64 * 192;
    if (idx < 64 * 192) {
        int k = idx / 192, r = idx % 192;
        WhT1[idx] = Wh1[r * 64 + k];
    }
}

// ---------------- GAT0 projections for ALL timesteps ----------------
__global__ __launch_bounds__(256) void k_mm0_all(const float* __restrict__ x,      // [5N,16]
                                                 const float* __restrict__ W,     // [16,64]
                                                 const float* __restrict__ Wres,  // [16,64]
                                                 const float* __restrict__ asrc,  // [64]
                                                 const float* __restrict__ adst,  // [64]
                                                 float* __restrict__ xw, float* __restrict__ xres,
                                                 float* __restrict__ als, float* __restrict__ ald) {
    int wave = threadIdx.x >> 6, lane = threadIdx.x & 63;
    int m = blockIdx.x * 4 + wave;
    if (m >= NM) return;
    const float* xr = x + (size_t)m * F_IN;
    float xreg[F_IN];
#pragma unroll
    for (int k = 0; k < F_IN; k++) xreg[k] = xr[k];
    float acc = 0.f, accr = 0.f;
#pragma unroll
    for (int k = 0; k < F_IN; k++) {
        acc  += xreg[k] * W[k * 64 + lane];
        accr += xreg[k] * Wres[k * 64 + lane];
    }
    xw[(size_t)m * 64 + lane]   = acc;
    xres[(size_t)m * 64 + lane] = accr;
    float ps = acc * asrc[lane], pd = acc * adst[lane];
    for (int off = 16; off; off >>= 1) {
        ps += __shfl_down(ps, off, 32);
        pd += __shfl_down(pd, off, 32);
    }
    if ((lane & 31) == 0) {
        int h = lane >> 5;
        als[m * 2 + h] = ps;
        ald[m * 2 + h] = pd;
    }
}

// ---------------- fused GAT0 gather + ELU + residual + GAT1 projection, ALL timesteps ----------------
__global__ __launch_bounds__(256) void k_gat0_all(const float* __restrict__ xw,   // [5N,64]
                                                  const float* __restrict__ xres, // [5N,64]
                                                  const float* __restrict__ als,  // [5N,2]
                                                  const float* __restrict__ ald,  // [5N,2]
                                                  const int* __restrict__ offs, const int* __restrict__ csr,
                                                  const float* __restrict__ b,    // [64]
                                                  const float* __restrict__ W1,   // [64,32]
                                                  const float* __restrict__ Wres1,// [64,32]
                                                  const float* __restrict__ as1,  // [32]
                                                  const float* __restrict__ ad1v, // [32]
                                                  float* __restrict__ xw1, float* __restrict__ xres1,
                                                  float* __restrict__ als1, float* __restrict__ ald1) {
    int wave = threadIdx.x >> 6, lane = threadIdx.x & 63;
    int m = blockIdx.x * 4 + wave;
    if (m >= NM) return;
    int t = m / NNODES;
    int node = m - t * NNODES;
    int base = t * NNODES;
    int beg = offs[node], end = offs[node + 1];
    int deg = end - beg;
    float ad0 = ald[m * 2 + 0], ad1 = ald[m * 2 + 1];
    float acc;
    if (deg <= 64) {
        int s = 0; float e0 = -INFINITY, e1 = -INFINITY;
        if (lane < deg) {
            s = base + csr[beg + lane];
            e0 = als[s * 2 + 0] + ad0; e0 = e0 > 0.f ? e0 : 0.2f * e0;
            e1 = als[s * 2 + 1] + ad1; e1 = e1 > 0.f ? e1 : 0.2f * e1;
        }
        float m0 = e0, m1 = e1;
        for (int o = 32; o; o >>= 1) {
            m0 = fmaxf(m0, __shfl_xor(m0, o));
            m1 = fmaxf(m1, __shfl_xor(m1, o));
        }
        float ex0 = (lane < deg) ? expf(e0 - m0) : 0.f;
        float ex1 = (lane < deg) ? expf(e1 - m1) : 0.f;
        float d0 = ex0, d1 = ex1;
        for (int o = 32; o; o >>= 1) {
            d0 += __shfl_xor(d0, o);
            d1 += __shfl_xor(d1, o);
        }
        ex0 *= 1.f / (d0 + 1e-16f);
        ex1 *= 1.f / (d1 + 1e-16f);
        float a0 = 0.f, a1 = 0.f, a2 = 0.f, a3 = 0.f;
        int i = 0;
        for (; i + 4 <= deg; i += 4) {
            int   s0 = __shfl(s, i),     s1 = __shfl(s, i + 1), s2 = __shfl(s, i + 2), s3 = __shfl(s, i + 3);
            float u0 = __shfl(ex0, i),   v0 = __shfl(ex1, i);
            float u1 = __shfl(ex0, i+1), v1 = __shfl(ex1, i+1);
            float u2 = __shfl(ex0, i+2), v2 = __shfl(ex1, i+2);
            float u3 = __shfl(ex0, i+3), v3 = __shfl(ex1, i+3);
            a0 += (lane < 32 ? u0 : v0) * xw[(size_t)s0 * 64 + lane];
            a1 += (lane < 32 ? u1 : v1) * xw[(size_t)s1 * 64 + lane];
            a2 += (lane < 32 ? u2 : v2) * xw[(size_t)s2 * 64 + lane];
            a3 += (lane < 32 ? u3 : v3) * xw[(size_t)s3 * 64 + lane];
        }
        for (; i < deg; i++) {
            int s0 = __shfl(s, i);
            float u = __shfl(ex0, i), v = __shfl(ex1, i);
            a0 += (lane < 32 ? u : v) * xw[(size_t)s0 * 64 + lane];
        }
        acc = (a0 + a1) + (a2 + a3);
    } else {
        float m0 = -INFINITY, m1 = -INFINITY;
        for (int i = beg + lane; i < end; i += 64) {
            int s = base + csr[i];
            float e0 = als[s * 2 + 0] + ad0; e0 = e0 > 0.f ? e0 : 0.2f * e0;
            float e1 = als[s * 2 + 1] + ad1; e1 = e1 > 0.f ? e1 : 0.2f * e1;
            m0 = fmaxf(m0, e0); m1 = fmaxf(m1, e1);
        }
        for (int o = 32; o; o >>= 1) {
            m0 = fmaxf(m0, __shfl_xor(m0, o));
            m1 = fmaxf(m1, __shfl_xor(m1, o));
        }
        float d0 = 0.f, d1 = 0.f;
        for (int i = beg + lane; i < end; i += 64) {
            int s = base + csr[i];
            float e0 = als[s * 2 + 0] + ad0; e0 = e0 > 0.f ? e0 : 0.2f * e0;
            float e1 = als[s * 2 + 1] + ad1; e1 = e1 > 0.f ? e1 : 0.2f * e1;
            d0 += expf(e0 - m0); d1 += expf(e1 - m1);
        }
        for (int o = 32; o; o >>= 1) { d0 += __shfl_xor(d0, o); d1 += __shfl_xor(d1, o); }
        float inv0 = 1.f / (d0 + 1e-16f), inv1 = 1.f / (d1 + 1e-16f);
        acc = 0.f;
        for (int i = beg; i < end; i++) {
            int s = base + csr[i];
            float e, wgt;
            if (lane < 32) { e = als[s * 2 + 0] + ad0; e = e > 0.f ? e : 0.2f * e; wgt = expf(e - m0) * inv0; }
            else           { e = als[s * 2 + 1] + ad1; e = e > 0.f ? e : 0.2f * e; wgt = expf(e - m1) * inv1; }
            acc += wgt * xw[(size_t)s * 64 + lane];
        }
    }
    float x1v = acc + b[lane];
    x1v = x1v > 0.f ? x1v : expm1f(x1v);
    x1v += xres[(size_t)m * 64 + lane];
    // GAT1 projection: readlane broadcasts (VALU) instead of ds_bpermute
    int j = lane & 31;
    const float* Wp = (lane < 32) ? W1 : Wres1;
    float pacc = 0.f;
#pragma unroll
    for (int k = 0; k < 64; k++) {
        float xv = RL(x1v, k);
        pacc += xv * Wp[k * 32 + j];
    }
    if (lane < 32) xw1[(size_t)m * 32 + j]   = pacc;
    else           xres1[(size_t)m * 32 + j] = pacc;
    float ps = (lane < 32) ? pacc * as1[j]  : 0.f;
    float pd = (lane < 32) ? pacc * ad1v[j] : 0.f;
    for (int o = 16; o; o >>= 1) {
        ps += __shfl_down(ps, o, 32);
        pd += __shfl_down(pd, o, 32);
    }
    if (lane == 0) { als1[m] = ps; ald1[m] = pd; }
}

// ---------------- GAT1 gather -> x2, ALL timesteps ----------------
__global__ __launch_bounds__(256) void k_gat1_all(const float* __restrict__ xw1,   // [5N,32]
                                                  const float* __restrict__ xres1, // [5N,32]
                                                  const float* __restrict__ als1,  // [5N]
                                                  const float* __restrict__ ald1,  // [5N]
                                                  const int* __restrict__ offs, const int* __restrict__ csr,
                                                  const float* __restrict__ b,     // [32]
                                                  float* __restrict__ x2) {
    int wave = threadIdx.x >> 6, lane = threadIdx.x & 63;
    int m = blockIdx.x * 4 + wave;
    if (m >= NM) return;
    int t = m / NNODES;
    int node = m - t * NNODES;
    int base = t * NNODES;
    int beg = offs[node], end = offs[node + 1];
    int deg = end - beg;
    float adv = ald1[m];
    int ch = lane & 31, half = lane >> 5;
    float aggr;
    if (deg <= 64) {
        int s = 0; float e = -INFINITY;
        if (lane < deg) {
            s = base + csr[beg + lane];
            e = als1[s] + adv; e = e > 0.f ? e : 0.2f * e;
        }
        float mx = e;
        for (int o = 32; o; o >>= 1) mx = fmaxf(mx, __shfl_xor(mx, o));
        float ex = (lane < deg) ? expf(e - mx) : 0.f;
        float d = ex;
        for (int o = 32; o; o >>= 1) d += __shfl_xor(d, o);
        ex *= 1.f / (d + 1e-16f);
        float acc = 0.f;
        for (int i = 0; i < deg; i += 2) {
            int i2 = (i + 1 < deg) ? i + 1 : i;
            int   sa = __shfl(s, i),  sb = __shfl(s, i2);
            float wa = __shfl(ex, i), wb = __shfl(ex, i2);
            if (i + 1 >= deg) wb = 0.f;
            int   sm = half ? sb : sa;
            float wm = half ? wb : wa;
            acc += wm * xw1[(size_t)sm * 32 + ch];
        }
        acc += __shfl_xor(acc, 32);
        aggr = acc;
    } else {
        float mx = -INFINITY;
        for (int i = beg + lane; i < end; i += 64) {
            float e = als1[base + csr[i]] + adv; e = e > 0.f ? e : 0.2f * e;
            mx = fmaxf(mx, e);
        }
        for (int o = 32; o; o >>= 1) mx = fmaxf(mx, __shfl_xor(mx, o));
        float d = 0.f;
        for (int i = beg + lane; i < end; i += 64) {
            float e = als1[base + csr[i]] + adv; e = e > 0.f ? e : 0.2f * e;
            d += expf(e - mx);
        }
        for (int o = 32; o; o >>= 1) d += __shfl_xor(d, o);
        float inv = 1.f / (d + 1e-16f);
        float acc = 0.f;
        for (int i = beg; i < end; i++) {
            int s = base + csr[i];
            float e = als1[s] + adv; e = e > 0.f ? e : 0.2f * e;
            float wgt = expf(e - mx) * inv;
            acc += wgt * xw1[(size_t)s * 32 + ch];
        }
        aggr = acc;
    }
    if (lane < 32) {
        float v = aggr + b[ch];
        v = v > 0.f ? v : expm1f(v);
        x2[(size_t)m * 32 + ch] = v + xres1[(size_t)m * 32 + ch];
    }
}

// ---------------- fused: 5-step GRU0+GRU1 chain + MLP head, 4 nodes/wave, readlane broadcasts ----------------
__global__ __launch_bounds__(256) void k_gruhead(const float* __restrict__ x2,   // [5N,32]
                                                 const float* __restrict__ WiT0, // [32,192]
                                                 const float* __restrict__ WhT0, // [64,192]
                                                 const float* __restrict__ WiT1, // [64,192]
                                                 const float* __restrict__ WhT1, // [64,192]
                                                 const float* __restrict__ bi0, const float* __restrict__ bh0,
                                                 const float* __restrict__ bi1, const float* __restrict__ bh1,
                                                 const float* __restrict__ fc1W, // [64,32]
                                                 const float* __restrict__ fc1b, // [32]
                                                 const float* __restrict__ fc2W, // [32]
                                                 const float* __restrict__ fc2b, // [1]
                                                 float* __restrict__ out) {
    int wave = threadIdx.x >> 6, lane = threadIdx.x & 63;
    int node0 = (blockIdx.x * 4 + wave) * GNPW;   // 10000 % 16 == 0: no bounds checks

    float bir0 = bi0[lane] + bh0[lane];           // r,z gate biases merge (gi+gh)
    float biz0 = bi0[64 + lane] + bh0[64 + lane];
    float bin0 = bi0[128 + lane], bhn0 = bh0[128 + lane];
    float bir1 = bi1[lane] + bh1[lane];
    float biz1 = bi1[64 + lane] + bh1[64 + lane];
    float bin1 = bi1[128 + lane], bhn1 = bh1[128 + lane];

    float h0[GNPW] = {0.f, 0.f, 0.f, 0.f};        // lane = hidden channel
    float h1[GNPW] = {0.f, 0.f, 0.f, 0.f};

    for (int t = 0; t < T_STEPS; t++) {
        // x2 rows for 4 nodes = 128 contiguous floats
        float xa = x2[((size_t)t * NNODES + node0) * 32 + lane];        // nodes 0,1
        float xb = x2[((size_t)t * NNODES + node0) * 32 + 64 + lane];   // nodes 2,3

        // ---- GRU0 ----
        float gr[GNPW], gz[GNPW], gin[GNPW], ghn[GNPW];
#pragma unroll
        for (int n = 0; n < GNPW; n++) { gr[n] = bir0; gz[n] = biz0; gin[n] = bin0; ghn[n] = bhn0; }
#pragma unroll 8
        for (int k = 0; k < 32; k++) {
            float wr = WiT0[k * 192 + lane];
            float wz = WiT0[k * 192 + 64 + lane];
            float wn = WiT0[k * 192 + 128 + lane];
            float xv[GNPW];
            xv[0] = RL(xa, k); xv[1] = RL(xa, 32 + k);
            xv[2] = RL(xb, k); xv[3] = RL(xb, 32 + k);
#pragma unroll
            for (int n = 0; n < GNPW; n++) {
                gr[n] += xv[n] * wr; gz[n] += xv[n] * wz; gin[n] += xv[n] * wn;
            }
        }
#pragma unroll 4
        for (int k = 0; k < 64; k++) {
            float wr = WhT0[k * 192 + lane];
            float wz = WhT0[k * 192 + 64 + lane];
            float wn = WhT0[k * 192 + 128 + lane];
#pragma unroll
            for (int n = 0; n < GNPW; n++) {
                float hv = RL(h0[n], k);
                gr[n] += hv * wr; gz[n] += hv * wz; ghn[n] += hv * wn;
            }
        }
#pragma unroll
        for (int n = 0; n < GNPW; n++) {
            float r = 1.f / (1.f + expf(-gr[n]));
            float z = 1.f / (1.f + expf(-gz[n]));
            float nn = tanhf(gin[n] + r * ghn[n]);
            h0[n] = (1.f - z) * nn + z * h0[n];
        }

        // ---- GRU1: x = h0 (registers), h = h1 ----
#pragma unroll
        for (int n = 0; n < GNPW; n++) { gr[n] = bir1; gz[n] = biz1; gin[n] = bin1; ghn[n] = bhn1; }
#pragma unroll 4
        for (int k = 0; k < 64; k++) {
            float wir = WiT1[k * 192 + lane];
            float wiz = WiT1[k * 192 + 64 + lane];
            float win = WiT1[k * 192 + 128 + lane];
            float whr = WhT1[k * 192 + lane];
            float whz = WhT1[k * 192 + 64 + lane];
            float whn = WhT1[k * 192 + 128 + lane];
#pragma unroll
            for (int n = 0; n < GNPW; n++) {
                float xv = RL(h0[n], k);
                float hv = RL(h1[n], k);
                gr[n] += xv * wir + hv * whr;
                gz[n] += xv * wiz + hv * whz;
                gin[n] += xv * win;
                ghn[n] += hv * whn;
            }
        }
#pragma unroll
        for (int n = 0; n < GNPW; n++) {
            float r = 1.f / (1.f + expf(-gr[n]));
            float z = 1.f / (1.f + expf(-gz[n]));
            float nn = tanhf(gin[n] + r * ghn[n]);
            h1[n] = (1.f - z) * nn + z * h1[n];
        }
    }

    // ---- MLP head: two passes of node-pairs; lanes 0-31 -> even node, 32-63 -> odd ----
    int j = lane & 31, half = lane >> 5;
#pragma unroll
    for (int p = 0; p < 2; p++) {
        float a = fc1b[j];
#pragma unroll
        for (int k = 0; k < 64; k++) {
            float he = RL(h1[2 * p], k);
            float ho = RL(h1[2 * p + 1], k);
            a += (half ? ho : he) * fc1W[k * 32 + j];
        }
        a = fmaxf(a, 0.f);
        float v = a * fc2W[j];
        for (int o = 16; o; o >>= 1) v += __shfl_down(v, o, 32);
        if ((lane & 31) == 0) out[node0 + 2 * p + half] = v + fc2b[0];
    }
}

extern "C" void kernel_launch(void* const* d_in, const int* in_sizes, int n_in,
                              void* d_out, int out_size, void* d_ws, size_t ws_size,
                              hipStream_t stream) {
    const float* x_seq   = (const float*)d_in[0];
    const int*   ei      = (const int*)d_in[1];
    const float* gat0_W  = (const float*)d_in[2];
    const float* gat0_as = (const float*)d_in[3];
    const float* gat0_ad = (const float*)d_in[4];
    const float* gat0_b  = (const float*)d_in[5];
    const float* res0_W  = (const float*)d_in[6];
    const float* gat1_W  = (const float*)d_in[7];
    const float* gat1_as = (const float*)d_in[8];
    const float* gat1_ad = (const float*)d_in[9];
    const float* gat1_b  = (const float*)d_in[10];
    const float* res1_W  = (const float*)d_in[11];
    const float* gru0_Wi = (const float*)d_in[12];
    const float* gru0_Wh = (const float*)d_in[13];
    const float* gru0_bi = (const float*)d_in[14];
    const float* gru0_bh = (const float*)d_in[15];
    const float* gru1_Wi = (const float*)d_in[16];
    const float* gru1_Wh = (const float*)d_in[17];
    const float* gru1_bi = (const float*)d_in[18];
    const float* gru1_bh = (const float*)d_in[19];
    const float* fc1_W   = (const float*)d_in[20];
    const float* fc1_b   = (const float*)d_in[21];
    const float* fc2_W   = (const float*)d_in[22];
    const float* fc2_b   = (const float*)d_in[23];
    float* out = (float*)d_out;

    char* w = (char*)d_ws;
    size_t off = 0;
    auto take = [&](size_t bytes) { size_t r = off; off += (bytes + 255) & ~(size_t)255; return r; };
    const size_t N = NNODES, M = NM;
    int*   counts = (int*)(w + take(N * 4));
    int*   cursor = (int*)(w + take(N * 4));
    int*   offs   = (int*)(w + take((N + 1) * 4));
    int*   csr    = (int*)(w + take((size_t)ETOT * 4));
    float* xw0    = (float*)(w + take(M * 64 * 4));
    float* xres0  = (float*)(w + take(M * 64 * 4));
    float* als0   = (float*)(w + take(M * 2 * 4));
    float* ald0   = (float*)(w + take(M * 2 * 4));
    float* xw1    = (float*)(w + take(M * 32 * 4));
    float* xres1  = (float*)(w + take(M * 32 * 4));
    float* als1   = (float*)(w + take(M * 4));
    float* ald1   = (float*)(w + take(M * 4));
    float* x2     = (float*)(w + take(M * 32 * 4));
    float* wiT0   = (float*)(w + take(32 * 192 * 4));
    float* whT0   = (float*)(w + take(64 * 192 * 4));
    float* wiT1   = (float*)(w + take(64 * 192 * 4));
    float* whT1   = (float*)(w + take(64 * 192 * 4));

    // CSR build + weight transpose (once per launch; ws re-poisoned each call)
    hipMemsetAsync(counts, 0, N * 4, stream);
    hipMemsetAsync(cursor, 0, N * 4, stream);
    const int egrid = (ETOT + 255) / 256;
    k_count<<<egrid, 256, 0, stream>>>(ei, counts);
    k_scan<<<1, 1024, 0, stream>>>(counts, offs);
    k_fill<<<egrid, 256, 0, stream>>>(ei, offs, cursor, csr);
    const int ttot = 32 * 192 + 3 * 64 * 192;
    k_transpose<<<(ttot + 255) / 256, 256, 0, stream>>>(gru0_Wi, gru0_Wh, gru1_Wi, gru1_Wh,
                                                        wiT0, whT0, wiT1, whT1);

    // Batched GAT phases over all 5 timesteps (independent of recurrence)
    const int mgrid = (NM + 3) / 4;   // 12500 blocks
    k_mm0_all<<<mgrid, 256, 0, stream>>>(x_seq, gat0_W, res0_W, gat0_as, gat0_ad, xw0, xres0, als0, ald0);
    k_gat0_all<<<mgrid, 256, 0, stream>>>(xw0, xres0, als0, ald0, offs, csr, gat0_b,
                                          gat1_W, res1_W, gat1_as, gat1_ad,
                                          xw1, xres1, als1, ald1);
    k_gat1_all<<<mgrid, 256, 0, stream>>>(xw1, xres1, als1, ald1, offs, csr, gat1_b, x2);

    // Recurrent chain + head, single kernel (per-node recurrence, h-state in registers)
    const int ggrid = NNODES / (4 * GNPW);   // 625 blocks, 4 nodes/wave
    k_gruhead<<<ggrid, 256, 0, stream>>>(x2, wiT0, whT0, wiT1, whT1,
                                         gru0_bi, gru0_bh, gru1_bi, gru1_bh,
                                         fc1_W, fc1_b, fc2_W, fc2_b, out);
}

// Round 7
// 382.159 us; speedup vs baseline: 4.6109x; 1.0926x over previous
//
#include <hip/hip_runtime.h>
#include <hip/hip_bf16.h>
#include <math.h>

#define T_STEPS 5
#define NNODES  10000
#define NM      (T_STEPS * NNODES)   // 50000 node-instances (t,n)
#define F_IN    16
#define NEDGES  160000
#define ETOT    (NEDGES + NNODES)    // + self loops
#define GW      8                    // waves per block in gruhead (512 threads)
#define GNPW    5                    // nodes per wave: 8*5=40 nodes/block, 250 blocks

// SGPR broadcast: readlane (uniform index) instead of ds_bpermute shuffles
#define RL(v, k) __int_as_float(__builtin_amdgcn_readlane(__float_as_int(v), (k)))

// ---------------- CSR build ----------------
__global__ __launch_bounds__(256) void k_count(const int* __restrict__ ei, int* __restrict__ counts) {
    int idx = blockIdx.x * 256 + threadIdx.x;
    if (idx >= ETOT) return;
    int dst = (idx < NEDGES) ? ei[NEDGES + idx] : (idx - NEDGES);
    atomicAdd(&counts[dst], 1);
}

__global__ __launch_bounds__(1024) void k_scan(const int* __restrict__ counts, int* __restrict__ offs) {
    __shared__ int ssum[1024];
    int t = threadIdx.x;
    const int chunk = (NNODES + 1023) / 1024;
    int start = t * chunk, end = min(start + chunk, NNODES);
    int s = 0;
    for (int i = start; i < end; i++) s += counts[i];
    ssum[t] = s;
    __syncthreads();
    for (int off = 1; off < 1024; off <<= 1) {
        int v = (t >= off) ? ssum[t - off] : 0;
        __syncthreads();
        ssum[t] += v;
        __syncthreads();
    }
    int excl = (t == 0) ? 0 : ssum[t - 1];
    for (int i = start; i < end; i++) { offs[i] = excl; excl += counts[i]; }
    if (t == 1023) offs[NNODES] = ssum[1023];
}

__global__ __launch_bounds__(256) void k_fill(const int* __restrict__ ei, const int* __restrict__ offs,
                                              int* __restrict__ cursor, int* __restrict__ csr) {
    int idx = blockIdx.x * 256 + threadIdx.x;
    if (idx >= ETOT) return;
    int src, dst;
    if (idx < NEDGES) { src = ei[idx]; dst = ei[NEDGES + idx]; }
    else              { src = dst = idx - NEDGES; }
    int p = atomicAdd(&cursor[dst], 1);
    csr[offs[dst] + p] = src;
}

// ---------------- one-time weight transpose for GRU cells ----------------
// WiT[k*192 + r] = Wi[r*K + k]; WhT[k*192 + r] = Wh[r*64 + k]
__global__ __launch_bounds__(256) void k_transpose(const float* __restrict__ Wi0, const float* __restrict__ Wh0,
                                                   const float* __restrict__ Wi1, const float* __restrict__ Wh1,
                                                   float* __restrict__ WiT0, float* __restrict__ WhT0,
                                                   float* __restrict__ WiT1, float* __restrict__ WhT1) {
    int idx = blockIdx.x * 256 + threadIdx.x;
    if (idx < 32 * 192) {
        int k = idx / 192, r = idx % 192;
        WiT0[idx] = Wi0[r * 32 + k];
        return;
    }
    idx -= 32 * 192;
    if (idx < 64 * 192) {
        int k = idx / 192, r = idx % 192;
        WhT0[idx] = Wh0[r * 64 + k];
        return;
    }
    idx -= 64 * 192;
    if (idx < 64 * 192) {
        int k = idx / 192, r = idx % 192;
        WiT1[idx] = Wi1[r * 64 + k];
        return;
    }
    idx -= 64 * 192;
    if (idx < 64 * 192) {
        int k = idx / 192, r = idx % 192;
        WhT1[idx] = Wh1[r * 64 + k];
    }
}

// ---------------- GAT0 projections for ALL timesteps ----------------
__global__ __launch_bounds__(256) void k_mm0_all(const float* __restrict__ x,      // [5N,16]
                                                 const float* __restrict__ W,     // [16,64]
                                                 const float* __restrict__ Wres,  // [16,64]
                                                 const float* __restrict__ asrc,  // [64]
                                                 const float* __restrict__ adst,  // [64]
                                                 float* __restrict__ xw, float* __restrict__ xres,
                                                 float* __restrict__ als, float* __restrict__ ald) {
    int wave = threadIdx.x >> 6, lane = threadIdx.x & 63;
    int m = blockIdx.x * 4 + wave;
    if (m >= NM) return;
    const float* xr = x + (size_t)m * F_IN;
    float xreg[F_IN];
#pragma unroll
    for (int k = 0; k < F_IN; k++) xreg[k] = xr[k];
    float acc = 0.f, accr = 0.f;
#pragma unroll
    for (int k = 0; k < F_IN; k++) {
        acc  += xreg[k] * W[k * 64 + lane];
        accr += xreg[k] * Wres[k * 64 + lane];
    }
    xw[(size_t)m * 64 + lane]   = acc;
    xres[(size_t)m * 64 + lane] = accr;
    float ps = acc * asrc[lane], pd = acc * adst[lane];
    for (int off = 16; off; off >>= 1) {
        ps += __shfl_down(ps, off, 32);
        pd += __shfl_down(pd, off, 32);
    }
    if ((lane & 31) == 0) {
        int h = lane >> 5;
        als[m * 2 + h] = ps;
        ald[m * 2 + h] = pd;
    }
}

// ---------------- fused GAT0 gather + ELU + residual + GAT1 projection, ALL timesteps ----------------
__global__ __launch_bounds__(256) void k_gat0_all(const float* __restrict__ xw,   // [5N,64]
                                                  const float* __restrict__ xres, // [5N,64]
                                                  const float* __restrict__ als,  // [5N,2]
                                                  const float* __restrict__ ald,  // [5N,2]
                                                  const int* __restrict__ offs, const int* __restrict__ csr,
                                                  const float* __restrict__ b,    // [64]
                                                  const float* __restrict__ W1,   // [64,32]
                                                  const float* __restrict__ Wres1,// [64,32]
                                                  const float* __restrict__ as1,  // [32]
                                                  const float* __restrict__ ad1v, // [32]
                                                  float* __restrict__ xw1, float* __restrict__ xres1,
                                                  float* __restrict__ als1, float* __restrict__ ald1) {
    int wave = threadIdx.x >> 6, lane = threadIdx.x & 63;
    int m = blockIdx.x * 4 + wave;
    if (m >= NM) return;
    int t = m / NNODES;
    int node = m - t * NNODES;
    int base = t * NNODES;
    int beg = offs[node], end = offs[node + 1];
    int deg = end - beg;
    float ad0 = ald[m * 2 + 0], ad1 = ald[m * 2 + 1];
    float acc;
    if (deg <= 64) {
        int s = 0; float e0 = -INFINITY, e1 = -INFINITY;
        if (lane < deg) {
            s = base + csr[beg + lane];
            e0 = als[s * 2 + 0] + ad0; e0 = e0 > 0.f ? e0 : 0.2f * e0;
            e1 = als[s * 2 + 1] + ad1; e1 = e1 > 0.f ? e1 : 0.2f * e1;
        }
        float m0 = e0, m1 = e1;
        for (int o = 32; o; o >>= 1) {
            m0 = fmaxf(m0, __shfl_xor(m0, o));
            m1 = fmaxf(m1, __shfl_xor(m1, o));
        }
        float ex0 = (lane < deg) ? expf(e0 - m0) : 0.f;
        float ex1 = (lane < deg) ? expf(e1 - m1) : 0.f;
        float d0 = ex0, d1 = ex1;
        for (int o = 32; o; o >>= 1) {
            d0 += __shfl_xor(d0, o);
            d1 += __shfl_xor(d1, o);
        }
        ex0 *= 1.f / (d0 + 1e-16f);
        ex1 *= 1.f / (d1 + 1e-16f);
        float a0 = 0.f, a1 = 0.f, a2 = 0.f, a3 = 0.f;
        int i = 0;
        for (; i + 4 <= deg; i += 4) {
            int   s0 = __shfl(s, i),     s1 = __shfl(s, i + 1), s2 = __shfl(s, i + 2), s3 = __shfl(s, i + 3);
            float u0 = __shfl(ex0, i),   v0 = __shfl(ex1, i);
            float u1 = __shfl(ex0, i+1), v1 = __shfl(ex1, i+1);
            float u2 = __shfl(ex0, i+2), v2 = __shfl(ex1, i+2);
            float u3 = __shfl(ex0, i+3), v3 = __shfl(ex1, i+3);
            a0 += (lane < 32 ? u0 : v0) * xw[(size_t)s0 * 64 + lane];
            a1 += (lane < 32 ? u1 : v1) * xw[(size_t)s1 * 64 + lane];
            a2 += (lane < 32 ? u2 : v2) * xw[(size_t)s2 * 64 + lane];
            a3 += (lane < 32 ? u3 : v3) * xw[(size_t)s3 * 64 + lane];
        }
        for (; i < deg; i++) {
            int s0 = __shfl(s, i);
            float u = __shfl(ex0, i), v = __shfl(ex1, i);
            a0 += (lane < 32 ? u : v) * xw[(size_t)s0 * 64 + lane];
        }
        acc = (a0 + a1) + (a2 + a3);
    } else {
        float m0 = -INFINITY, m1 = -INFINITY;
        for (int i = beg + lane; i < end; i += 64) {
            int s = base + csr[i];
            float e0 = als[s * 2 + 0] + ad0; e0 = e0 > 0.f ? e0 : 0.2f * e0;
            float e1 = als[s * 2 + 1] + ad1; e1 = e1 > 0.f ? e1 : 0.2f * e1;
            m0 = fmaxf(m0, e0); m1 = fmaxf(m1, e1);
        }
        for (int o = 32; o; o >>= 1) {
            m0 = fmaxf(m0, __shfl_xor(m0, o));
            m1 = fmaxf(m1, __shfl_xor(m1, o));
        }
        float d0 = 0.f, d1 = 0.f;
        for (int i = beg + lane; i < end; i += 64) {
            int s = base + csr[i];
            float e0 = als[s * 2 + 0] + ad0; e0 = e0 > 0.f ? e0 : 0.2f * e0;
            float e1 = als[s * 2 + 1] + ad1; e1 = e1 > 0.f ? e1 : 0.2f * e1;
            d0 += expf(e0 - m0); d1 += expf(e1 - m1);
        }
        for (int o = 32; o; o >>= 1) { d0 += __shfl_xor(d0, o); d1 += __shfl_xor(d1, o); }
        float inv0 = 1.f / (d0 + 1e-16f), inv1 = 1.f / (d1 + 1e-16f);
        acc = 0.f;
        for (int i = beg; i < end; i++) {
            int s = base + csr[i];
            float e, wgt;
            if (lane < 32) { e = als[s * 2 + 0] + ad0; e = e > 0.f ? e : 0.2f * e; wgt = expf(e - m0) * inv0; }
            else           { e = als[s * 2 + 1] + ad1; e = e > 0.f ? e : 0.2f * e; wgt = expf(e - m1) * inv1; }
            acc += wgt * xw[(size_t)s * 64 + lane];
        }
    }
    float x1v = acc + b[lane];
    x1v = x1v > 0.f ? x1v : expm1f(x1v);
    x1v += xres[(size_t)m * 64 + lane];
    // GAT1 projection: readlane broadcasts (VALU) instead of ds_bpermute
    int j = lane & 31;
    const float* Wp = (lane < 32) ? W1 : Wres1;
    float pacc = 0.f;
#pragma unroll
    for (int k = 0; k < 64; k++) {
        float xv = RL(x1v, k);
        pacc += xv * Wp[k * 32 + j];
    }
    if (lane < 32) xw1[(size_t)m * 32 + j]   = pacc;
    else           xres1[(size_t)m * 32 + j] = pacc;
    float ps = (lane < 32) ? pacc * as1[j]  : 0.f;
    float pd = (lane < 32) ? pacc * ad1v[j] : 0.f;
    for (int o = 16; o; o >>= 1) {
        ps += __shfl_down(ps, o, 32);
        pd += __shfl_down(pd, o, 32);
    }
    if (lane == 0) { als1[m] = ps; ald1[m] = pd; }
}

// ---------------- GAT1 gather -> x2, ALL timesteps ----------------
__global__ __launch_bounds__(256) void k_gat1_all(const float* __restrict__ xw1,   // [5N,32]
                                                  const float* __restrict__ xres1, // [5N,32]
                                                  const float* __restrict__ als1,  // [5N]
                                                  const float* __restrict__ ald1,  // [5N]
                                                  const int* __restrict__ offs, const int* __restrict__ csr,
                                                  const float* __restrict__ b,     // [32]
                                                  float* __restrict__ x2) {
    int wave = threadIdx.x >> 6, lane = threadIdx.x & 63;
    int m = blockIdx.x * 4 + wave;
    if (m >= NM) return;
    int t = m / NNODES;
    int node = m - t * NNODES;
    int base = t * NNODES;
    int beg = offs[node], end = offs[node + 1];
    int deg = end - beg;
    float adv = ald1[m];
    int ch = lane & 31, half = lane >> 5;
    float aggr;
    if (deg <= 64) {
        int s = 0; float e = -INFINITY;
        if (lane < deg) {
            s = base + csr[beg + lane];
            e = als1[s] + adv; e = e > 0.f ? e : 0.2f * e;
        }
        float mx = e;
        for (int o = 32; o; o >>= 1) mx = fmaxf(mx, __shfl_xor(mx, o));
        float ex = (lane < deg) ? expf(e - mx) : 0.f;
        float d = ex;
        for (int o = 32; o; o >>= 1) d += __shfl_xor(d, o);
        ex *= 1.f / (d + 1e-16f);
        float acc = 0.f;
        for (int i = 0; i < deg; i += 2) {
            int i2 = (i + 1 < deg) ? i + 1 : i;
            int   sa = __shfl(s, i),  sb = __shfl(s, i2);
            float wa = __shfl(ex, i), wb = __shfl(ex, i2);
            if (i + 1 >= deg) wb = 0.f;
            int   sm = half ? sb : sa;
            float wm = half ? wb : wa;
            acc += wm * xw1[(size_t)sm * 32 + ch];
        }
        acc += __shfl_xor(acc, 32);
        aggr = acc;
    } else {
        float mx = -INFINITY;
        for (int i = beg + lane; i < end; i += 64) {
            float e = als1[base + csr[i]] + adv; e = e > 0.f ? e : 0.2f * e;
            mx = fmaxf(mx, e);
        }
        for (int o = 32; o; o >>= 1) mx = fmaxf(mx, __shfl_xor(mx, o));
        float d = 0.f;
        for (int i = beg + lane; i < end; i += 64) {
            float e = als1[base + csr[i]] + adv; e = e > 0.f ? e : 0.2f * e;
            d += expf(e - mx);
        }
        for (int o = 32; o; o >>= 1) d += __shfl_xor(d, o);
        float inv = 1.f / (d + 1e-16f);
        float acc = 0.f;
        for (int i = beg; i < end; i++) {
            int s = base + csr[i];
            float e = als1[s] + adv; e = e > 0.f ? e : 0.2f * e;
            float wgt = expf(e - mx) * inv;
            acc += wgt * xw1[(size_t)s * 32 + ch];
        }
        aggr = acc;
    }
    if (lane < 32) {
        float v = aggr + b[ch];
        v = v > 0.f ? v : expm1f(v);
        x2[(size_t)m * 32 + ch] = v + xres1[(size_t)m * 32 + ch];
    }
}

// ---------------- fused: 5-step GRU0+GRU1 chain + MLP head ----------------
// 512 threads (8 waves x 5 nodes). Per-phase LDS staging of the 49KB weight
// matrices (block-level reuse: L2 weight traffic / 8 waves). readlane broadcasts.
__global__ __launch_bounds__(512) void k_gruhead(const float* __restrict__ x2,   // [5N,32]
                                                 const float* __restrict__ WiT0, // [32,192] (global, L1-resident)
                                                 const float* __restrict__ WhT0, // [64,192]
                                                 const float* __restrict__ WiT1, // [64,192]
                                                 const float* __restrict__ WhT1, // [64,192]
                                                 const float* __restrict__ bi0, const float* __restrict__ bh0,
                                                 const float* __restrict__ bi1, const float* __restrict__ bh1,
                                                 const float* __restrict__ fc1W, // [64,32]
                                                 const float* __restrict__ fc1b, // [32]
                                                 const float* __restrict__ fc2W, // [32]
                                                 const float* __restrict__ fc2b, // [1]
                                                 float* __restrict__ out) {
    __shared__ float lw[64 * 192];   // 49152 B: one weight matrix at a time
    int tid = threadIdx.x;
    int wave = tid >> 6, lane = tid & 63;
    int node0 = (blockIdx.x * GW + wave) * GNPW;   // 250*8*5 = 10000 exactly

    float bir0 = bi0[lane] + bh0[lane];            // r,z biases merge (gi+gh)
    float biz0 = bi0[64 + lane] + bh0[64 + lane];
    float bin0 = bi0[128 + lane], bhn0 = bh0[128 + lane];
    float bir1 = bi1[lane] + bh1[lane];
    float biz1 = bi1[64 + lane] + bh1[64 + lane];
    float bin1 = bi1[128 + lane], bhn1 = bh1[128 + lane];

    float h0[GNPW] = {0.f, 0.f, 0.f, 0.f, 0.f};    // lane = hidden channel
    float h1[GNPW] = {0.f, 0.f, 0.f, 0.f, 0.f};

    auto stage = [&](const float* __restrict__ src) {
        __syncthreads();                            // protect previous LDS readers
        const float4* s4 = (const float4*)src;
        float4* d4 = (float4*)lw;
#pragma unroll
        for (int i = 0; i < 6; i++) d4[tid + i * 512] = s4[tid + i * 512];
        __syncthreads();
    };

    for (int t = 0; t < T_STEPS; t++) {
        size_t rb = ((size_t)t * NNODES + node0) * 32;
        float xa = x2[rb + lane];                   // nodes 0,1
        float xb = x2[rb + 64 + lane];              // nodes 2,3
        float xc = x2[rb + 128 + (lane & 31)];      // node 4 (broadcast both halves)

        // ---- GRU0 ----
        float gr[GNPW], gz[GNPW], gin[GNPW], ghn[GNPW];
#pragma unroll
        for (int n = 0; n < GNPW; n++) { gr[n] = bir0; gz[n] = biz0; gin[n] = bin0; ghn[n] = bhn0; }
        // x-part: WiT0 from global (24.5KB, L1-cached across t)
#pragma unroll 4
        for (int k = 0; k < 32; k++) {
            float wr = WiT0[k * 192 + lane];
            float wz = WiT0[k * 192 + 64 + lane];
            float wn = WiT0[k * 192 + 128 + lane];
            float xv[GNPW];
            xv[0] = RL(xa, k); xv[1] = RL(xa, 32 + k);
            xv[2] = RL(xb, k); xv[3] = RL(xb, 32 + k);
            xv[4] = RL(xc, k);
#pragma unroll
            for (int n = 0; n < GNPW; n++) {
                gr[n] += xv[n] * wr; gz[n] += xv[n] * wz; gin[n] += xv[n] * wn;
            }
        }
        // h-part: WhT0 via LDS
        stage(WhT0);
#pragma unroll 4
        for (int k = 0; k < 64; k++) {
            float wr = lw[k * 192 + lane];
            float wz = lw[k * 192 + 64 + lane];
            float wn = lw[k * 192 + 128 + lane];
#pragma unroll
            for (int n = 0; n < GNPW; n++) {
                float hv = RL(h0[n], k);
                gr[n] += hv * wr; gz[n] += hv * wz; ghn[n] += hv * wn;
            }
        }
#pragma unroll
        for (int n = 0; n < GNPW; n++) {
            float r = 1.f / (1.f + expf(-gr[n]));
            float z = 1.f / (1.f + expf(-gz[n]));
            float nn = tanhf(gin[n] + r * ghn[n]);
            h0[n] = (1.f - z) * nn + z * h0[n];
        }

        // ---- GRU1 x-pass: WiT1 via LDS, x = h0 (registers) ----
#pragma unroll
        for (int n = 0; n < GNPW; n++) { gr[n] = bir1; gz[n] = biz1; gin[n] = bin1; }
        stage(WiT1);
#pragma unroll 4
        for (int k = 0; k < 64; k++) {
            float wir = lw[k * 192 + lane];
            float wiz = lw[k * 192 + 64 + lane];
            float win = lw[k * 192 + 128 + lane];
#pragma unroll
            for (int n = 0; n < GNPW; n++) {
                float xv = RL(h0[n], k);
                gr[n] += xv * wir; gz[n] += xv * wiz; gin[n] += xv * win;
            }
        }
        // ---- GRU1 h-pass: WhT1 via LDS ----
#pragma unroll
        for (int n = 0; n < GNPW; n++) ghn[n] = bhn1;
        stage(WhT1);
#pragma unroll 4
        for (int k = 0; k < 64; k++) {
            float whr = lw[k * 192 + lane];
            float whz = lw[k * 192 + 64 + lane];
            float whn = lw[k * 192 + 128 + lane];
#pragma unroll
            for (int n = 0; n < GNPW; n++) {
                float hv = RL(h1[n], k);
                gr[n] += hv * whr; gz[n] += hv * whz; ghn[n] += hv * whn;
            }
        }
#pragma unroll
        for (int n = 0; n < GNPW; n++) {
            float r = 1.f / (1.f + expf(-gr[n]));
            float z = 1.f / (1.f + expf(-gz[n]));
            float nn = tanhf(gin[n] + r * ghn[n]);
            h1[n] = (1.f - z) * nn + z * h1[n];
        }
    }

    // ---- MLP head: node-pairs; lanes 0-31 -> even node, 32-63 -> odd ----
    int j = lane & 31, half = lane >> 5;
#pragma unroll
    for (int p = 0; p < 3; p++) {
        int ne = 2 * p;
        int no = (2 * p + 1 < GNPW) ? 2 * p + 1 : 2 * p;
        float a = fc1b[j];
#pragma unroll
        for (int k = 0; k < 64; k++) {
            float he = RL(h1[ne], k);
            float ho = RL(h1[no], k);
            a += (half ? ho : he) * fc1W[k * 32 + j];
        }
        a = fmaxf(a, 0.f);
        float v = a * fc2W[j];
        for (int o = 16; o; o >>= 1) v += __shfl_down(v, o, 32);
        if ((lane & 31) == 0 && 2 * p + half < GNPW) out[node0 + 2 * p + half] = v + fc2b[0];
    }
}

extern "C" void kernel_launch(void* const* d_in, const int* in_sizes, int n_in,
                              void* d_out, int out_size, void* d_ws, size_t ws_size,
                              hipStream_t stream) {
    const float* x_seq   = (const float*)d_in[0];
    const int*   ei      = (const int*)d_in[1];
    const float* gat0_W  = (const float*)d_in[2];
    const float* gat0_as = (const float*)d_in[3];
    const float* gat0_ad = (const float*)d_in[4];
    const float* gat0_b  = (const float*)d_in[5];
    const float* res0_W  = (const float*)d_in[6];
    const float* gat1_W  = (const float*)d_in[7];
    const float* gat1_as = (const float*)d_in[8];
    const float* gat1_ad = (const float*)d_in[9];
    const float* gat1_b  = (const float*)d_in[10];
    const float* res1_W  = (const float*)d_in[11];
    const float* gru0_Wi = (const float*)d_in[12];
    const float* gru0_Wh = (const float*)d_in[13];
    const float* gru0_bi = (const float*)d_in[14];
    const float* gru0_bh = (const float*)d_in[15];
    const float* gru1_Wi = (const float*)d_in[16];
    const float* gru1_Wh = (const float*)d_in[17];
    const float* gru1_bi = (const float*)d_in[18];
    const float* gru1_bh = (const float*)d_in[19];
    const float* fc1_W   = (const float*)d_in[20];
    const float* fc1_b   = (const float*)d_in[21];
    const float* fc2_W   = (const float*)d_in[22];
    const float* fc2_b   = (const float*)d_in[23];
    float* out = (float*)d_out;

    char* w = (char*)d_ws;
    size_t off = 0;
    auto take = [&](size_t bytes) { size_t r = off; off += (bytes + 255) & ~(size_t)255; return r; };
    const size_t N = NNODES, M = NM;
    int*   counts = (int*)(w + take(N * 4));
    int*   cursor = (int*)(w + take(N * 4));
    int*   offs   = (int*)(w + take((N + 1) * 4));
    int*   csr    = (int*)(w + take((size_t)ETOT * 4));
    float* xw0    = (float*)(w + take(M * 64 * 4));
    float* xres0  = (float*)(w + take(M * 64 * 4));
    float* als0   = (float*)(w + take(M * 2 * 4));
    float* ald0   = (float*)(w + take(M * 2 * 4));
    float* xw1    = (float*)(w + take(M * 32 * 4));
    float* xres1  = (float*)(w + take(M * 32 * 4));
    float* als1   = (float*)(w + take(M * 4));
    float* ald1   = (float*)(w + take(M * 4));
    float* x2     = (float*)(w + take(M * 32 * 4));
    float* wiT0   = (float*)(w + take(32 * 192 * 4));
    float* whT0   = (float*)(w + take(64 * 192 * 4));
    float* wiT1   = (float*)(w + take(64 * 192 * 4));
    float* whT1   = (float*)(w + take(64 * 192 * 4));

    // CSR build + weight transpose (once per launch; ws re-poisoned each call)
    hipMemsetAsync(counts, 0, N * 4, stream);
    hipMemsetAsync(cursor, 0, N * 4, stream);
    const int egrid = (ETOT + 255) / 256;
    k_count<<<egrid, 256, 0, stream>>>(ei, counts);
    k_scan<<<1, 1024, 0, stream>>>(counts, offs);
    k_fill<<<egrid, 256, 0, stream>>>(ei, offs, cursor, csr);
    const int ttot = 32 * 192 + 3 * 64 * 192;
    k_transpose<<<(ttot + 255) / 256, 256, 0, stream>>>(gru0_Wi, gru0_Wh, gru1_Wi, gru1_Wh,
                                                        wiT0, whT0, wiT1, whT1);

    // Batched GAT phases over all 5 timesteps (independent of recurrence)
    const int mgrid = (NM + 3) / 4;   // 12500 blocks
    k_mm0_all<<<mgrid, 256, 0, stream>>>(x_seq, gat0_W, res0_W, gat0_as, gat0_ad, xw0, xres0, als0, ald0);
    k_gat0_all<<<mgrid, 256, 0, stream>>>(xw0, xres0, als0, ald0, offs, csr, gat0_b,
                                          gat1_W, res1_W, gat1_as, gat1_ad,
                                          xw1, xres1, als1, ald1);
    k_gat1_all<<<mgrid, 256, 0, stream>>>(xw1, xres1, als1, ald1, offs, csr, gat1_b, x2);

    // Recurrent chain + head: 250 blocks x 512 threads, LDS-staged weights
    const int ggrid = NNODES / (GW * GNPW);   // 250
    k_gruhead<<<ggrid, 512, 0, stream>>>(x2, wiT0, whT0, wiT1, whT1,
                                         gru0_bi, gru0_bh, gru1_bi, gru1_bh,
                                         fc1_W, fc1_b, fc2_W, fc2_b, out);
}

// Round 8
// 380.709 us; speedup vs baseline: 4.6285x; 1.0038x over previous
//
#include <hip/hip_runtime.h>
#include <hip/hip_bf16.h>
#include <math.h>

#define T_STEPS 5
#define NNODES  10000
#define NM      (T_STEPS * NNODES)   // 50000 node-instances (t,n)
#define F_IN    16
#define NEDGES  160000
#define ETOT    (NEDGES + NNODES)    // + self loops
#define GW      8                    // waves per block in gruhead (512 threads)
#define GNPW    5                    // nodes per wave: 8*5=40 nodes/block, 250 blocks

// SGPR broadcast: readlane (uniform index) instead of ds_bpermute shuffles
#define RL(v, k) __int_as_float(__builtin_amdgcn_readlane(__float_as_int(v), (k)))

// ---------------- CSR build ----------------
__global__ __launch_bounds__(256) void k_count(const int* __restrict__ ei, int* __restrict__ counts) {
    int idx = blockIdx.x * 256 + threadIdx.x;
    if (idx >= ETOT) return;
    int dst = (idx < NEDGES) ? ei[NEDGES + idx] : (idx - NEDGES);
    atomicAdd(&counts[dst], 1);
}

__global__ __launch_bounds__(1024) void k_scan(const int* __restrict__ counts, int* __restrict__ offs) {
    __shared__ int ssum[1024];
    int t = threadIdx.x;
    const int chunk = (NNODES + 1023) / 1024;
    int start = t * chunk, end = min(start + chunk, NNODES);
    int s = 0;
    for (int i = start; i < end; i++) s += counts[i];
    ssum[t] = s;
    __syncthreads();
    for (int off = 1; off < 1024; off <<= 1) {
        int v = (t >= off) ? ssum[t - off] : 0;
        __syncthreads();
        ssum[t] += v;
        __syncthreads();
    }
    int excl = (t == 0) ? 0 : ssum[t - 1];
    for (int i = start; i < end; i++) { offs[i] = excl; excl += counts[i]; }
    if (t == 1023) offs[NNODES] = ssum[1023];
}

__global__ __launch_bounds__(256) void k_fill(const int* __restrict__ ei, const int* __restrict__ offs,
                                              int* __restrict__ cursor, int* __restrict__ csr) {
    int idx = blockIdx.x * 256 + threadIdx.x;
    if (idx >= ETOT) return;
    int src, dst;
    if (idx < NEDGES) { src = ei[idx]; dst = ei[NEDGES + idx]; }
    else              { src = dst = idx - NEDGES; }
    int p = atomicAdd(&cursor[dst], 1);
    csr[offs[dst] + p] = src;
}

// ---------------- one-time weight transpose (flat + k4-packed float4 formats) ----------------
// flat:   WT[k*192 + c] = W[c*K + k]
// packed: P4[k4*192 + c] = float4(W[c*K+4k4], W[c*K+4k4+1], W[c*K+4k4+2], W[c*K+4k4+3])
__global__ __launch_bounds__(256) void k_transpose(const float* __restrict__ Wi0, const float* __restrict__ Wh0,
                                                   const float* __restrict__ Wi1, const float* __restrict__ Wh1,
                                                   float* __restrict__ WiT0, float* __restrict__ WhT0,
                                                   float* __restrict__ WiT1, float* __restrict__ WhT1,
                                                   float4* __restrict__ wp0, float4* __restrict__ hp0,
                                                   float4* __restrict__ ip1, float4* __restrict__ hp1) {
    int idx = blockIdx.x * 256 + threadIdx.x;
    if (idx < 6144)  { int k = idx / 192, r = idx % 192; WiT0[idx] = Wi0[r * 32 + k]; return; }
    idx -= 6144;
    if (idx < 12288) { int k = idx / 192, r = idx % 192; WhT0[idx] = Wh0[r * 64 + k]; return; }
    idx -= 12288;
    if (idx < 12288) { int k = idx / 192, r = idx % 192; WiT1[idx] = Wi1[r * 64 + k]; return; }
    idx -= 12288;
    if (idx < 12288) { int k = idx / 192, r = idx % 192; WhT1[idx] = Wh1[r * 64 + k]; return; }
    idx -= 12288;
    if (idx < 1536) { int k4 = idx / 192, c = idx % 192; const float* s = Wi0 + c * 32 + 4 * k4;
                      wp0[idx] = make_float4(s[0], s[1], s[2], s[3]); return; }
    idx -= 1536;
    if (idx < 3072) { int k4 = idx / 192, c = idx % 192; const float* s = Wh0 + c * 64 + 4 * k4;
                      hp0[idx] = make_float4(s[0], s[1], s[2], s[3]); return; }
    idx -= 3072;
    if (idx < 3072) { int k4 = idx / 192, c = idx % 192; const float* s = Wi1 + c * 64 + 4 * k4;
                      ip1[idx] = make_float4(s[0], s[1], s[2], s[3]); return; }
    idx -= 3072;
    if (idx < 3072) { int k4 = idx / 192, c = idx % 192; const float* s = Wh1 + c * 64 + 4 * k4;
                      hp1[idx] = make_float4(s[0], s[1], s[2], s[3]); }
}

// ---------------- GAT0 projections for ALL timesteps ----------------
__global__ __launch_bounds__(256) void k_mm0_all(const float* __restrict__ x,      // [5N,16]
                                                 const float* __restrict__ W,     // [16,64]
                                                 const float* __restrict__ Wres,  // [16,64]
                                                 const float* __restrict__ asrc,  // [64]
                                                 const float* __restrict__ adst,  // [64]
                                                 float* __restrict__ xw, float* __restrict__ xres,
                                                 float* __restrict__ als, float* __restrict__ ald) {
    int wave = threadIdx.x >> 6, lane = threadIdx.x & 63;
    int m = blockIdx.x * 4 + wave;
    if (m >= NM) return;
    const float* xr = x + (size_t)m * F_IN;
    float xreg[F_IN];
#pragma unroll
    for (int k = 0; k < F_IN; k++) xreg[k] = xr[k];
    float acc = 0.f, accr = 0.f;
#pragma unroll
    for (int k = 0; k < F_IN; k++) {
        acc  += xreg[k] * W[k * 64 + lane];
        accr += xreg[k] * Wres[k * 64 + lane];
    }
    xw[(size_t)m * 64 + lane]   = acc;
    xres[(size_t)m * 64 + lane] = accr;
    float ps = acc * asrc[lane], pd = acc * adst[lane];
    for (int off = 16; off; off >>= 1) {
        ps += __shfl_down(ps, off, 32);
        pd += __shfl_down(pd, off, 32);
    }
    if ((lane & 31) == 0) {
        int h = lane >> 5;
        als[m * 2 + h] = ps;
        ald[m * 2 + h] = pd;
    }
}

// ---------------- fused GAT0 gather + ELU + residual + GAT1 projection, ALL timesteps ----------------
__global__ __launch_bounds__(256) void k_gat0_all(const float* __restrict__ xw,   // [5N,64]
                                                  const float* __restrict__ xres, // [5N,64]
                                                  const float* __restrict__ als,  // [5N,2]
                                                  const float* __restrict__ ald,  // [5N,2]
                                                  const int* __restrict__ offs, const int* __restrict__ csr,
                                                  const float* __restrict__ b,    // [64]
                                                  const float* __restrict__ W1,   // [64,32]
                                                  const float* __restrict__ Wres1,// [64,32]
                                                  const float* __restrict__ as1,  // [32]
                                                  const float* __restrict__ ad1v, // [32]
                                                  float* __restrict__ xw1, float* __restrict__ xres1,
                                                  float* __restrict__ als1, float* __restrict__ ald1) {
    int wave = threadIdx.x >> 6, lane = threadIdx.x & 63;
    int m = blockIdx.x * 4 + wave;
    if (m >= NM) return;
    int t = m / NNODES;
    int node = m - t * NNODES;
    int base = t * NNODES;
    int beg = offs[node], end = offs[node + 1];
    int deg = end - beg;
    float ad0 = ald[m * 2 + 0], ad1 = ald[m * 2 + 1];
    float acc;
    if (deg <= 64) {
        int s = 0; float e0 = -INFINITY, e1 = -INFINITY;
        if (lane < deg) {
            s = base + csr[beg + lane];
            e0 = als[s * 2 + 0] + ad0; e0 = e0 > 0.f ? e0 : 0.2f * e0;
            e1 = als[s * 2 + 1] + ad1; e1 = e1 > 0.f ? e1 : 0.2f * e1;
        }
        float m0 = e0, m1 = e1;
        for (int o = 32; o; o >>= 1) {
            m0 = fmaxf(m0, __shfl_xor(m0, o));
            m1 = fmaxf(m1, __shfl_xor(m1, o));
        }
        float ex0 = (lane < deg) ? __expf(e0 - m0) : 0.f;
        float ex1 = (lane < deg) ? __expf(e1 - m1) : 0.f;
        float d0 = ex0, d1 = ex1;
        for (int o = 32; o; o >>= 1) {
            d0 += __shfl_xor(d0, o);
            d1 += __shfl_xor(d1, o);
        }
        ex0 *= 1.f / (d0 + 1e-16f);
        ex1 *= 1.f / (d1 + 1e-16f);
        float a0 = 0.f, a1 = 0.f, a2 = 0.f, a3 = 0.f;
        int i = 0;
        for (; i + 4 <= deg; i += 4) {
            int   s0 = __shfl(s, i),     s1 = __shfl(s, i + 1), s2 = __shfl(s, i + 2), s3 = __shfl(s, i + 3);
            float u0 = __shfl(ex0, i),   v0 = __shfl(ex1, i);
            float u1 = __shfl(ex0, i+1), v1 = __shfl(ex1, i+1);
            float u2 = __shfl(ex0, i+2), v2 = __shfl(ex1, i+2);
            float u3 = __shfl(ex0, i+3), v3 = __shfl(ex1, i+3);
            a0 += (lane < 32 ? u0 : v0) * xw[(size_t)s0 * 64 + lane];
            a1 += (lane < 32 ? u1 : v1) * xw[(size_t)s1 * 64 + lane];
            a2 += (lane < 32 ? u2 : v2) * xw[(size_t)s2 * 64 + lane];
            a3 += (lane < 32 ? u3 : v3) * xw[(size_t)s3 * 64 + lane];
        }
        for (; i < deg; i++) {
            int s0 = __shfl(s, i);
            float u = __shfl(ex0, i), v = __shfl(ex1, i);
            a0 += (lane < 32 ? u : v) * xw[(size_t)s0 * 64 + lane];
        }
        acc = (a0 + a1) + (a2 + a3);
    } else {
        float m0 = -INFINITY, m1 = -INFINITY;
        for (int i = beg + lane; i < end; i += 64) {
            int s = base + csr[i];
            float e0 = als[s * 2 + 0] + ad0; e0 = e0 > 0.f ? e0 : 0.2f * e0;
            float e1 = als[s * 2 + 1] + ad1; e1 = e1 > 0.f ? e1 : 0.2f * e1;
            m0 = fmaxf(m0, e0); m1 = fmaxf(m1, e1);
        }
        for (int o = 32; o; o >>= 1) {
            m0 = fmaxf(m0, __shfl_xor(m0, o));
            m1 = fmaxf(m1, __shfl_xor(m1, o));
        }
        float d0 = 0.f, d1 = 0.f;
        for (int i = beg + lane; i < end; i += 64) {
            int s = base + csr[i];
            float e0 = als[s * 2 + 0] + ad0; e0 = e0 > 0.f ? e0 : 0.2f * e0;
            float e1 = als[s * 2 + 1] + ad1; e1 = e1 > 0.f ? e1 : 0.2f * e1;
            d0 += __expf(e0 - m0); d1 += __expf(e1 - m1);
        }
        for (int o = 32; o; o >>= 1) { d0 += __shfl_xor(d0, o); d1 += __shfl_xor(d1, o); }
        float inv0 = 1.f / (d0 + 1e-16f), inv1 = 1.f / (d1 + 1e-16f);
        acc = 0.f;
        for (int i = beg; i < end; i++) {
            int s = base + csr[i];
            float e, wgt;
            if (lane < 32) { e = als[s * 2 + 0] + ad0; e = e > 0.f ? e : 0.2f * e; wgt = __expf(e - m0) * inv0; }
            else           { e = als[s * 2 + 1] + ad1; e = e > 0.f ? e : 0.2f * e; wgt = __expf(e - m1) * inv1; }
            acc += wgt * xw[(size_t)s * 64 + lane];
        }
    }
    float x1v = acc + b[lane];
    x1v = x1v > 0.f ? x1v : expm1f(x1v);
    x1v += xres[(size_t)m * 64 + lane];
    // GAT1 projection: readlane broadcasts (VALU) instead of ds_bpermute
    int j = lane & 31;
    const float* Wp = (lane < 32) ? W1 : Wres1;
    float pacc = 0.f;
#pragma unroll
    for (int k = 0; k < 64; k++) {
        float xv = RL(x1v, k);
        pacc += xv * Wp[k * 32 + j];
    }
    if (lane < 32) xw1[(size_t)m * 32 + j]   = pacc;
    else           xres1[(size_t)m * 32 + j] = pacc;
    float ps = (lane < 32) ? pacc * as1[j]  : 0.f;
    float pd = (lane < 32) ? pacc * ad1v[j] : 0.f;
    for (int o = 16; o; o >>= 1) {
        ps += __shfl_down(ps, o, 32);
        pd += __shfl_down(pd, o, 32);
    }
    if (lane == 0) { als1[m] = ps; ald1[m] = pd; }
}

// ---------------- GAT1 gather -> x2, ALL timesteps ----------------
__global__ __launch_bounds__(256) void k_gat1_all(const float* __restrict__ xw1,   // [5N,32]
                                                  const float* __restrict__ xres1, // [5N,32]
                                                  const float* __restrict__ als1,  // [5N]
                                                  const float* __restrict__ ald1,  // [5N]
                                                  const int* __restrict__ offs, const int* __restrict__ csr,
                                                  const float* __restrict__ b,     // [32]
                                                  float* __restrict__ x2) {
    int wave = threadIdx.x >> 6, lane = threadIdx.x & 63;
    int m = blockIdx.x * 4 + wave;
    if (m >= NM) return;
    int t = m / NNODES;
    int node = m - t * NNODES;
    int base = t * NNODES;
    int beg = offs[node], end = offs[node + 1];
    int deg = end - beg;
    float adv = ald1[m];
    int ch = lane & 31, half = lane >> 5;
    float aggr;
    if (deg <= 64) {
        int s = 0; float e = -INFINITY;
        if (lane < deg) {
            s = base + csr[beg + lane];
            e = als1[s] + adv; e = e > 0.f ? e : 0.2f * e;
        }
        float mx = e;
        for (int o = 32; o; o >>= 1) mx = fmaxf(mx, __shfl_xor(mx, o));
        float ex = (lane < deg) ? __expf(e - mx) : 0.f;
        float d = ex;
        for (int o = 32; o; o >>= 1) d += __shfl_xor(d, o);
        ex *= 1.f / (d + 1e-16f);
        float acc = 0.f;
        for (int i = 0; i < deg; i += 2) {
            int i2 = (i + 1 < deg) ? i + 1 : i;
            int   sa = __shfl(s, i),  sb = __shfl(s, i2);
            float wa = __shfl(ex, i), wb = __shfl(ex, i2);
            if (i + 1 >= deg) wb = 0.f;
            int   sm = half ? sb : sa;
            float wm = half ? wb : wa;
            acc += wm * xw1[(size_t)sm * 32 + ch];
        }
        acc += __shfl_xor(acc, 32);
        aggr = acc;
    } else {
        float mx = -INFINITY;
        for (int i = beg + lane; i < end; i += 64) {
            float e = als1[base + csr[i]] + adv; e = e > 0.f ? e : 0.2f * e;
            mx = fmaxf(mx, e);
        }
        for (int o = 32; o; o >>= 1) mx = fmaxf(mx, __shfl_xor(mx, o));
        float d = 0.f;
        for (int i = beg + lane; i < end; i += 64) {
            float e = als1[base + csr[i]] + adv; e = e > 0.f ? e : 0.2f * e;
            d += __expf(e - mx);
        }
        for (int o = 32; o; o >>= 1) d += __shfl_xor(d, o);
        float inv = 1.f / (d + 1e-16f);
        float acc = 0.f;
        for (int i = beg; i < end; i++) {
            int s = base + csr[i];
            float e = als1[s] + adv; e = e > 0.f ? e : 0.2f * e;
            float wgt = __expf(e - mx) * inv;
            acc += wgt * xw1[(size_t)s * 32 + ch];
        }
        aggr = acc;
    }
    if (lane < 32) {
        float v = aggr + b[ch];
        v = v > 0.f ? v : expm1f(v);
        x2[(size_t)m * 32 + ch] = v + xres1[(size_t)m * 32 + ch];
    }
}

// ---------------- persistent-LDS GRU chain + head: 147KB dyn LDS, no in-loop barriers ----------------
__global__ __launch_bounds__(512) void k_gruhead_p(const float* __restrict__ x2,   // [5N,32]
                                                   const float4* __restrict__ wp0, // [8*192] packed (global/L1)
                                                   const float4* __restrict__ hp0, // [16*192] packed
                                                   const float4* __restrict__ ip1,
                                                   const float4* __restrict__ hp1,
                                                   const float* __restrict__ bi0, const float* __restrict__ bh0,
                                                   const float* __restrict__ bi1, const float* __restrict__ bh1,
                                                   const float* __restrict__ fc1W, const float* __restrict__ fc1b,
                                                   const float* __restrict__ fc2W, const float* __restrict__ fc2b,
                                                   float* __restrict__ out) {
    extern __shared__ float4 lds4[];                // 3 x 3072 float4 = 147456 B
    float4* Lh0 = lds4;
    float4* Li1 = lds4 + 3072;
    float4* Lh1 = lds4 + 6144;
    int tid = threadIdx.x, wave = tid >> 6, lane = tid & 63;
    int node0 = (blockIdx.x * GW + wave) * GNPW;    // 250*8*5 = 10000 exactly

    for (int i = tid; i < 3072; i += 512) { Lh0[i] = hp0[i]; Li1[i] = ip1[i]; Lh1[i] = hp1[i]; }
    __syncthreads();                                // the only barrier

    float bir0 = bi0[lane] + bh0[lane];
    float biz0 = bi0[64 + lane] + bh0[64 + lane];
    float bin0 = bi0[128 + lane], bhn0 = bh0[128 + lane];
    float bir1 = bi1[lane] + bh1[lane];
    float biz1 = bi1[64 + lane] + bh1[64 + lane];
    float bin1 = bi1[128 + lane], bhn1 = bh1[128 + lane];

    float h0[GNPW] = {0.f, 0.f, 0.f, 0.f, 0.f};
    float h1[GNPW] = {0.f, 0.f, 0.f, 0.f, 0.f};

    for (int t = 0; t < T_STEPS; t++) {
        size_t rb = ((size_t)t * NNODES + node0) * 32;
        float xa = x2[rb + lane];
        float xb = x2[rb + 64 + lane];
        float xc = x2[rb + 128 + (lane & 31)];

        float gr[GNPW], gz[GNPW], gin[GNPW], ghn[GNPW];
#pragma unroll
        for (int n = 0; n < GNPW; n++) { gr[n] = bir0; gz[n] = biz0; gin[n] = bin0; ghn[n] = bhn0; }
        // GRU0 x-part (K=32, packed global wp0)
#pragma unroll
        for (int k4 = 0; k4 < 8; k4++) {
            float4 wr = wp0[(k4 * 3 + 0) * 64 + lane];
            float4 wz = wp0[(k4 * 3 + 1) * 64 + lane];
            float4 wn = wp0[(k4 * 3 + 2) * 64 + lane];
            int kb = 4 * k4;
#pragma unroll
            for (int n = 0; n < GNPW; n++) {
                float x0, x1, x2v, x3;
                if      (n == 0) { x0 = RL(xa, kb); x1 = RL(xa, kb+1); x2v = RL(xa, kb+2); x3 = RL(xa, kb+3); }
                else if (n == 1) { x0 = RL(xa, 32+kb); x1 = RL(xa, 33+kb); x2v = RL(xa, 34+kb); x3 = RL(xa, 35+kb); }
                else if (n == 2) { x0 = RL(xb, kb); x1 = RL(xb, kb+1); x2v = RL(xb, kb+2); x3 = RL(xb, kb+3); }
                else if (n == 3) { x0 = RL(xb, 32+kb); x1 = RL(xb, 33+kb); x2v = RL(xb, 34+kb); x3 = RL(xb, 35+kb); }
                else             { x0 = RL(xc, kb); x1 = RL(xc, kb+1); x2v = RL(xc, kb+2); x3 = RL(xc, kb+3); }
                gr[n]  += x0 * wr.x + x1 * wr.y + x2v * wr.z + x3 * wr.w;
                gz[n]  += x0 * wz.x + x1 * wz.y + x2v * wz.z + x3 * wz.w;
                gin[n] += x0 * wn.x + x1 * wn.y + x2v * wn.z + x3 * wn.w;
            }
        }
        // GRU0 h-part (K=64, LDS Lh0)
#pragma unroll 4
        for (int k4 = 0; k4 < 16; k4++) {
            float4 wr = Lh0[(k4 * 3 + 0) * 64 + lane];
            float4 wz = Lh0[(k4 * 3 + 1) * 64 + lane];
            float4 wn = Lh0[(k4 * 3 + 2) * 64 + lane];
            int kb = 4 * k4;
#pragma unroll
            for (int n = 0; n < GNPW; n++) {
                float x0 = RL(h0[n], kb), x1 = RL(h0[n], kb+1), x2v = RL(h0[n], kb+2), x3 = RL(h0[n], kb+3);
                gr[n]  += x0 * wr.x + x1 * wr.y + x2v * wr.z + x3 * wr.w;
                gz[n]  += x0 * wz.x + x1 * wz.y + x2v * wz.z + x3 * wz.w;
                ghn[n] += x0 * wn.x + x1 * wn.y + x2v * wn.z + x3 * wn.w;
            }
        }
#pragma unroll
        for (int n = 0; n < GNPW; n++) {
            float r = 1.f / (1.f + __expf(-gr[n]));
            float z = 1.f / (1.f + __expf(-gz[n]));
            float nn = tanhf(gin[n] + r * ghn[n]);
            h0[n] = (1.f - z) * nn + z * h0[n];
        }

        // GRU1 x-pass (Li1, x = h0 new)
#pragma unroll
        for (int n = 0; n < GNPW; n++) { gr[n] = bir1; gz[n] = biz1; gin[n] = bin1; }
#pragma unroll 4
        for (int k4 = 0; k4 < 16; k4++) {
            float4 wr = Li1[(k4 * 3 + 0) * 64 + lane];
            float4 wz = Li1[(k4 * 3 + 1) * 64 + lane];
            float4 wn = Li1[(k4 * 3 + 2) * 64 + lane];
            int kb = 4 * k4;
#pragma unroll
            for (int n = 0; n < GNPW; n++) {
                float x0 = RL(h0[n], kb), x1 = RL(h0[n], kb+1), x2v = RL(h0[n], kb+2), x3 = RL(h0[n], kb+3);
                gr[n]  += x0 * wr.x + x1 * wr.y + x2v * wr.z + x3 * wr.w;
                gz[n]  += x0 * wz.x + x1 * wz.y + x2v * wz.z + x3 * wz.w;
                gin[n] += x0 * wn.x + x1 * wn.y + x2v * wn.z + x3 * wn.w;
            }
        }
        // GRU1 h-pass (Lh1)
#pragma unroll
        for (int n = 0; n < GNPW; n++) ghn[n] = bhn1;
#pragma unroll 4
        for (int k4 = 0; k4 < 16; k4++) {
            float4 wr = Lh1[(k4 * 3 + 0) * 64 + lane];
            float4 wz = Lh1[(k4 * 3 + 1) * 64 + lane];
            float4 wn = Lh1[(k4 * 3 + 2) * 64 + lane];
            int kb = 4 * k4;
#pragma unroll
            for (int n = 0; n < GNPW; n++) {
                float x0 = RL(h1[n], kb), x1 = RL(h1[n], kb+1), x2v = RL(h1[n], kb+2), x3 = RL(h1[n], kb+3);
                gr[n]  += x0 * wr.x + x1 * wr.y + x2v * wr.z + x3 * wr.w;
                gz[n]  += x0 * wz.x + x1 * wz.y + x2v * wz.z + x3 * wz.w;
                ghn[n] += x0 * wn.x + x1 * wn.y + x2v * wn.z + x3 * wn.w;
            }
        }
#pragma unroll
        for (int n = 0; n < GNPW; n++) {
            float r = 1.f / (1.f + __expf(-gr[n]));
            float z = 1.f / (1.f + __expf(-gz[n]));
            float nn = tanhf(gin[n] + r * ghn[n]);
            h1[n] = (1.f - z) * nn + z * h1[n];
        }
    }

    // MLP head
    int j = lane & 31, half = lane >> 5;
#pragma unroll
    for (int p = 0; p < 3; p++) {
        int ne = 2 * p;
        int no = (2 * p + 1 < GNPW) ? 2 * p + 1 : 2 * p;
        float a = fc1b[j];
#pragma unroll
        for (int k = 0; k < 64; k++) {
            float he = RL(h1[ne], k);
            float ho = RL(h1[no], k);
            a += (half ? ho : he) * fc1W[k * 32 + j];
        }
        a = fmaxf(a, 0.f);
        float v = a * fc2W[j];
        for (int o = 16; o; o >>= 1) v += __shfl_down(v, o, 32);
        if ((lane & 31) == 0 && 2 * p + half < GNPW) out[node0 + 2 * p + half] = v + fc2b[0];
    }
}

// ---------------- fallback: per-phase LDS staging (49KB static), flat weights ----------------
__global__ __launch_bounds__(512) void k_gruhead(const float* __restrict__ x2,
                                                 const float* __restrict__ WiT0,
                                                 const float* __restrict__ WhT0,
                                                 const float* __restrict__ WiT1,
                                                 const float* __restrict__ WhT1,
                                                 const float* __restrict__ bi0, const float* __restrict__ bh0,
                                                 const float* __restrict__ bi1, const float* __restrict__ bh1,
                                                 const float* __restrict__ fc1W, const float* __restrict__ fc1b,
                                                 const float* __restrict__ fc2W, const float* __restrict__ fc2b,
                                                 float* __restrict__ out) {
    __shared__ float lw[64 * 192];
    int tid = threadIdx.x;
    int wave = tid >> 6, lane = tid & 63;
    int node0 = (blockIdx.x * GW + wave) * GNPW;

    float bir0 = bi0[lane] + bh0[lane];
    float biz0 = bi0[64 + lane] + bh0[64 + lane];
    float bin0 = bi0[128 + lane], bhn0 = bh0[128 + lane];
    float bir1 = bi1[lane] + bh1[lane];
    float biz1 = bi1[64 + lane] + bh1[64 + lane];
    float bin1 = bi1[128 + lane], bhn1 = bh1[128 + lane];

    float h0[GNPW] = {0.f, 0.f, 0.f, 0.f, 0.f};
    float h1[GNPW] = {0.f, 0.f, 0.f, 0.f, 0.f};

    auto stage = [&](const float* __restrict__ src) {
        __syncthreads();
        const float4* s4 = (const float4*)src;
        float4* d4 = (float4*)lw;
#pragma unroll
        for (int i = 0; i < 6; i++) d4[tid + i * 512] = s4[tid + i * 512];
        __syncthreads();
    };

    for (int t = 0; t < T_STEPS; t++) {
        size_t rb = ((size_t)t * NNODES + node0) * 32;
        float xa = x2[rb + lane];
        float xb = x2[rb + 64 + lane];
        float xc = x2[rb + 128 + (lane & 31)];

        float gr[GNPW], gz[GNPW], gin[GNPW], ghn[GNPW];
#pragma unroll
        for (int n = 0; n < GNPW; n++) { gr[n] = bir0; gz[n] = biz0; gin[n] = bin0; ghn[n] = bhn0; }
#pragma unroll 4
        for (int k = 0; k < 32; k++) {
            float wr = WiT0[k * 192 + lane];
            float wz = WiT0[k * 192 + 64 + lane];
            float wn = WiT0[k * 192 + 128 + lane];
            float xv[GNPW];
            xv[0] = RL(xa, k); xv[1] = RL(xa, 32 + k);
            xv[2] = RL(xb, k); xv[3] = RL(xb, 32 + k);
            xv[4] = RL(xc, k);
#pragma unroll
            for (int n = 0; n < GNPW; n++) {
                gr[n] += xv[n] * wr; gz[n] += xv[n] * wz; gin[n] += xv[n] * wn;
            }
        }
        stage(WhT0);
#pragma unroll 4
        for (int k = 0; k < 64; k++) {
            float wr = lw[k * 192 + lane];
            float wz = lw[k * 192 + 64 + lane];
            float wn = lw[k * 192 + 128 + lane];
#pragma unroll
            for (int n = 0; n < GNPW; n++) {
                float hv = RL(h0[n], k);
                gr[n] += hv * wr; gz[n] += hv * wz; ghn[n] += hv * wn;
            }
        }
#pragma unroll
        for (int n = 0; n < GNPW; n++) {
            float r = 1.f / (1.f + __expf(-gr[n]));
            float z = 1.f / (1.f + __expf(-gz[n]));
            float nn = tanhf(gin[n] + r * ghn[n]);
            h0[n] = (1.f - z) * nn + z * h0[n];
        }
#pragma unroll
        for (int n = 0; n < GNPW; n++) { gr[n] = bir1; gz[n] = biz1; gin[n] = bin1; }
        stage(WiT1);
#pragma unroll 4
        for (int k = 0; k < 64; k++) {
            float wir = lw[k * 192 + lane];
            float wiz = lw[k * 192 + 64 + lane];
            float win = lw[k * 192 + 128 + lane];
#pragma unroll
            for (int n = 0; n < GNPW; n++) {
                float xv = RL(h0[n], k);
                gr[n] += xv * wir; gz[n] += xv * wiz; gin[n] += xv * win;
            }
        }
#pragma unroll
        for (int n = 0; n < GNPW; n++) ghn[n] = bhn1;
        stage(WhT1);
#pragma unroll 4
        for (int k = 0; k < 64; k++) {
            float whr = lw[k * 192 + lane];
            float whz = lw[k * 192 + 64 + lane];
            float whn = lw[k * 192 + 128 + lane];
#pragma unroll
            for (int n = 0; n < GNPW; n++) {
                float hv = RL(h1[n], k);
                gr[n] += hv * whr; gz[n] += hv * whz; ghn[n] += hv * whn;
            }
        }
#pragma unroll
        for (int n = 0; n < GNPW; n++) {
            float r = 1.f / (1.f + __expf(-gr[n]));
            float z = 1.f / (1.f + __expf(-gz[n]));
            float nn = tanhf(gin[n] + r * ghn[n]);
            h1[n] = (1.f - z) * nn + z * h1[n];
        }
    }

    int j = lane & 31, half = lane >> 5;
#pragma unroll
    for (int p = 0; p < 3; p++) {
        int ne = 2 * p;
        int no = (2 * p + 1 < GNPW) ? 2 * p + 1 : 2 * p;
        float a = fc1b[j];
#pragma unroll
        for (int k = 0; k < 64; k++) {
            float he = RL(h1[ne], k);
            float ho = RL(h1[no], k);
            a += (half ? ho : he) * fc1W[k * 32 + j];
        }
        a = fmaxf(a, 0.f);
        float v = a * fc2W[j];
        for (int o = 16; o; o >>= 1) v += __shfl_down(v, o, 32);
        if ((lane & 31) == 0 && 2 * p + half < GNPW) out[node0 + 2 * p + half] = v + fc2b[0];
    }
}

extern "C" void kernel_launch(void* const* d_in, const int* in_sizes, int n_in,
                              void* d_out, int out_size, void* d_ws, size_t ws_size,
                              hipStream_t stream) {
    const float* x_seq   = (const float*)d_in[0];
    const int*   ei      = (const int*)d_in[1];
    const float* gat0_W  = (const float*)d_in[2];
    const float* gat0_as = (const float*)d_in[3];
    const float* gat0_ad = (const float*)d_in[4];
    const float* gat0_b  = (const float*)d_in[5];
    const float* res0_W  = (const float*)d_in[6];
    const float* gat1_W  = (const float*)d_in[7];
    const float* gat1_as = (const float*)d_in[8];
    const float* gat1_ad = (const float*)d_in[9];
    const float* gat1_b  = (const float*)d_in[10];
    const float* res1_W  = (const float*)d_in[11];
    const float* gru0_Wi = (const float*)d_in[12];
    const float* gru0_Wh = (const float*)d_in[13];
    const float* gru0_bi = (const float*)d_in[14];
    const float* gru0_bh = (const float*)d_in[15];
    const float* gru1_Wi = (const float*)d_in[16];
    const float* gru1_Wh = (const float*)d_in[17];
    const float* gru1_bi = (const float*)d_in[18];
    const float* gru1_bh = (const float*)d_in[19];
    const float* fc1_W   = (const float*)d_in[20];
    const float* fc1_b   = (const float*)d_in[21];
    const float* fc2_W   = (const float*)d_in[22];
    const float* fc2_b   = (const float*)d_in[23];
    float* out = (float*)d_out;

    char* w = (char*)d_ws;
    size_t off = 0;
    auto take = [&](size_t bytes) { size_t r = off; off += (bytes + 255) & ~(size_t)255; return r; };
    const size_t N = NNODES, M = NM;
    int*    counts = (int*)(w + take(N * 4));
    int*    cursor = (int*)(w + take(N * 4));
    int*    offs   = (int*)(w + take((N + 1) * 4));
    int*    csr    = (int*)(w + take((size_t)ETOT * 4));
    float*  xw0    = (float*)(w + take(M * 64 * 4));
    float*  xres0  = (float*)(w + take(M * 64 * 4));
    float*  als0   = (float*)(w + take(M * 2 * 4));
    float*  ald0   = (float*)(w + take(M * 2 * 4));
    float*  xw1    = (float*)(w + take(M * 32 * 4));
    float*  xres1  = (float*)(w + take(M * 32 * 4));
    float*  als1   = (float*)(w + take(M * 4));
    float*  ald1   = (float*)(w + take(M * 4));
    float*  x2     = (float*)(w + take(M * 32 * 4));
    float*  wiT0   = (float*)(w + take(32 * 192 * 4));
    float*  whT0   = (float*)(w + take(64 * 192 * 4));
    float*  wiT1   = (float*)(w + take(64 * 192 * 4));
    float*  whT1   = (float*)(w + take(64 * 192 * 4));
    float4* wp0    = (float4*)(w + take(1536 * 16));
    float4* hp0    = (float4*)(w + take(3072 * 16));
    float4* ip1    = (float4*)(w + take(3072 * 16));
    float4* hp1    = (float4*)(w + take(3072 * 16));

    // CSR build + weight transpose (once per launch; ws re-poisoned each call)
    hipMemsetAsync(counts, 0, N * 4, stream);
    hipMemsetAsync(cursor, 0, N * 4, stream);
    const int egrid = (ETOT + 255) / 256;
    k_count<<<egrid, 256, 0, stream>>>(ei, counts);
    k_scan<<<1, 1024, 0, stream>>>(counts, offs);
    k_fill<<<egrid, 256, 0, stream>>>(ei, offs, cursor, csr);
    const int ttot = 6144 + 3 * 12288 + 1536 + 3 * 3072;   // 53760
    k_transpose<<<(ttot + 255) / 256, 256, 0, stream>>>(gru0_Wi, gru0_Wh, gru1_Wi, gru1_Wh,
                                                        wiT0, whT0, wiT1, whT1,
                                                        wp0, hp0, ip1, hp1);

    // Batched GAT phases over all 5 timesteps (independent of recurrence)
    const int mgrid = (NM + 3) / 4;   // 12500 blocks
    k_mm0_all<<<mgrid, 256, 0, stream>>>(x_seq, gat0_W, res0_W, gat0_as, gat0_ad, xw0, xres0, als0, ald0);
    k_gat0_all<<<mgrid, 256, 0, stream>>>(xw0, xres0, als0, ald0, offs, csr, gat0_b,
                                          gat1_W, res1_W, gat1_as, gat1_ad,
                                          xw1, xres1, als1, ald1);
    k_gat1_all<<<mgrid, 256, 0, stream>>>(xw1, xres1, als1, ald1, offs, csr, gat1_b, x2);

    // Recurrent chain + head: prefer persistent-LDS variant (147456 B dyn shared)
    const int ggrid = NNODES / (GW * GNPW);   // 250
    hipError_t ae = hipFuncSetAttribute(reinterpret_cast<const void*>(k_gruhead_p),
                                        hipFuncAttributeMaxDynamicSharedMemorySize, 147456);
    if (ae == hipSuccess) {
        k_gruhead_p<<<ggrid, 512, 147456, stream>>>(x2, wp0, hp0, ip1, hp1,
                                                    gru0_bi, gru0_bh, gru1_bi, gru1_bh,
                                                    fc1_W, fc1_b, fc2_W, fc2_b, out);
    } else {
        k_gruhead<<<ggrid, 512, 0, stream>>>(x2, wiT0, whT0, wiT1, whT1,
                                             gru0_bi, gru0_bh, gru1_bi, gru1_bh,
                                             fc1_W, fc1_b, fc2_W, fc2_b, out);
    }
}